// Round 1
// baseline (873.375 us; speedup 1.0000x reference)
//
#include <hip/hip_runtime.h>
#include <hip/hip_bf16.h>

#define S_LEN 2048
#define NHEAD 16
#define NOPE 128
#define ROPE 64
#define HD 192   // nope + rope

typedef unsigned short ushort_t;
typedef __attribute__((ext_vector_type(8))) short short8;
typedef __attribute__((ext_vector_type(4))) float f32x4;

__device__ __forceinline__ unsigned short f2bf(float f) {
  unsigned int u = __float_as_uint(f);
  return (unsigned short)((u + 0x7FFFu + ((u >> 16) & 1u)) >> 16);
}

// ---------------- transpose + cast: B f32 [K][N] -> Bt bf16 [Npad][K] ----------------
__global__ __launch_bounds__(256) void transpose_cast_k(const float* __restrict__ B,
                                                        ushort_t* __restrict__ Bt,
                                                        int K, int N) {
  __shared__ float tile[32][33];
  const int tx = threadIdx.x & 31, ty = threadIdx.x >> 5;  // 32 x 8
  const int n0 = blockIdx.x * 32, k0 = blockIdx.y * 32;
  if (n0 >= N) {
#pragma unroll
    for (int r = 0; r < 4; ++r)
      Bt[(size_t)(n0 + ty + 8 * r) * K + k0 + tx] = 0;
    return;
  }
#pragma unroll
  for (int r = 0; r < 4; ++r)
    tile[ty + 8 * r][tx] = B[(size_t)(k0 + ty + 8 * r) * N + n0 + tx];
  __syncthreads();
#pragma unroll
  for (int r = 0; r < 4; ++r)
    Bt[(size_t)(n0 + ty + 8 * r) * K + k0 + tx] = f2bf(tile[tx][ty + 8 * r]);
}

// ---------------- MFMA GEMM (unchanged, verified) ----------------
template<bool A_IS_F32>
__global__ __launch_bounds__(256) void mfma_gemm(const void* __restrict__ Av,
                                                 const ushort_t* __restrict__ Bt,
                                                 float* __restrict__ C,
                                                 int M, int N, int K, int ldc) {
  __shared__ ushort_t As[128 * 32];
  __shared__ ushort_t Bs[128 * 32];
  const int tid = threadIdx.x;
  const int lane = tid & 63;
  const int wave = tid >> 6;
  const int wm = wave & 1, wn = wave >> 1;
  const int m0 = blockIdx.y * 128, n0 = blockIdx.x * 128;
  const int l15 = lane & 15, quad = lane >> 4;

  f32x4 acc[4][4] = {};

  const int it0 = tid, it1 = tid + 256;
  const int ma0 = it0 >> 2, kc0 = it0 & 3;
  const int ma1 = it1 >> 2, kc1 = it1 & 3;

  for (int k0 = 0; k0 < K; k0 += 32) {
    if (A_IS_F32) {
      const float* Af = (const float*)Av;
      {
        const float4 v0 = *(const float4*)&Af[(size_t)(m0 + ma0) * K + k0 + kc0 * 8];
        const float4 v1 = *(const float4*)&Af[(size_t)(m0 + ma0) * K + k0 + kc0 * 8 + 4];
        union { uint4 u; ushort_t s[8]; } pk;
        pk.s[0] = f2bf(v0.x); pk.s[1] = f2bf(v0.y); pk.s[2] = f2bf(v0.z); pk.s[3] = f2bf(v0.w);
        pk.s[4] = f2bf(v1.x); pk.s[5] = f2bf(v1.y); pk.s[6] = f2bf(v1.z); pk.s[7] = f2bf(v1.w);
        *(uint4*)&As[it0 * 8] = pk.u;
      }
      {
        const float4 v0 = *(const float4*)&Af[(size_t)(m0 + ma1) * K + k0 + kc1 * 8];
        const float4 v1 = *(const float4*)&Af[(size_t)(m0 + ma1) * K + k0 + kc1 * 8 + 4];
        union { uint4 u; ushort_t s[8]; } pk;
        pk.s[0] = f2bf(v0.x); pk.s[1] = f2bf(v0.y); pk.s[2] = f2bf(v0.z); pk.s[3] = f2bf(v0.w);
        pk.s[4] = f2bf(v1.x); pk.s[5] = f2bf(v1.y); pk.s[6] = f2bf(v1.z); pk.s[7] = f2bf(v1.w);
        *(uint4*)&As[it1 * 8] = pk.u;
      }
    } else {
      const ushort_t* Ab = (const ushort_t*)Av;
      *(uint4*)&As[it0 * 8] = *(const uint4*)&Ab[(size_t)(m0 + ma0) * K + k0 + kc0 * 8];
      *(uint4*)&As[it1 * 8] = *(const uint4*)&Ab[(size_t)(m0 + ma1) * K + k0 + kc1 * 8];
    }
    *(uint4*)&Bs[it0 * 8] = *(const uint4*)&Bt[(size_t)(n0 + ma0) * K + k0 + kc0 * 8];
    *(uint4*)&Bs[it1 * 8] = *(const uint4*)&Bt[(size_t)(n0 + ma1) * K + k0 + kc1 * 8];
    __syncthreads();

    short8 af[4], bf[4];
#pragma unroll
    for (int i = 0; i < 4; ++i)
      af[i] = *(const short8*)&As[(wm * 64 + i * 16 + l15) * 32 + quad * 8];
#pragma unroll
    for (int j = 0; j < 4; ++j)
      bf[j] = *(const short8*)&Bs[(wn * 64 + j * 16 + l15) * 32 + quad * 8];
#pragma unroll
    for (int i = 0; i < 4; ++i)
#pragma unroll
      for (int j = 0; j < 4; ++j)
        acc[i][j] = __builtin_amdgcn_mfma_f32_16x16x32_bf16(af[i], bf[j], acc[i][j], 0, 0, 0);
    __syncthreads();
  }

#pragma unroll
  for (int i = 0; i < 4; ++i)
#pragma unroll
    for (int r = 0; r < 4; ++r) {
      const size_t rg = (size_t)(m0 + wm * 64 + i * 16 + quad * 4 + r);
#pragma unroll
      for (int j = 0; j < 4; ++j)
        C[rg * ldc + n0 + wn * 64 + j * 16 + l15] = acc[i][j][r];
    }
}

// ---------------- RMSNorm: f32 in -> bf16 out ----------------
__global__ __launch_bounds__(256) void rmsnorm_k(const float* __restrict__ in, int in_stride,
                                                 ushort_t* __restrict__ out, int out_stride,
                                                 const float* __restrict__ w, int L) {
  const int row = blockIdx.x;
  const int tid = threadIdx.x;
  const float* ip = in + (size_t)row * in_stride;
  ushort_t* op = out + (size_t)row * out_stride;
  const int nper = L >> 8;
  float r[6];
  float ss = 0.f;
  for (int j = 0; j < nper; ++j) {
    r[j] = ip[tid + (j << 8)];
    ss += r[j] * r[j];
  }
  for (int off = 32; off; off >>= 1) ss += __shfl_down(ss, off);
  __shared__ float wsum[4];
  __shared__ float scale_s;
  if ((tid & 63) == 0) wsum[tid >> 6] = ss;
  __syncthreads();
  if (tid == 0) {
    float t = wsum[0] + wsum[1] + wsum[2] + wsum[3];
    scale_s = rsqrtf(t / (float)L + 1e-5f);
  }
  __syncthreads();
  const float sc = scale_s;
  for (int j = 0; j < nper; ++j)
    op[tid + (j << 8)] = f2bf(r[j] * sc * w[tid + (j << 8)]);
}

// ---------------- RoPE ----------------
__global__ __launch_bounds__(512) void rope_k(float* __restrict__ qall,
                                              const float* __restrict__ kvd,
                                              float* __restrict__ krope,
                                              const float* __restrict__ cosb,
                                              const float* __restrict__ sinb) {
  const int row = blockIdx.x;
  const int s = row & (S_LEN - 1);
  const int tid = threadIdx.x;
  const int d = tid & 31, h = tid >> 5;
  const float c = cosb[s * 32 + d];
  const float sn = sinb[s * 32 + d];
  float* qb = qall + (size_t)row * 3072 + h * HD + NOPE;
  float x0 = qb[2 * d], x1 = qb[2 * d + 1];
  qb[2 * d]     = x0 * c - x1 * sn;
  qb[2 * d + 1] = x0 * sn + x1 * c;
  if (tid < 32) {
    const float* kb = kvd + (size_t)row * 640 + 512;
    float y0 = kb[2 * d], y1 = kb[2 * d + 1];
    krope[(size_t)row * 64 + 2 * d]     = y0 * c - y1 * sn;
    krope[(size_t)row * 64 + 2 * d + 1] = y0 * sn + y1 * c;
  }
}

// ---------------- MFMA flash attention ----------------
// Grid 512 = b(2) x h(16) x tile(16); 256 threads = 4 waves x 32 q-rows.
// Round 7 changes:
//  * complementary tile pairing: b=1 half of grid reverses the tile map so the
//    presumed same-CU block pair (bx, bx+256) carries tiles t and 15-t
//    -> every CU gets 34 chunk-units of causal work instead of 4..64.
//  * T14 async-STAGE split: chunk c+1 global loads issue into registers before
//    chunk c's compute (K before QK^T, V after the P-write); cvt+LDS-write
//    happen after the post-compute barrier. sched_barrier(0) pins early issue.
//  * T5 s_setprio(1) around the QK^T and PV MFMA clusters.
#define QT 128
#define KC 64
__global__ __launch_bounds__(256, 2) void attn_k(const float* __restrict__ qall,
                                                 const float* __restrict__ kvu,
                                                 const float* __restrict__ krope,
                                                 ushort_t* __restrict__ outp) {
  const int bx = blockIdx.x;
  const int second = bx >> 8;
  const int h = (bx >> 4) & 15;
  int tile = bx & 15;
  if (second) tile = 15 - tile;       // complementary pairing across grid halves
  const int b = second;
  const int q0 = tile * QT;
  const int tid = threadIdx.x;
  const int lane = tid & 63;
  const int wq = tid >> 6;
  const int l15 = lane & 15, quad = lane >> 4;

  __shared__ ushort_t Kb[64 * 200];
  __shared__ ushort_t Vt[128 * 72];
  __shared__ ushort_t Pb[4][32 * 72];

  const int qbase = q0 + wq * 32;
  const size_t growq = (size_t)b * S_LEN + qbase;

  // Q fragments (bf16) in registers: [mt][ks]
  short8 qf[2][6];
#pragma unroll
  for (int mt = 0; mt < 2; ++mt)
#pragma unroll
    for (int ks = 0; ks < 6; ++ks) {
      const float* src = &qall[(growq + mt * 16 + l15) * 3072 + h * HD + ks * 32 + quad * 8];
      const float4 v0 = *(const float4*)src;
      const float4 v1 = *(const float4*)(src + 4);
      union { short8 s8; ushort_t u[8]; } pk;
      pk.u[0] = f2bf(v0.x); pk.u[1] = f2bf(v0.y); pk.u[2] = f2bf(v0.z); pk.u[3] = f2bf(v0.w);
      pk.u[4] = f2bf(v1.x); pk.u[5] = f2bf(v1.y); pk.u[6] = f2bf(v1.z); pk.u[7] = f2bf(v1.w);
      qf[mt][ks] = pk.s8;
    }

  f32x4 oacc[2][8] = {};
  float mrow[2][4], lrow[2][4];
  int q_r[2][4];
#pragma unroll
  for (int mt = 0; mt < 2; ++mt)
#pragma unroll
    for (int r = 0; r < 4; ++r) {
      mrow[mt][r] = -1e30f; lrow[mt][r] = 0.f;
      q_r[mt][r] = qbase + mt * 16 + quad * 4 + r;
    }

  const float scale = 0.07216878364870323f;  // 1/sqrt(192)
  const int nchunk = (q0 + QT) / KC;

  // ---- register staging buffers (chunk c+1 in flight during chunk c) ----
  float4 pkn[8];   // K nope  (64x128 f32 / 256 thr)
  float4 pkr[4];   // K rope  (64x64  f32 / 256 thr)
  float4 pv[8];    // V       (64x128 f32 / 256 thr)

  auto load_K = [&](int c) {
    const size_t growk = (size_t)b * S_LEN + c * KC;
#pragma unroll
    for (int it = 0; it < 4; ++it) {
      const int i = tid + (it << 8);
      const int key = i >> 4, dg = i & 15;
      const float* p = &kvu[(growk + key) * 4096 + h * 256 + dg * 8];
      pkn[2 * it]     = *(const float4*)p;
      pkn[2 * it + 1] = *(const float4*)(p + 4);
    }
#pragma unroll
    for (int it = 0; it < 2; ++it) {
      const int i = tid + (it << 8);
      const int key = i >> 3, dg = i & 7;
      const float* p = &krope[(growk + key) * 64 + dg * 8];
      pkr[2 * it]     = *(const float4*)p;
      pkr[2 * it + 1] = *(const float4*)(p + 4);
    }
  };
  auto load_V = [&](int c) {
    const size_t growk = (size_t)b * S_LEN + c * KC;
#pragma unroll
    for (int it = 0; it < 8; ++it) {
      const int i = tid + (it << 8);
      const int key = i >> 5, vg = i & 31;
      pv[it] = *(const float4*)&kvu[(growk + key) * 4096 + h * 256 + 128 + vg * 4];
    }
  };
  auto write_KV = [&]() {
#pragma unroll
    for (int it = 0; it < 4; ++it) {
      const int i = tid + (it << 8);
      const int key = i >> 4, dg = i & 15;
      const float4 v0 = pkn[2 * it], v1 = pkn[2 * it + 1];
      union { uint4 u; ushort_t s[8]; } pk;
      pk.s[0] = f2bf(v0.x); pk.s[1] = f2bf(v0.y); pk.s[2] = f2bf(v0.z); pk.s[3] = f2bf(v0.w);
      pk.s[4] = f2bf(v1.x); pk.s[5] = f2bf(v1.y); pk.s[6] = f2bf(v1.z); pk.s[7] = f2bf(v1.w);
      *(uint4*)&Kb[key * 200 + dg * 8] = pk.u;
    }
#pragma unroll
    for (int it = 0; it < 2; ++it) {
      const int i = tid + (it << 8);
      const int key = i >> 3, dg = i & 7;
      const float4 v0 = pkr[2 * it], v1 = pkr[2 * it + 1];
      union { uint4 u; ushort_t s[8]; } pk;
      pk.s[0] = f2bf(v0.x); pk.s[1] = f2bf(v0.y); pk.s[2] = f2bf(v0.z); pk.s[3] = f2bf(v0.w);
      pk.s[4] = f2bf(v1.x); pk.s[5] = f2bf(v1.y); pk.s[6] = f2bf(v1.z); pk.s[7] = f2bf(v1.w);
      *(uint4*)&Kb[key * 200 + 128 + dg * 8] = pk.u;
    }
#pragma unroll
    for (int it = 0; it < 8; ++it) {
      const int i = tid + (it << 8);
      const int key = i >> 5, vg = i & 31;
      const float4 v = pv[it];
      Vt[(vg * 4 + 0) * 72 + key] = f2bf(v.x);
      Vt[(vg * 4 + 1) * 72 + key] = f2bf(v.y);
      Vt[(vg * 4 + 2) * 72 + key] = f2bf(v.z);
      Vt[(vg * 4 + 3) * 72 + key] = f2bf(v.w);
    }
  };

  // ---- prologue: stage chunk 0 ----
  load_K(0);
  load_V(0);
  write_KV();
  __syncthreads();

  for (int c = 0; c < nchunk; ++c) {
    const int j0 = c * KC;
    const bool more = (c + 1 < nchunk);

    // issue next chunk's K loads; latency hides under QK^T + softmax
    if (more) {
      load_K(c + 1);
      __builtin_amdgcn_sched_barrier(0);
    }

    // ---- QK^T ----
    f32x4 sacc[2][4] = {};
    __builtin_amdgcn_s_setprio(1);
#pragma unroll
    for (int ks = 0; ks < 6; ++ks) {
      short8 kf[4];
#pragma unroll
      for (int kt = 0; kt < 4; ++kt)
        kf[kt] = *(const short8*)&Kb[(kt * 16 + l15) * 200 + ks * 32 + quad * 8];
#pragma unroll
      for (int mt = 0; mt < 2; ++mt)
#pragma unroll
        for (int kt = 0; kt < 4; ++kt)
          sacc[mt][kt] = __builtin_amdgcn_mfma_f32_16x16x32_bf16(qf[mt][ks], kf[kt], sacc[mt][kt], 0, 0, 0);
    }
    __builtin_amdgcn_s_setprio(0);

    // ---- mask + scale (in place) ----
#pragma unroll
    for (int mt = 0; mt < 2; ++mt)
#pragma unroll
      for (int kt = 0; kt < 4; ++kt) {
        const int key = j0 + kt * 16 + l15;
#pragma unroll
        for (int r = 0; r < 4; ++r)
          sacc[mt][kt][r] = (key <= q_r[mt][r]) ? sacc[mt][kt][r] * scale : -1e30f;
      }
    // ---- online softmax (wave-internal, per quad group) ----
    float alpha[2][4];
#pragma unroll
    for (int mt = 0; mt < 2; ++mt)
#pragma unroll
      for (int r = 0; r < 4; ++r) {
        float mx = fmaxf(fmaxf(sacc[mt][0][r], sacc[mt][1][r]),
                         fmaxf(sacc[mt][2][r], sacc[mt][3][r]));
        mx = fmaxf(mx, __shfl_xor(mx, 1));
        mx = fmaxf(mx, __shfl_xor(mx, 2));
        mx = fmaxf(mx, __shfl_xor(mx, 4));
        mx = fmaxf(mx, __shfl_xor(mx, 8));
        const float mn = fmaxf(mrow[mt][r], mx);
        alpha[mt][r] = __expf(mrow[mt][r] - mn);
        mrow[mt][r] = mn;
      }
#pragma unroll
    for (int mt = 0; mt < 2; ++mt)
#pragma unroll
      for (int kt = 0; kt < 4; ++kt)
#pragma unroll
        for (int r = 0; r < 4; ++r)
          sacc[mt][kt][r] = __expf(sacc[mt][kt][r] - mrow[mt][r]);
#pragma unroll
    for (int mt = 0; mt < 2; ++mt)
#pragma unroll
      for (int r = 0; r < 4; ++r) {
        float rs = sacc[mt][0][r] + sacc[mt][1][r] + sacc[mt][2][r] + sacc[mt][3][r];
        rs += __shfl_xor(rs, 1);
        rs += __shfl_xor(rs, 2);
        rs += __shfl_xor(rs, 4);
        rs += __shfl_xor(rs, 8);
        lrow[mt][r] = lrow[mt][r] * alpha[mt][r] + rs;
      }
    // ---- write P (bf16) to per-wave-private LDS ----
#pragma unroll
    for (int mt = 0; mt < 2; ++mt)
#pragma unroll
      for (int kt = 0; kt < 4; ++kt)
#pragma unroll
        for (int r = 0; r < 4; ++r)
          Pb[wq][(mt * 16 + quad * 4 + r) * 72 + kt * 16 + l15] = f2bf(sacc[mt][kt][r]);

    // issue next chunk's V loads; latency hides under rescale + PV
    if (more) {
      load_V(c + 1);
      __builtin_amdgcn_sched_barrier(0);
    }

    // ---- rescale O ----
#pragma unroll
    for (int mt = 0; mt < 2; ++mt)
#pragma unroll
      for (int nt = 0; nt < 8; ++nt)
#pragma unroll
        for (int r = 0; r < 4; ++r)
          oacc[mt][nt][r] *= alpha[mt][r];
    // ---- PV ----
    __builtin_amdgcn_s_setprio(1);
#pragma unroll
    for (int st = 0; st < 2; ++st) {
      short8 pf[2];
#pragma unroll
      for (int mt = 0; mt < 2; ++mt)
        pf[mt] = *(const short8*)&Pb[wq][(mt * 16 + l15) * 72 + st * 32 + quad * 8];
#pragma unroll
      for (int nt = 0; nt < 8; ++nt) {
        const short8 vf = *(const short8*)&Vt[(nt * 16 + l15) * 72 + st * 32 + quad * 8];
#pragma unroll
        for (int mt = 0; mt < 2; ++mt)
          oacc[mt][nt] = __builtin_amdgcn_mfma_f32_16x16x32_bf16(pf[mt], vf, oacc[mt][nt], 0, 0, 0);
      }
    }
    __builtin_amdgcn_s_setprio(0);

    __syncthreads();          // all waves done reading Kb/Vt for chunk c
    if (more) write_KV();     // cvt + LDS write for chunk c+1 (vmcnt drains here)
    __syncthreads();
  }

  // ---- store (bf16) ----
#pragma unroll
  for (int mt = 0; mt < 2; ++mt)
#pragma unroll
    for (int r = 0; r < 4; ++r) {
      const float inv = 1.0f / lrow[mt][r];
      const size_t orow = growq + mt * 16 + quad * 4 + r;
#pragma unroll
      for (int nt = 0; nt < 8; ++nt)
        outp[orow * 2048 + h * 128 + nt * 16 + l15] = f2bf(oacc[mt][nt][r] * inv);
    }
}

extern "C" void kernel_launch(void* const* d_in, const int* in_sizes, int n_in,
                              void* d_out, int out_size, void* d_ws, size_t ws_size,
                              hipStream_t stream) {
  const float* x        = (const float*)d_in[0];
  const float* wd_q     = (const float*)d_in[1];
  const float* wu_q     = (const float*)d_in[2];
  const float* q_norm_w = (const float*)d_in[3];
  const float* wd_kv    = (const float*)d_in[4];
  const float* wu_kv    = (const float*)d_in[5];
  const float* kv_norm_w= (const float*)d_in[6];
  const float* wo       = (const float*)d_in[7];
  const float* cosb     = (const float*)d_in[8];
  const float* sinb     = (const float*)d_in[9];
  float* out = (float*)d_out;

  char* ws = (char*)d_ws;
  float*    qall  = (float*)(ws + 0);            // 4096x3072 f32; cq aliases @0
  float*    cq    = (float*)(ws + 0);
  float*    kvu   = (float*)(ws + 50331648);     // 4096x4096 f32
  ushort_t* cqn   = (ushort_t*)(ws + 117440512); // 4096x1536 bf16
  float*    kvd   = (float*)(ws + 130023424);    // 4096x640 f32 (dead after rope)
  ushort_t* ckvn  = (ushort_t*)(ws + 140509184); // 4096x512 bf16 (dead after kvu gemm)
  ushort_t* aoutb = (ushort_t*)(ws + 130023424); // 4096x2048 bf16, aliases kvd+ckvn
  float*    krope = (float*)(ws + 146800640);    // 4096x64 f32
  ushort_t* wdqt  = (ushort_t*)(ws + 147849216); // 1536x2048 bf16
  ushort_t* wdkvt = (ushort_t*)(ws + 154140672); // 640x2048 bf16
  ushort_t* wuqt  = (ushort_t*)(ws + 156762112); // 3072x1536 bf16
  ushort_t* wukvt = (ushort_t*)(ws + 166199296); // 4096x512 bf16
  ushort_t* wot   = (ushort_t*)(ws + 170393600); // 2048x2048 bf16

  const int M = 2 * S_LEN;  // 4096
  dim3 blk(256);

  transpose_cast_k<<<dim3(1536 / 32, 2048 / 32), blk, 0, stream>>>(wd_q, wdqt, 2048, 1536);
  transpose_cast_k<<<dim3(640 / 32, 2048 / 32), blk, 0, stream>>>(wd_kv, wdkvt, 2048, 576);
  transpose_cast_k<<<dim3(3072 / 32, 1536 / 32), blk, 0, stream>>>(wu_q, wuqt, 1536, 3072);
  transpose_cast_k<<<dim3(4096 / 32, 512 / 32), blk, 0, stream>>>(wu_kv, wukvt, 512, 4096);
  transpose_cast_k<<<dim3(2048 / 32, 2048 / 32), blk, 0, stream>>>(wo, wot, 2048, 2048);

  mfma_gemm<true><<<dim3(1536 / 128, M / 128), blk, 0, stream>>>(x, wdqt, cq, M, 1536, 2048, 1536);
  mfma_gemm<true><<<dim3(640 / 128, M / 128), blk, 0, stream>>>(x, wdkvt, kvd, M, 640, 2048, 640);
  rmsnorm_k<<<M, 256, 0, stream>>>(cq, 1536, cqn, 1536, q_norm_w, 1536);
  rmsnorm_k<<<M, 256, 0, stream>>>(kvd, 640, ckvn, 512, kv_norm_w, 512);
  mfma_gemm<false><<<dim3(3072 / 128, M / 128), blk, 0, stream>>>(cqn, wuqt, qall, M, 3072, 1536, 3072);
  mfma_gemm<false><<<dim3(4096 / 128, M / 128), blk, 0, stream>>>(ckvn, wukvt, kvu, M, 4096, 512, 4096);
  rope_k<<<M, 512, 0, stream>>>(qall, kvd, krope, cosb, sinb);
  attn_k<<<2 * NHEAD * (S_LEN / QT), 256, 0, stream>>>(qall, kvu, krope, aoutb);
  mfma_gemm<false><<<dim3(2048 / 128, M / 128), blk, 0, stream>>>(aoutb, wot, out, M, 2048, 2048, 2048);
}

// Round 2
// 589.103 us; speedup vs baseline: 1.4826x; 1.4826x over previous
//
#include <hip/hip_runtime.h>
#include <hip/hip_bf16.h>

#define S_LEN 2048
#define NHEAD 16
#define NOPE 128
#define ROPE 64
#define HD 192   // nope + rope

typedef unsigned short ushort_t;
typedef __attribute__((ext_vector_type(8))) short short8;
typedef __attribute__((ext_vector_type(4))) float f32x4;

__device__ __forceinline__ unsigned short f2bf(float f) {
  unsigned int u = __float_as_uint(f);
  return (unsigned short)((u + 0x7FFFu + ((u >> 16) & 1u)) >> 16);
}

// ---------------- transpose + cast: B f32 [K][N] -> Bt bf16 [Npad][K] ----------------
__global__ __launch_bounds__(256) void transpose_cast_k(const float* __restrict__ B,
                                                        ushort_t* __restrict__ Bt,
                                                        int K, int N) {
  __shared__ float tile[32][33];
  const int tx = threadIdx.x & 31, ty = threadIdx.x >> 5;  // 32 x 8
  const int n0 = blockIdx.x * 32, k0 = blockIdx.y * 32;
  if (n0 >= N) {
#pragma unroll
    for (int r = 0; r < 4; ++r)
      Bt[(size_t)(n0 + ty + 8 * r) * K + k0 + tx] = 0;
    return;
  }
#pragma unroll
  for (int r = 0; r < 4; ++r)
    tile[ty + 8 * r][tx] = B[(size_t)(k0 + ty + 8 * r) * N + n0 + tx];
  __syncthreads();
#pragma unroll
  for (int r = 0; r < 4; ++r)
    Bt[(size_t)(n0 + ty + 8 * r) * K + k0 + tx] = f2bf(tile[tx][ty + 8 * r]);
}

// ---------------- MFMA GEMM ----------------
// EPI=0: f32 row-major C.
// EPI=1: KV split epilogue for the kvu GEMM (N=4096 = 16 heads x [128 K | 128 V]):
//        K half  -> kb16[token][h*128+d]  (bf16, row-major)
//        V half  -> vT[(b*16+h)*128 + vd][token] (bf16, transposed via LDS)
template<bool A_IS_F32, int EPI>
__global__ __launch_bounds__(256) void mfma_gemm(const void* __restrict__ Av,
                                                 const ushort_t* __restrict__ Bt,
                                                 float* __restrict__ C,
                                                 int M, int N, int K, int ldc,
                                                 ushort_t* __restrict__ kb16o,
                                                 ushort_t* __restrict__ vto) {
  __shared__ ushort_t As[128 * 32];
  __shared__ ushort_t Bs[128 * 32];
  const int tid = threadIdx.x;
  const int lane = tid & 63;
  const int wave = tid >> 6;
  const int wm = wave & 1, wn = wave >> 1;
  const int m0 = blockIdx.y * 128, n0 = blockIdx.x * 128;
  const int l15 = lane & 15, quad = lane >> 4;

  f32x4 acc[4][4] = {};

  const int it0 = tid, it1 = tid + 256;
  const int ma0 = it0 >> 2, kc0 = it0 & 3;
  const int ma1 = it1 >> 2, kc1 = it1 & 3;

  for (int k0 = 0; k0 < K; k0 += 32) {
    if (A_IS_F32) {
      const float* Af = (const float*)Av;
      {
        const float4 v0 = *(const float4*)&Af[(size_t)(m0 + ma0) * K + k0 + kc0 * 8];
        const float4 v1 = *(const float4*)&Af[(size_t)(m0 + ma0) * K + k0 + kc0 * 8 + 4];
        union { uint4 u; ushort_t s[8]; } pk;
        pk.s[0] = f2bf(v0.x); pk.s[1] = f2bf(v0.y); pk.s[2] = f2bf(v0.z); pk.s[3] = f2bf(v0.w);
        pk.s[4] = f2bf(v1.x); pk.s[5] = f2bf(v1.y); pk.s[6] = f2bf(v1.z); pk.s[7] = f2bf(v1.w);
        *(uint4*)&As[it0 * 8] = pk.u;
      }
      {
        const float4 v0 = *(const float4*)&Af[(size_t)(m0 + ma1) * K + k0 + kc1 * 8];
        const float4 v1 = *(const float4*)&Af[(size_t)(m0 + ma1) * K + k0 + kc1 * 8 + 4];
        union { uint4 u; ushort_t s[8]; } pk;
        pk.s[0] = f2bf(v0.x); pk.s[1] = f2bf(v0.y); pk.s[2] = f2bf(v0.z); pk.s[3] = f2bf(v0.w);
        pk.s[4] = f2bf(v1.x); pk.s[5] = f2bf(v1.y); pk.s[6] = f2bf(v1.z); pk.s[7] = f2bf(v1.w);
        *(uint4*)&As[it1 * 8] = pk.u;
      }
    } else {
      const ushort_t* Ab = (const ushort_t*)Av;
      *(uint4*)&As[it0 * 8] = *(const uint4*)&Ab[(size_t)(m0 + ma0) * K + k0 + kc0 * 8];
      *(uint4*)&As[it1 * 8] = *(const uint4*)&Ab[(size_t)(m0 + ma1) * K + k0 + kc1 * 8];
    }
    *(uint4*)&Bs[it0 * 8] = *(const uint4*)&Bt[(size_t)(n0 + ma0) * K + k0 + kc0 * 8];
    *(uint4*)&Bs[it1 * 8] = *(const uint4*)&Bt[(size_t)(n0 + ma1) * K + k0 + kc1 * 8];
    __syncthreads();

    short8 af[4], bf[4];
#pragma unroll
    for (int i = 0; i < 4; ++i)
      af[i] = *(const short8*)&As[(wm * 64 + i * 16 + l15) * 32 + quad * 8];
#pragma unroll
    for (int j = 0; j < 4; ++j)
      bf[j] = *(const short8*)&Bs[(wn * 64 + j * 16 + l15) * 32 + quad * 8];
#pragma unroll
    for (int i = 0; i < 4; ++i)
#pragma unroll
      for (int j = 0; j < 4; ++j)
        acc[i][j] = __builtin_amdgcn_mfma_f32_16x16x32_bf16(af[i], bf[j], acc[i][j], 0, 0, 0);
    __syncthreads();
  }

  if constexpr (EPI == 0) {
#pragma unroll
    for (int i = 0; i < 4; ++i)
#pragma unroll
      for (int r = 0; r < 4; ++r) {
        const size_t rg = (size_t)(m0 + wm * 64 + i * 16 + quad * 4 + r);
#pragma unroll
        for (int j = 0; j < 4; ++j)
          C[rg * ldc + n0 + wn * 64 + j * 16 + l15] = acc[i][j][r];
      }
  } else {
    const int h = n0 >> 8;
    const bool is_v = (n0 >> 7) & 1;
    if (!is_v) {
      // K half: bf16 row-major kb16[token][h*128 + d]
#pragma unroll
      for (int i = 0; i < 4; ++i)
#pragma unroll
        for (int r = 0; r < 4; ++r) {
          const size_t rg = (size_t)(m0 + wm * 64 + i * 16 + quad * 4 + r);
#pragma unroll
          for (int j = 0; j < 4; ++j)
            kb16o[rg * 2048 + h * 128 + wn * 64 + j * 16 + l15] = f2bf(acc[i][j][r]);
        }
    } else {
      // V half: transpose to vT[(b*16+h)*128 + vd][token] via LDS
      __shared__ __align__(16) ushort_t trb[64 * 136];
      const int bb = m0 >> 11;            // batch index
      const int m0loc = m0 & 2047;        // token offset within batch
      ushort_t* vbase = vto + ((size_t)(bb * NHEAD + h) * 128) * 2048;
#pragma unroll
      for (int vh = 0; vh < 2; ++vh) {
        if (wn == vh) {
#pragma unroll
          for (int i = 0; i < 4; ++i)
#pragma unroll
            for (int r = 0; r < 4; ++r) {
              const int tloc = wm * 64 + i * 16 + quad * 4 + r;   // 0..127
#pragma unroll
              for (int j = 0; j < 4; ++j)
                trb[(j * 16 + l15) * 136 + tloc] = f2bf(acc[i][j][r]);
            }
        }
        __syncthreads();
        // cooperative coalesced write: 64 vd rows x 128 tokens (16B chunks)
#pragma unroll
        for (int it = 0; it < 4; ++it) {
          const int u = tid + (it << 8);
          const int vdl = u >> 4, tc = u & 15;
          *(uint4*)&vbase[(size_t)(vh * 64 + vdl) * 2048 + m0loc + tc * 8] =
              *(const uint4*)&trb[vdl * 136 + tc * 8];
        }
        __syncthreads();
      }
    }
  }
}

// ---------------- RMSNorm: f32 in -> bf16 out ----------------
__global__ __launch_bounds__(256) void rmsnorm_k(const float* __restrict__ in, int in_stride,
                                                 ushort_t* __restrict__ out, int out_stride,
                                                 const float* __restrict__ w, int L) {
  const int row = blockIdx.x;
  const int tid = threadIdx.x;
  const float* ip = in + (size_t)row * in_stride;
  ushort_t* op = out + (size_t)row * out_stride;
  const int nper = L >> 8;
  float r[6];
  float ss = 0.f;
  for (int j = 0; j < nper; ++j) {
    r[j] = ip[tid + (j << 8)];
    ss += r[j] * r[j];
  }
  for (int off = 32; off; off >>= 1) ss += __shfl_down(ss, off);
  __shared__ float wsum[4];
  __shared__ float scale_s;
  if ((tid & 63) == 0) wsum[tid >> 6] = ss;
  __syncthreads();
  if (tid == 0) {
    float t = wsum[0] + wsum[1] + wsum[2] + wsum[3];
    scale_s = rsqrtf(t / (float)L + 1e-5f);
  }
  __syncthreads();
  const float sc = scale_s;
  for (int j = 0; j < nper; ++j)
    op[tid + (j << 8)] = f2bf(r[j] * sc * w[tid + (j << 8)]);
}

// ---------------- RoPE (krope emitted as bf16) ----------------
__global__ __launch_bounds__(512) void rope_k(float* __restrict__ qall,
                                              const float* __restrict__ kvd,
                                              ushort_t* __restrict__ krope16,
                                              const float* __restrict__ cosb,
                                              const float* __restrict__ sinb) {
  const int row = blockIdx.x;
  const int s = row & (S_LEN - 1);
  const int tid = threadIdx.x;
  const int d = tid & 31, h = tid >> 5;
  const float c = cosb[s * 32 + d];
  const float sn = sinb[s * 32 + d];
  float* qb = qall + (size_t)row * 3072 + h * HD + NOPE;
  float x0 = qb[2 * d], x1 = qb[2 * d + 1];
  qb[2 * d]     = x0 * c - x1 * sn;
  qb[2 * d + 1] = x0 * sn + x1 * c;
  if (tid < 32) {
    const float* kb = kvd + (size_t)row * 640 + 512;
    float y0 = kb[2 * d], y1 = kb[2 * d + 1];
    union { unsigned int u; ushort_t s2[2]; } pk;
    pk.s2[0] = f2bf(y0 * c - y1 * sn);
    pk.s2[1] = f2bf(y0 * sn + y1 * c);
    *(unsigned int*)&krope16[(size_t)row * 64 + 2 * d] = pk.u;
  }
}

// ---------------- MFMA flash attention ----------------
// Grid 512 = b(2) x h(16) x tile(16); 256 threads = 4 waves x 32 q-rows.
// K/V/krope arrive pre-cast to bf16 (and V pre-transposed) from the producers,
// so per-chunk staging is pure uint4 copies: no cvt VALU, no scalar transpose
// writes (round-0's 16-way bank conflict source), half the staged bytes.
// Complementary tile pairing across the two grid halves balances causal work.
#define QT 128
#define KC 64
__global__ __launch_bounds__(256, 2) void attn_k(const float* __restrict__ qall,
                                                 const ushort_t* __restrict__ kb16,
                                                 const ushort_t* __restrict__ vT,
                                                 const ushort_t* __restrict__ krope16,
                                                 ushort_t* __restrict__ outp) {
  const int bx = blockIdx.x;
  const int second = bx >> 8;
  const int h = (bx >> 4) & 15;
  int tile = bx & 15;
  if (second) tile = 15 - tile;       // complementary pairing across grid halves
  const int b = second;
  const int q0 = tile * QT;
  const int tid = threadIdx.x;
  const int lane = tid & 63;
  const int wq = tid >> 6;
  const int l15 = lane & 15, quad = lane >> 4;

  __shared__ ushort_t Kb[64 * 200];
  __shared__ ushort_t Vt[128 * 72];
  __shared__ ushort_t Pb[4][32 * 72];

  const int qbase = q0 + wq * 32;
  const size_t growq = (size_t)b * S_LEN + qbase;
  const ushort_t* vTh = vT + ((size_t)(b * NHEAD + h) * 128) * 2048;

  // Q fragments (bf16) in registers: [mt][ks]
  short8 qf[2][6];
#pragma unroll
  for (int mt = 0; mt < 2; ++mt)
#pragma unroll
    for (int ks = 0; ks < 6; ++ks) {
      const float* src = &qall[(growq + mt * 16 + l15) * 3072 + h * HD + ks * 32 + quad * 8];
      const float4 v0 = *(const float4*)src;
      const float4 v1 = *(const float4*)(src + 4);
      union { short8 s8; ushort_t u[8]; } pk;
      pk.u[0] = f2bf(v0.x); pk.u[1] = f2bf(v0.y); pk.u[2] = f2bf(v0.z); pk.u[3] = f2bf(v0.w);
      pk.u[4] = f2bf(v1.x); pk.u[5] = f2bf(v1.y); pk.u[6] = f2bf(v1.z); pk.u[7] = f2bf(v1.w);
      qf[mt][ks] = pk.s8;
    }

  f32x4 oacc[2][8] = {};
  float mrow[2][4], lrow[2][4];
  int q_r[2][4];
#pragma unroll
  for (int mt = 0; mt < 2; ++mt)
#pragma unroll
    for (int r = 0; r < 4; ++r) {
      mrow[mt][r] = -1e30f; lrow[mt][r] = 0.f;
      q_r[mt][r] = qbase + mt * 16 + quad * 4 + r;
    }

  const float scale = 0.07216878364870323f;  // 1/sqrt(192)
  const int nchunk = (q0 + QT) / KC;

  for (int c = 0; c < nchunk; ++c) {
    const int j0 = c * KC;
    const size_t growk = (size_t)b * S_LEN + j0;
    __syncthreads();
    // ---- stage K nope (64 keys x 16 chunks of 16B) ----
#pragma unroll
    for (int it = 0; it < 4; ++it) {
      const int u = tid + (it << 8);
      const int key = u >> 4, dg = u & 15;
      *(uint4*)&Kb[key * 200 + dg * 8] =
          *(const uint4*)&kb16[(growk + key) * 2048 + h * 128 + dg * 8];
    }
    // ---- stage K rope (64 keys x 8 chunks) ----
#pragma unroll
    for (int it = 0; it < 2; ++it) {
      const int u = tid + (it << 8);
      const int key = u >> 3, dg = u & 7;
      *(uint4*)&Kb[key * 200 + 128 + dg * 8] =
          *(const uint4*)&krope16[(growk + key) * 64 + dg * 8];
    }
    // ---- stage V^T (128 vd rows x 8 chunks of 8 keys) ----
#pragma unroll
    for (int it = 0; it < 4; ++it) {
      const int u = tid + (it << 8);
      const int vd = u >> 3, kc = u & 7;
      *(uint4*)&Vt[vd * 72 + kc * 8] =
          *(const uint4*)&vTh[(size_t)vd * 2048 + j0 + kc * 8];
    }
    __syncthreads();

    // ---- QK^T ----
    f32x4 sacc[2][4] = {};
    __builtin_amdgcn_s_setprio(1);
#pragma unroll
    for (int ks = 0; ks < 6; ++ks) {
      short8 kf[4];
#pragma unroll
      for (int kt = 0; kt < 4; ++kt)
        kf[kt] = *(const short8*)&Kb[(kt * 16 + l15) * 200 + ks * 32 + quad * 8];
#pragma unroll
      for (int mt = 0; mt < 2; ++mt)
#pragma unroll
        for (int kt = 0; kt < 4; ++kt)
          sacc[mt][kt] = __builtin_amdgcn_mfma_f32_16x16x32_bf16(qf[mt][ks], kf[kt], sacc[mt][kt], 0, 0, 0);
    }
    __builtin_amdgcn_s_setprio(0);

    // ---- mask + scale (in place) ----
#pragma unroll
    for (int mt = 0; mt < 2; ++mt)
#pragma unroll
      for (int kt = 0; kt < 4; ++kt) {
        const int key = j0 + kt * 16 + l15;
#pragma unroll
        for (int r = 0; r < 4; ++r)
          sacc[mt][kt][r] = (key <= q_r[mt][r]) ? sacc[mt][kt][r] * scale : -1e30f;
      }
    // ---- online softmax (wave-internal, per quad group) ----
    float alpha[2][4];
#pragma unroll
    for (int mt = 0; mt < 2; ++mt)
#pragma unroll
      for (int r = 0; r < 4; ++r) {
        float mx = fmaxf(fmaxf(sacc[mt][0][r], sacc[mt][1][r]),
                         fmaxf(sacc[mt][2][r], sacc[mt][3][r]));
        mx = fmaxf(mx, __shfl_xor(mx, 1));
        mx = fmaxf(mx, __shfl_xor(mx, 2));
        mx = fmaxf(mx, __shfl_xor(mx, 4));
        mx = fmaxf(mx, __shfl_xor(mx, 8));
        const float mn = fmaxf(mrow[mt][r], mx);
        alpha[mt][r] = __expf(mrow[mt][r] - mn);
        mrow[mt][r] = mn;
      }
#pragma unroll
    for (int mt = 0; mt < 2; ++mt)
#pragma unroll
      for (int kt = 0; kt < 4; ++kt)
#pragma unroll
        for (int r = 0; r < 4; ++r)
          sacc[mt][kt][r] = __expf(sacc[mt][kt][r] - mrow[mt][r]);
#pragma unroll
    for (int mt = 0; mt < 2; ++mt)
#pragma unroll
      for (int r = 0; r < 4; ++r) {
        float rs = sacc[mt][0][r] + sacc[mt][1][r] + sacc[mt][2][r] + sacc[mt][3][r];
        rs += __shfl_xor(rs, 1);
        rs += __shfl_xor(rs, 2);
        rs += __shfl_xor(rs, 4);
        rs += __shfl_xor(rs, 8);
        lrow[mt][r] = lrow[mt][r] * alpha[mt][r] + rs;
      }
    // ---- write P (bf16) to per-wave-private LDS ----
#pragma unroll
    for (int mt = 0; mt < 2; ++mt)
#pragma unroll
      for (int kt = 0; kt < 4; ++kt)
#pragma unroll
        for (int r = 0; r < 4; ++r)
          Pb[wq][(mt * 16 + quad * 4 + r) * 72 + kt * 16 + l15] = f2bf(sacc[mt][kt][r]);
    // ---- rescale O ----
#pragma unroll
    for (int mt = 0; mt < 2; ++mt)
#pragma unroll
      for (int nt = 0; nt < 8; ++nt)
#pragma unroll
        for (int r = 0; r < 4; ++r)
          oacc[mt][nt][r] *= alpha[mt][r];
    // ---- PV ----
    __builtin_amdgcn_s_setprio(1);
#pragma unroll
    for (int st = 0; st < 2; ++st) {
      short8 pf[2];
#pragma unroll
      for (int mt = 0; mt < 2; ++mt)
        pf[mt] = *(const short8*)&Pb[wq][(mt * 16 + l15) * 72 + st * 32 + quad * 8];
#pragma unroll
      for (int nt = 0; nt < 8; ++nt) {
        const short8 vf = *(const short8*)&Vt[(nt * 16 + l15) * 72 + st * 32 + quad * 8];
#pragma unroll
        for (int mt = 0; mt < 2; ++mt)
          oacc[mt][nt] = __builtin_amdgcn_mfma_f32_16x16x32_bf16(pf[mt], vf, oacc[mt][nt], 0, 0, 0);
      }
    }
    __builtin_amdgcn_s_setprio(0);
  }

  // ---- store (bf16) ----
#pragma unroll
  for (int mt = 0; mt < 2; ++mt)
#pragma unroll
    for (int r = 0; r < 4; ++r) {
      const float inv = 1.0f / lrow[mt][r];
      const size_t orow = growq + mt * 16 + quad * 4 + r;
#pragma unroll
      for (int nt = 0; nt < 8; ++nt)
        outp[orow * 2048 + h * 128 + nt * 16 + l15] = f2bf(oacc[mt][nt][r] * inv);
    }
}

extern "C" void kernel_launch(void* const* d_in, const int* in_sizes, int n_in,
                              void* d_out, int out_size, void* d_ws, size_t ws_size,
                              hipStream_t stream) {
  const float* x        = (const float*)d_in[0];
  const float* wd_q     = (const float*)d_in[1];
  const float* wu_q     = (const float*)d_in[2];
  const float* q_norm_w = (const float*)d_in[3];
  const float* wd_kv    = (const float*)d_in[4];
  const float* wu_kv    = (const float*)d_in[5];
  const float* kv_norm_w= (const float*)d_in[6];
  const float* wo       = (const float*)d_in[7];
  const float* cosb     = (const float*)d_in[8];
  const float* sinb     = (const float*)d_in[9];
  float* out = (float*)d_out;

  char* ws = (char*)d_ws;
  float*    qall  = (float*)(ws + 0);            // 4096x3072 f32; cq aliases @0
  float*    cq    = (float*)(ws + 0);
  ushort_t* kb16  = (ushort_t*)(ws + 50331648);  // 4096x2048 bf16 K rows (16MB)
  ushort_t* vT    = (ushort_t*)(ws + 67108864);  // [b*16+h][128 vd][2048 tok] bf16 (16MB)
  ushort_t* cqn   = (ushort_t*)(ws + 117440512); // 4096x1536 bf16
  float*    kvd   = (float*)(ws + 130023424);    // 4096x640 f32 (dead after rope)
  ushort_t* ckvn  = (ushort_t*)(ws + 140509184); // 4096x512 bf16 (dead after kvu gemm)
  ushort_t* aoutb = (ushort_t*)(ws + 130023424); // 4096x2048 bf16, aliases kvd+ckvn
  ushort_t* krope16 = (ushort_t*)(ws + 146800640); // 4096x64 bf16
  ushort_t* wdqt  = (ushort_t*)(ws + 147849216); // 1536x2048 bf16
  ushort_t* wdkvt = (ushort_t*)(ws + 154140672); // 640x2048 bf16
  ushort_t* wuqt  = (ushort_t*)(ws + 156762112); // 3072x1536 bf16
  ushort_t* wukvt = (ushort_t*)(ws + 166199296); // 4096x512 bf16
  ushort_t* wot   = (ushort_t*)(ws + 170393600); // 2048x2048 bf16

  const int M = 2 * S_LEN;  // 4096
  dim3 blk(256);

  transpose_cast_k<<<dim3(1536 / 32, 2048 / 32), blk, 0, stream>>>(wd_q, wdqt, 2048, 1536);
  transpose_cast_k<<<dim3(640 / 32, 2048 / 32), blk, 0, stream>>>(wd_kv, wdkvt, 2048, 576);
  transpose_cast_k<<<dim3(3072 / 32, 1536 / 32), blk, 0, stream>>>(wu_q, wuqt, 1536, 3072);
  transpose_cast_k<<<dim3(4096 / 32, 512 / 32), blk, 0, stream>>>(wu_kv, wukvt, 512, 4096);
  transpose_cast_k<<<dim3(2048 / 32, 2048 / 32), blk, 0, stream>>>(wo, wot, 2048, 2048);

  mfma_gemm<true, 0><<<dim3(1536 / 128, M / 128), blk, 0, stream>>>(
      x, wdqt, cq, M, 1536, 2048, 1536, nullptr, nullptr);
  mfma_gemm<true, 0><<<dim3(640 / 128, M / 128), blk, 0, stream>>>(
      x, wdkvt, kvd, M, 640, 2048, 640, nullptr, nullptr);
  rmsnorm_k<<<M, 256, 0, stream>>>(cq, 1536, cqn, 1536, q_norm_w, 1536);
  rmsnorm_k<<<M, 256, 0, stream>>>(kvd, 640, ckvn, 512, kv_norm_w, 512);
  mfma_gemm<false, 0><<<dim3(3072 / 128, M / 128), blk, 0, stream>>>(
      cqn, wuqt, qall, M, 3072, 1536, 3072, nullptr, nullptr);
  mfma_gemm<false, 1><<<dim3(4096 / 128, M / 128), blk, 0, stream>>>(
      ckvn, wukvt, nullptr, M, 4096, 512, 0, kb16, vT);
  rope_k<<<M, 512, 0, stream>>>(qall, kvd, krope16, cosb, sinb);
  attn_k<<<2 * NHEAD * (S_LEN / QT), 256, 0, stream>>>(qall, kb16, vT, krope16, aoutb);
  mfma_gemm<false, 0><<<dim3(2048 / 128, M / 128), blk, 0, stream>>>(
      aoutb, wot, out, M, 2048, 2048, 2048, nullptr, nullptr);
}

// Round 3
// 585.306 us; speedup vs baseline: 1.4922x; 1.0065x over previous
//
#include <hip/hip_runtime.h>
#include <hip/hip_bf16.h>

#define S_LEN 2048
#define NHEAD 16
#define NOPE 128
#define ROPE 64
#define HD 192   // nope + rope

typedef unsigned short ushort_t;
typedef __attribute__((ext_vector_type(8))) short short8;
typedef __attribute__((ext_vector_type(4))) float f32x4;

__device__ __forceinline__ unsigned short f2bf(float f) {
  unsigned int u = __float_as_uint(f);
  return (unsigned short)((u + 0x7FFFu + ((u >> 16) & 1u)) >> 16);
}

__device__ __forceinline__ void gload_lds16(const ushort_t* g, ushort_t* lds_generic_unused) {
  // unused helper placeholder (kept out of use; direct builtin calls below)
}

// ---------------- cast f32 -> bf16 (x pre-cast so all GEMMs take the bf16 path) --------
__global__ __launch_bounds__(256) void cast_f32_bf16_k(const float* __restrict__ in,
                                                       ushort_t* __restrict__ out) {
  const int i = blockIdx.x * 256 + threadIdx.x;
  const float4 v0 = *(const float4*)&in[(size_t)i * 8];
  const float4 v1 = *(const float4*)&in[(size_t)i * 8 + 4];
  union { uint4 u; ushort_t s[8]; } pk;
  pk.s[0] = f2bf(v0.x); pk.s[1] = f2bf(v0.y); pk.s[2] = f2bf(v0.z); pk.s[3] = f2bf(v0.w);
  pk.s[4] = f2bf(v1.x); pk.s[5] = f2bf(v1.y); pk.s[6] = f2bf(v1.z); pk.s[7] = f2bf(v1.w);
  *(uint4*)&out[(size_t)i * 8] = pk.u;
}

// ---------------- transpose + cast: B f32 [K][N] -> Bt bf16 [Npad][K] ----------------
__global__ __launch_bounds__(256) void transpose_cast_k(const float* __restrict__ B,
                                                        ushort_t* __restrict__ Bt,
                                                        int K, int N) {
  __shared__ float tile[32][33];
  const int tx = threadIdx.x & 31, ty = threadIdx.x >> 5;  // 32 x 8
  const int n0 = blockIdx.x * 32, k0 = blockIdx.y * 32;
  if (n0 >= N) {
#pragma unroll
    for (int r = 0; r < 4; ++r)
      Bt[(size_t)(n0 + ty + 8 * r) * K + k0 + tx] = 0;
    return;
  }
#pragma unroll
  for (int r = 0; r < 4; ++r)
    tile[ty + 8 * r][tx] = B[(size_t)(k0 + ty + 8 * r) * N + n0 + tx];
  __syncthreads();
#pragma unroll
  for (int r = 0; r < 4; ++r)
    Bt[(size_t)(n0 + ty + 8 * r) * K + k0 + tx] = f2bf(tile[tx][ty + 8 * r]);
}

// ---------------- MFMA GEMM (bf16 A and B; global_load_lds staging) ----------------
// Staging layout: thread u writes LDS bytes [u*16, u*16+16) = wave-uniform base +
// lane*16  -> exactly the global_load_lds dest pattern. Global src is per-lane.
// EPI=0: f32 row-major C.
// EPI=1: KV split epilogue (kvu GEMM, N=4096 = 16 heads x [128 K | 128 V]).
template<int EPI>
__global__ __launch_bounds__(256) void mfma_gemm(const ushort_t* __restrict__ A,
                                                 const ushort_t* __restrict__ Bt,
                                                 float* __restrict__ C,
                                                 int M, int N, int K, int ldc,
                                                 ushort_t* __restrict__ kb16o,
                                                 ushort_t* __restrict__ vto) {
  __shared__ ushort_t As[128 * 32];
  __shared__ ushort_t Bs[128 * 32];
  const int tid = threadIdx.x;
  const int lane = tid & 63;
  const int wave = tid >> 6;
  const int wm = wave & 1, wn = wave >> 1;
  const int m0 = blockIdx.y * 128, n0 = blockIdx.x * 128;
  const int l15 = lane & 15, quad = lane >> 4;

  f32x4 acc[4][4] = {};

  const int it0 = tid, it1 = tid + 256;
  const int ma0 = it0 >> 2, kc0 = it0 & 3;
  const int ma1 = it1 >> 2, kc1 = it1 & 3;

  typedef __attribute__((address_space(3))) ushort_t lds_us;
  lds_us* AsL = (lds_us*)As;
  lds_us* BsL = (lds_us*)Bs;
  const int wbase = wave * 512;   // shorts: 64 lanes * 8 shorts

  for (int k0 = 0; k0 < K; k0 += 32) {
    __builtin_amdgcn_global_load_lds(
        (const __attribute__((address_space(1))) void*)&A[(size_t)(m0 + ma0) * K + k0 + kc0 * 8],
        (__attribute__((address_space(3))) void*)(AsL + wbase), 16, 0, 0);
    __builtin_amdgcn_global_load_lds(
        (const __attribute__((address_space(1))) void*)&A[(size_t)(m0 + ma1) * K + k0 + kc1 * 8],
        (__attribute__((address_space(3))) void*)(AsL + 2048 + wbase), 16, 0, 0);
    __builtin_amdgcn_global_load_lds(
        (const __attribute__((address_space(1))) void*)&Bt[(size_t)(n0 + ma0) * K + k0 + kc0 * 8],
        (__attribute__((address_space(3))) void*)(BsL + wbase), 16, 0, 0);
    __builtin_amdgcn_global_load_lds(
        (const __attribute__((address_space(1))) void*)&Bt[(size_t)(n0 + ma1) * K + k0 + kc1 * 8],
        (__attribute__((address_space(3))) void*)(BsL + 2048 + wbase), 16, 0, 0);
    __syncthreads();

    short8 af[4], bf[4];
#pragma unroll
    for (int i = 0; i < 4; ++i)
      af[i] = *(const short8*)&As[(wm * 64 + i * 16 + l15) * 32 + quad * 8];
#pragma unroll
    for (int j = 0; j < 4; ++j)
      bf[j] = *(const short8*)&Bs[(wn * 64 + j * 16 + l15) * 32 + quad * 8];
#pragma unroll
    for (int i = 0; i < 4; ++i)
#pragma unroll
      for (int j = 0; j < 4; ++j)
        acc[i][j] = __builtin_amdgcn_mfma_f32_16x16x32_bf16(af[i], bf[j], acc[i][j], 0, 0, 0);
    __syncthreads();
  }

  if constexpr (EPI == 0) {
#pragma unroll
    for (int i = 0; i < 4; ++i)
#pragma unroll
      for (int r = 0; r < 4; ++r) {
        const size_t rg = (size_t)(m0 + wm * 64 + i * 16 + quad * 4 + r);
#pragma unroll
        for (int j = 0; j < 4; ++j)
          C[rg * ldc + n0 + wn * 64 + j * 16 + l15] = acc[i][j][r];
      }
  } else {
    const int h = n0 >> 8;
    const bool is_v = (n0 >> 7) & 1;
    if (!is_v) {
      // K half: bf16 row-major kb16[token][h*128 + d]
#pragma unroll
      for (int i = 0; i < 4; ++i)
#pragma unroll
        for (int r = 0; r < 4; ++r) {
          const size_t rg = (size_t)(m0 + wm * 64 + i * 16 + quad * 4 + r);
#pragma unroll
          for (int j = 0; j < 4; ++j)
            kb16o[rg * 2048 + h * 128 + wn * 64 + j * 16 + l15] = f2bf(acc[i][j][r]);
        }
    } else {
      // V half: transpose to vT[(b*16+h)*128 + vd][token] via LDS
      __shared__ __align__(16) ushort_t trb[64 * 136];
      const int bb = m0 >> 11;            // batch index
      const int m0loc = m0 & 2047;        // token offset within batch
      ushort_t* vbase = vto + ((size_t)(bb * NHEAD + h) * 128) * 2048;
#pragma unroll
      for (int vh = 0; vh < 2; ++vh) {
        if (wn == vh) {
#pragma unroll
          for (int i = 0; i < 4; ++i)
#pragma unroll
            for (int r = 0; r < 4; ++r) {
              const int tloc = wm * 64 + i * 16 + quad * 4 + r;   // 0..127
#pragma unroll
              for (int j = 0; j < 4; ++j)
                trb[(j * 16 + l15) * 136 + tloc] = f2bf(acc[i][j][r]);
            }
        }
        __syncthreads();
        // cooperative coalesced write: 64 vd rows x 128 tokens (16B chunks)
#pragma unroll
        for (int it = 0; it < 4; ++it) {
          const int u = tid + (it << 8);
          const int vdl = u >> 4, tc = u & 15;
          *(uint4*)&vbase[(size_t)(vh * 64 + vdl) * 2048 + m0loc + tc * 8] =
              *(const uint4*)&trb[vdl * 136 + tc * 8];
        }
        __syncthreads();
      }
    }
  }
}

// ---------------- RMSNorm: f32 in -> bf16 out ----------------
__global__ __launch_bounds__(256) void rmsnorm_k(const float* __restrict__ in, int in_stride,
                                                 ushort_t* __restrict__ out, int out_stride,
                                                 const float* __restrict__ w, int L) {
  const int row = blockIdx.x;
  const int tid = threadIdx.x;
  const float* ip = in + (size_t)row * in_stride;
  ushort_t* op = out + (size_t)row * out_stride;
  const int nper = L >> 8;
  float r[6];
  float ss = 0.f;
  for (int j = 0; j < nper; ++j) {
    r[j] = ip[tid + (j << 8)];
    ss += r[j] * r[j];
  }
  for (int off = 32; off; off >>= 1) ss += __shfl_down(ss, off);
  __shared__ float wsum[4];
  __shared__ float scale_s;
  if ((tid & 63) == 0) wsum[tid >> 6] = ss;
  __syncthreads();
  if (tid == 0) {
    float t = wsum[0] + wsum[1] + wsum[2] + wsum[3];
    scale_s = rsqrtf(t / (float)L + 1e-5f);
  }
  __syncthreads();
  const float sc = scale_s;
  for (int j = 0; j < nper; ++j)
    op[tid + (j << 8)] = f2bf(r[j] * sc * w[tid + (j << 8)]);
}

// ---------------- RoPE (krope emitted as bf16) ----------------
__global__ __launch_bounds__(512) void rope_k(float* __restrict__ qall,
                                              const float* __restrict__ kvd,
                                              ushort_t* __restrict__ krope16,
                                              const float* __restrict__ cosb,
                                              const float* __restrict__ sinb) {
  const int row = blockIdx.x;
  const int s = row & (S_LEN - 1);
  const int tid = threadIdx.x;
  const int d = tid & 31, h = tid >> 5;
  const float c = cosb[s * 32 + d];
  const float sn = sinb[s * 32 + d];
  float* qb = qall + (size_t)row * 3072 + h * HD + NOPE;
  float x0 = qb[2 * d], x1 = qb[2 * d + 1];
  qb[2 * d]     = x0 * c - x1 * sn;
  qb[2 * d + 1] = x0 * sn + x1 * c;
  if (tid < 32) {
    const float* kb = kvd + (size_t)row * 640 + 512;
    float y0 = kb[2 * d], y1 = kb[2 * d + 1];
    union { unsigned int u; ushort_t s2[2]; } pk;
    pk.s2[0] = f2bf(y0 * c - y1 * sn);
    pk.s2[1] = f2bf(y0 * sn + y1 * c);
    *(unsigned int*)&krope16[(size_t)row * 64 + 2 * d] = pk.u;
  }
}

// ---------------- MFMA flash attention ----------------
// Grid 512 = b(2) x h(16) x tile(16); 256 threads = 4 waves x 32 q-rows.
// Round 3: T14 async staging. K(c+1) prefetched into 6 uint4 regs + V(c) into
// 4 uint4 regs, both issued right after the K-ready barrier; V latency hides
// under QK^T (ds_write after), K latency under QK+softmax+PV (ds_write at next
// loop top). Pure copies, short live ranges -> no cvt chains, low spill risk.
#define QT 128
#define KC 64
__global__ __launch_bounds__(256, 2) void attn_k(const float* __restrict__ qall,
                                                 const ushort_t* __restrict__ kb16,
                                                 const ushort_t* __restrict__ vT,
                                                 const ushort_t* __restrict__ krope16,
                                                 ushort_t* __restrict__ outp) {
  const int bx = blockIdx.x;
  const int second = bx >> 8;
  const int h = (bx >> 4) & 15;
  int tile = bx & 15;
  if (second) tile = 15 - tile;       // complementary pairing across grid halves
  const int b = second;
  const int q0 = tile * QT;
  const int tid = threadIdx.x;
  const int lane = tid & 63;
  const int wq = tid >> 6;
  const int l15 = lane & 15, quad = lane >> 4;

  __shared__ ushort_t Kb[64 * 200];
  __shared__ ushort_t Vt[128 * 72];
  __shared__ ushort_t Pb[4][32 * 72];

  const int qbase = q0 + wq * 32;
  const size_t growq = (size_t)b * S_LEN + qbase;
  const ushort_t* vTh = vT + ((size_t)(b * NHEAD + h) * 128) * 2048;
  const size_t bbase = (size_t)b * S_LEN;

  // Q fragments (bf16) in registers: [mt][ks]
  short8 qf[2][6];
#pragma unroll
  for (int mt = 0; mt < 2; ++mt)
#pragma unroll
    for (int ks = 0; ks < 6; ++ks) {
      const float* src = &qall[(growq + mt * 16 + l15) * 3072 + h * HD + ks * 32 + quad * 8];
      const float4 v0 = *(const float4*)src;
      const float4 v1 = *(const float4*)(src + 4);
      union { short8 s8; ushort_t u[8]; } pk;
      pk.u[0] = f2bf(v0.x); pk.u[1] = f2bf(v0.y); pk.u[2] = f2bf(v0.z); pk.u[3] = f2bf(v0.w);
      pk.u[4] = f2bf(v1.x); pk.u[5] = f2bf(v1.y); pk.u[6] = f2bf(v1.z); pk.u[7] = f2bf(v1.w);
      qf[mt][ks] = pk.s8;
    }

  f32x4 oacc[2][8] = {};
  float mrow[2][4], lrow[2][4];
  int q_r[2][4];
#pragma unroll
  for (int mt = 0; mt < 2; ++mt)
#pragma unroll
    for (int r = 0; r < 4; ++r) {
      mrow[mt][r] = -1e30f; lrow[mt][r] = 0.f;
      q_r[mt][r] = qbase + mt * 16 + quad * 4 + r;
    }

  const float scale = 0.07216878364870323f;  // 1/sqrt(192)
  const int nchunk = (q0 + QT) / KC;

  // K staging registers (chunk c+1 in flight during chunk c's compute)
  uint4 rk[6];
  auto loadK = [&](int c) {
    const size_t growk = bbase + c * KC;
#pragma unroll
    for (int it = 0; it < 4; ++it) {
      const int u = tid + (it << 8);
      rk[it] = *(const uint4*)&kb16[(growk + (u >> 4)) * 2048 + h * 128 + (u & 15) * 8];
    }
#pragma unroll
    for (int it = 0; it < 2; ++it) {
      const int u = tid + (it << 8);
      rk[4 + it] = *(const uint4*)&krope16[(growk + (u >> 3)) * 64 + (u & 7) * 8];
    }
  };

  loadK(0);

  for (int c = 0; c < nchunk; ++c) {
    const int j0 = c * KC;
    __syncthreads();                 // (1) prev chunk's Kb/Vt reads complete
    // ---- Kb <- rk (ds_write only) ----
#pragma unroll
    for (int it = 0; it < 4; ++it) {
      const int u = tid + (it << 8);
      *(uint4*)&Kb[(u >> 4) * 200 + (u & 15) * 8] = rk[it];
    }
#pragma unroll
    for (int it = 0; it < 2; ++it) {
      const int u = tid + (it << 8);
      *(uint4*)&Kb[(u >> 3) * 200 + 128 + (u & 7) * 8] = rk[4 + it];
    }
    __syncthreads();                 // (2) Kb ready
    // ---- issue V(c) and K(c+1) loads; hide under QK^T (+softmax) ----
    uint4 rv[4];
#pragma unroll
    for (int it = 0; it < 4; ++it) {
      const int u = tid + (it << 8);
      rv[it] = *(const uint4*)&vTh[(size_t)(u >> 3) * 2048 + j0 + (u & 7) * 8];
    }
    if (c + 1 < nchunk) loadK(c + 1);
    __builtin_amdgcn_sched_barrier(0);

    // ---- QK^T ----
    f32x4 sacc[2][4] = {};
    __builtin_amdgcn_s_setprio(1);
#pragma unroll
    for (int ks = 0; ks < 6; ++ks) {
      short8 kf[4];
#pragma unroll
      for (int kt = 0; kt < 4; ++kt)
        kf[kt] = *(const short8*)&Kb[(kt * 16 + l15) * 200 + ks * 32 + quad * 8];
#pragma unroll
      for (int mt = 0; mt < 2; ++mt)
#pragma unroll
        for (int kt = 0; kt < 4; ++kt)
          sacc[mt][kt] = __builtin_amdgcn_mfma_f32_16x16x32_bf16(qf[mt][ks], kf[kt], sacc[mt][kt], 0, 0, 0);
    }
    __builtin_amdgcn_s_setprio(0);

    // ---- Vt <- rv (V loads have drained under QK^T) ----
#pragma unroll
    for (int it = 0; it < 4; ++it) {
      const int u = tid + (it << 8);
      *(uint4*)&Vt[(u >> 3) * 72 + (u & 7) * 8] = rv[it];
    }

    // ---- mask + scale (in place) ----
#pragma unroll
    for (int mt = 0; mt < 2; ++mt)
#pragma unroll
      for (int kt = 0; kt < 4; ++kt) {
        const int key = j0 + kt * 16 + l15;
#pragma unroll
        for (int r = 0; r < 4; ++r)
          sacc[mt][kt][r] = (key <= q_r[mt][r]) ? sacc[mt][kt][r] * scale : -1e30f;
      }
    // ---- online softmax (wave-internal, per quad group) ----
    float alpha[2][4];
#pragma unroll
    for (int mt = 0; mt < 2; ++mt)
#pragma unroll
      for (int r = 0; r < 4; ++r) {
        float mx = fmaxf(fmaxf(sacc[mt][0][r], sacc[mt][1][r]),
                         fmaxf(sacc[mt][2][r], sacc[mt][3][r]));
        mx = fmaxf(mx, __shfl_xor(mx, 1));
        mx = fmaxf(mx, __shfl_xor(mx, 2));
        mx = fmaxf(mx, __shfl_xor(mx, 4));
        mx = fmaxf(mx, __shfl_xor(mx, 8));
        const float mn = fmaxf(mrow[mt][r], mx);
        alpha[mt][r] = __expf(mrow[mt][r] - mn);
        mrow[mt][r] = mn;
      }
#pragma unroll
    for (int mt = 0; mt < 2; ++mt)
#pragma unroll
      for (int kt = 0; kt < 4; ++kt)
#pragma unroll
        for (int r = 0; r < 4; ++r)
          sacc[mt][kt][r] = __expf(sacc[mt][kt][r] - mrow[mt][r]);
#pragma unroll
    for (int mt = 0; mt < 2; ++mt)
#pragma unroll
      for (int r = 0; r < 4; ++r) {
        float rs = sacc[mt][0][r] + sacc[mt][1][r] + sacc[mt][2][r] + sacc[mt][3][r];
        rs += __shfl_xor(rs, 1);
        rs += __shfl_xor(rs, 2);
        rs += __shfl_xor(rs, 4);
        rs += __shfl_xor(rs, 8);
        lrow[mt][r] = lrow[mt][r] * alpha[mt][r] + rs;
      }
    // ---- write P (bf16) to per-wave-private LDS ----
#pragma unroll
    for (int mt = 0; mt < 2; ++mt)
#pragma unroll
      for (int kt = 0; kt < 4; ++kt)
#pragma unroll
        for (int r = 0; r < 4; ++r)
          Pb[wq][(mt * 16 + quad * 4 + r) * 72 + kt * 16 + l15] = f2bf(sacc[mt][kt][r]);

    __syncthreads();                 // (3) Vt ready for all waves
    // ---- rescale O ----
#pragma unroll
    for (int mt = 0; mt < 2; ++mt)
#pragma unroll
      for (int nt = 0; nt < 8; ++nt)
#pragma unroll
        for (int r = 0; r < 4; ++r)
          oacc[mt][nt][r] *= alpha[mt][r];
    // ---- PV ----
    __builtin_amdgcn_s_setprio(1);
#pragma unroll
    for (int st = 0; st < 2; ++st) {
      short8 pf[2];
#pragma unroll
      for (int mt = 0; mt < 2; ++mt)
        pf[mt] = *(const short8*)&Pb[wq][(mt * 16 + l15) * 72 + st * 32 + quad * 8];
#pragma unroll
      for (int nt = 0; nt < 8; ++nt) {
        const short8 vf = *(const short8*)&Vt[(nt * 16 + l15) * 72 + st * 32 + quad * 8];
#pragma unroll
        for (int mt = 0; mt < 2; ++mt)
          oacc[mt][nt] = __builtin_amdgcn_mfma_f32_16x16x32_bf16(pf[mt], vf, oacc[mt][nt], 0, 0, 0);
      }
    }
    __builtin_amdgcn_s_setprio(0);
  }

  // ---- store (bf16) ----
#pragma unroll
  for (int mt = 0; mt < 2; ++mt)
#pragma unroll
    for (int r = 0; r < 4; ++r) {
      const float inv = 1.0f / lrow[mt][r];
      const size_t orow = growq + mt * 16 + quad * 4 + r;
#pragma unroll
      for (int nt = 0; nt < 8; ++nt)
        outp[orow * 2048 + h * 128 + nt * 16 + l15] = f2bf(oacc[mt][nt][r] * inv);
    }
}

extern "C" void kernel_launch(void* const* d_in, const int* in_sizes, int n_in,
                              void* d_out, int out_size, void* d_ws, size_t ws_size,
                              hipStream_t stream) {
  const float* x        = (const float*)d_in[0];
  const float* wd_q     = (const float*)d_in[1];
  const float* wu_q     = (const float*)d_in[2];
  const float* q_norm_w = (const float*)d_in[3];
  const float* wd_kv    = (const float*)d_in[4];
  const float* wu_kv    = (const float*)d_in[5];
  const float* kv_norm_w= (const float*)d_in[6];
  const float* wo       = (const float*)d_in[7];
  const float* cosb     = (const float*)d_in[8];
  const float* sinb     = (const float*)d_in[9];
  float* out = (float*)d_out;

  char* ws = (char*)d_ws;
  float*    qall  = (float*)(ws + 0);            // 4096x3072 f32; cq aliases @0
  float*    cq    = (float*)(ws + 0);
  ushort_t* kb16  = (ushort_t*)(ws + 50331648);  // 4096x2048 bf16 K rows (16MB)
  ushort_t* vT    = (ushort_t*)(ws + 67108864);  // [b*16+h][128 vd][2048 tok] bf16 (16MB)
  ushort_t* xb    = (ushort_t*)(ws + 83886080);  // 4096x2048 bf16 pre-cast x (16MB)
  ushort_t* cqn   = (ushort_t*)(ws + 117440512); // 4096x1536 bf16
  float*    kvd   = (float*)(ws + 130023424);    // 4096x640 f32 (dead after rope)
  ushort_t* ckvn  = (ushort_t*)(ws + 140509184); // 4096x512 bf16 (dead after kvu gemm)
  ushort_t* aoutb = (ushort_t*)(ws + 130023424); // 4096x2048 bf16, aliases kvd+ckvn
  ushort_t* krope16 = (ushort_t*)(ws + 146800640); // 4096x64 bf16
  ushort_t* wdqt  = (ushort_t*)(ws + 147849216); // 1536x2048 bf16
  ushort_t* wdkvt = (ushort_t*)(ws + 154140672); // 640x2048 bf16
  ushort_t* wuqt  = (ushort_t*)(ws + 156762112); // 3072x1536 bf16
  ushort_t* wukvt = (ushort_t*)(ws + 166199296); // 4096x512 bf16
  ushort_t* wot   = (ushort_t*)(ws + 170393600); // 2048x2048 bf16

  const int M = 2 * S_LEN;  // 4096
  dim3 blk(256);

  cast_f32_bf16_k<<<4096, blk, 0, stream>>>(x, xb);   // 4096x2048 / 8 per thread

  transpose_cast_k<<<dim3(1536 / 32, 2048 / 32), blk, 0, stream>>>(wd_q, wdqt, 2048, 1536);
  transpose_cast_k<<<dim3(640 / 32, 2048 / 32), blk, 0, stream>>>(wd_kv, wdkvt, 2048, 576);
  transpose_cast_k<<<dim3(3072 / 32, 1536 / 32), blk, 0, stream>>>(wu_q, wuqt, 1536, 3072);
  transpose_cast_k<<<dim3(4096 / 32, 512 / 32), blk, 0, stream>>>(wu_kv, wukvt, 512, 4096);
  transpose_cast_k<<<dim3(2048 / 32, 2048 / 32), blk, 0, stream>>>(wo, wot, 2048, 2048);

  mfma_gemm<0><<<dim3(1536 / 128, M / 128), blk, 0, stream>>>(
      xb, wdqt, cq, M, 1536, 2048, 1536, nullptr, nullptr);
  mfma_gemm<0><<<dim3(640 / 128, M / 128), blk, 0, stream>>>(
      xb, wdkvt, kvd, M, 640, 2048, 640, nullptr, nullptr);
  rmsnorm_k<<<M, 256, 0, stream>>>(cq, 1536, cqn, 1536, q_norm_w, 1536);
  rmsnorm_k<<<M, 256, 0, stream>>>(kvd, 640, ckvn, 512, kv_norm_w, 512);
  mfma_gemm<0><<<dim3(3072 / 128, M / 128), blk, 0, stream>>>(
      cqn, wuqt, qall, M, 3072, 1536, 3072, nullptr, nullptr);
  mfma_gemm<1><<<dim3(4096 / 128, M / 128), blk, 0, stream>>>(
      ckvn, wukvt, nullptr, M, 4096, 512, 0, kb16, vT);
  rope_k<<<M, 512, 0, stream>>>(qall, kvd, krope16, cosb, sinb);
  attn_k<<<2 * NHEAD * (S_LEN / QT), 256, 0, stream>>>(qall, kb16, vT, krope16, aoutb);
  mfma_gemm<0><<<dim3(2048 / 128, M / 128), blk, 0, stream>>>(
      aoutb, wot, out, M, 2048, 2048, 2048, nullptr, nullptr);
}

// Round 4
// 554.909 us; speedup vs baseline: 1.5739x; 1.0548x over previous
//
#include <hip/hip_runtime.h>
#include <hip/hip_bf16.h>

#define S_LEN 2048
#define NHEAD 16
#define NOPE 128
#define ROPE 64
#define HD 192   // nope + rope

typedef unsigned short ushort_t;
typedef __attribute__((ext_vector_type(8))) short short8;
typedef __attribute__((ext_vector_type(4))) float f32x4;

#define AS1 __attribute__((address_space(1)))
#define AS3 __attribute__((address_space(3)))

__device__ __forceinline__ unsigned short f2bf(float f) {
  unsigned int u = __float_as_uint(f);
  return (unsigned short)((u + 0x7FFFu + ((u >> 16) & 1u)) >> 16);
}

// ---------------- cast f32 -> bf16 (x pre-cast so all GEMMs take the bf16 path) --------
__global__ __launch_bounds__(256) void cast_f32_bf16_k(const float* __restrict__ in,
                                                       ushort_t* __restrict__ out) {
  const int i = blockIdx.x * 256 + threadIdx.x;
  const float4 v0 = *(const float4*)&in[(size_t)i * 8];
  const float4 v1 = *(const float4*)&in[(size_t)i * 8 + 4];
  union { uint4 u; ushort_t s[8]; } pk;
  pk.s[0] = f2bf(v0.x); pk.s[1] = f2bf(v0.y); pk.s[2] = f2bf(v0.z); pk.s[3] = f2bf(v0.w);
  pk.s[4] = f2bf(v1.x); pk.s[5] = f2bf(v1.y); pk.s[6] = f2bf(v1.z); pk.s[7] = f2bf(v1.w);
  *(uint4*)&out[(size_t)i * 8] = pk.u;
}

// ---------------- transpose + cast: B f32 [K][N] -> Bt bf16 [Npad][K] ----------------
__global__ __launch_bounds__(256) void transpose_cast_k(const float* __restrict__ B,
                                                        ushort_t* __restrict__ Bt,
                                                        int K, int N) {
  __shared__ float tile[32][33];
  const int tx = threadIdx.x & 31, ty = threadIdx.x >> 5;  // 32 x 8
  const int n0 = blockIdx.x * 32, k0 = blockIdx.y * 32;
  if (n0 >= N) {
#pragma unroll
    for (int r = 0; r < 4; ++r)
      Bt[(size_t)(n0 + ty + 8 * r) * K + k0 + tx] = 0;
    return;
  }
#pragma unroll
  for (int r = 0; r < 4; ++r)
    tile[ty + 8 * r][tx] = B[(size_t)(k0 + ty + 8 * r) * N + n0 + tx];
  __syncthreads();
#pragma unroll
  for (int r = 0; r < 4; ++r)
    Bt[(size_t)(n0 + ty + 8 * r) * K + k0 + tx] = f2bf(tile[tx][ty + 8 * r]);
}

// ---------------- MFMA GEMM (bf16 A and B; global_load_lds staging) ----------------
template<int EPI>
__global__ __launch_bounds__(256) void mfma_gemm(const ushort_t* __restrict__ A,
                                                 const ushort_t* __restrict__ Bt,
                                                 float* __restrict__ C,
                                                 int M, int N, int K, int ldc,
                                                 ushort_t* __restrict__ kb16o,
                                                 ushort_t* __restrict__ vto) {
  __shared__ ushort_t As[128 * 32];
  __shared__ ushort_t Bs[128 * 32];
  const int tid = threadIdx.x;
  const int lane = tid & 63;
  const int wave = tid >> 6;
  const int wm = wave & 1, wn = wave >> 1;
  const int m0 = blockIdx.y * 128, n0 = blockIdx.x * 128;
  const int l15 = lane & 15, quad = lane >> 4;

  f32x4 acc[4][4] = {};

  const int it0 = tid, it1 = tid + 256;
  const int ma0 = it0 >> 2, kc0 = it0 & 3;
  const int ma1 = it1 >> 2, kc1 = it1 & 3;

  typedef AS3 ushort_t lds_us;
  lds_us* AsL = (lds_us*)As;
  lds_us* BsL = (lds_us*)Bs;
  const int wbase = wave * 512;   // shorts: 64 lanes * 8 shorts

  for (int k0 = 0; k0 < K; k0 += 32) {
    __builtin_amdgcn_global_load_lds(
        (const AS1 void*)&A[(size_t)(m0 + ma0) * K + k0 + kc0 * 8],
        (AS3 void*)(AsL + wbase), 16, 0, 0);
    __builtin_amdgcn_global_load_lds(
        (const AS1 void*)&A[(size_t)(m0 + ma1) * K + k0 + kc1 * 8],
        (AS3 void*)(AsL + 2048 + wbase), 16, 0, 0);
    __builtin_amdgcn_global_load_lds(
        (const AS1 void*)&Bt[(size_t)(n0 + ma0) * K + k0 + kc0 * 8],
        (AS3 void*)(BsL + wbase), 16, 0, 0);
    __builtin_amdgcn_global_load_lds(
        (const AS1 void*)&Bt[(size_t)(n0 + ma1) * K + k0 + kc1 * 8],
        (AS3 void*)(BsL + 2048 + wbase), 16, 0, 0);
    __syncthreads();

    short8 af[4], bf[4];
#pragma unroll
    for (int i = 0; i < 4; ++i)
      af[i] = *(const short8*)&As[(wm * 64 + i * 16 + l15) * 32 + quad * 8];
#pragma unroll
    for (int j = 0; j < 4; ++j)
      bf[j] = *(const short8*)&Bs[(wn * 64 + j * 16 + l15) * 32 + quad * 8];
#pragma unroll
    for (int i = 0; i < 4; ++i)
#pragma unroll
      for (int j = 0; j < 4; ++j)
        acc[i][j] = __builtin_amdgcn_mfma_f32_16x16x32_bf16(af[i], bf[j], acc[i][j], 0, 0, 0);
    __syncthreads();
  }

  if constexpr (EPI == 0) {
#pragma unroll
    for (int i = 0; i < 4; ++i)
#pragma unroll
      for (int r = 0; r < 4; ++r) {
        const size_t rg = (size_t)(m0 + wm * 64 + i * 16 + quad * 4 + r);
#pragma unroll
        for (int j = 0; j < 4; ++j)
          C[rg * ldc + n0 + wn * 64 + j * 16 + l15] = acc[i][j][r];
      }
  } else {
    const int h = n0 >> 8;
    const bool is_v = (n0 >> 7) & 1;
    if (!is_v) {
      // K half: bf16 row-major kb16[token][h*128 + d]
#pragma unroll
      for (int i = 0; i < 4; ++i)
#pragma unroll
        for (int r = 0; r < 4; ++r) {
          const size_t rg = (size_t)(m0 + wm * 64 + i * 16 + quad * 4 + r);
#pragma unroll
          for (int j = 0; j < 4; ++j)
            kb16o[rg * 2048 + h * 128 + wn * 64 + j * 16 + l15] = f2bf(acc[i][j][r]);
        }
    } else {
      // V half: transpose to vT[(b*16+h)*128 + vd][token] via LDS
      __shared__ __align__(16) ushort_t trb[64 * 136];
      const int bb = m0 >> 11;            // batch index
      const int m0loc = m0 & 2047;        // token offset within batch
      ushort_t* vbase = vto + ((size_t)(bb * NHEAD + h) * 128) * 2048;
#pragma unroll
      for (int vh = 0; vh < 2; ++vh) {
        if (wn == vh) {
#pragma unroll
          for (int i = 0; i < 4; ++i)
#pragma unroll
            for (int r = 0; r < 4; ++r) {
              const int tloc = wm * 64 + i * 16 + quad * 4 + r;   // 0..127
#pragma unroll
              for (int j = 0; j < 4; ++j)
                trb[(j * 16 + l15) * 136 + tloc] = f2bf(acc[i][j][r]);
            }
        }
        __syncthreads();
#pragma unroll
        for (int it = 0; it < 4; ++it) {
          const int u = tid + (it << 8);
          const int vdl = u >> 4, tc = u & 15;
          *(uint4*)&vbase[(size_t)(vh * 64 + vdl) * 2048 + m0loc + tc * 8] =
              *(const uint4*)&trb[vdl * 136 + tc * 8];
        }
        __syncthreads();
      }
    }
  }
}

// ---------------- RMSNorm: f32 in -> bf16 out ----------------
__global__ __launch_bounds__(256) void rmsnorm_k(const float* __restrict__ in, int in_stride,
                                                 ushort_t* __restrict__ out, int out_stride,
                                                 const float* __restrict__ w, int L) {
  const int row = blockIdx.x;
  const int tid = threadIdx.x;
  const float* ip = in + (size_t)row * in_stride;
  ushort_t* op = out + (size_t)row * out_stride;
  const int nper = L >> 8;
  float r[6];
  float ss = 0.f;
  for (int j = 0; j < nper; ++j) {
    r[j] = ip[tid + (j << 8)];
    ss += r[j] * r[j];
  }
  for (int off = 32; off; off >>= 1) ss += __shfl_down(ss, off);
  __shared__ float wsum[4];
  __shared__ float scale_s;
  if ((tid & 63) == 0) wsum[tid >> 6] = ss;
  __syncthreads();
  if (tid == 0) {
    float t = wsum[0] + wsum[1] + wsum[2] + wsum[3];
    scale_s = rsqrtf(t / (float)L + 1e-5f);
  }
  __syncthreads();
  const float sc = scale_s;
  for (int j = 0; j < nper; ++j)
    op[tid + (j << 8)] = f2bf(r[j] * sc * w[tid + (j << 8)]);
}

// ---------------- RoPE (krope emitted as bf16) ----------------
__global__ __launch_bounds__(512) void rope_k(float* __restrict__ qall,
                                              const float* __restrict__ kvd,
                                              ushort_t* __restrict__ krope16,
                                              const float* __restrict__ cosb,
                                              const float* __restrict__ sinb) {
  const int row = blockIdx.x;
  const int s = row & (S_LEN - 1);
  const int tid = threadIdx.x;
  const int d = tid & 31, h = tid >> 5;
  const float c = cosb[s * 32 + d];
  const float sn = sinb[s * 32 + d];
  float* qb = qall + (size_t)row * 3072 + h * HD + NOPE;
  float x0 = qb[2 * d], x1 = qb[2 * d + 1];
  qb[2 * d]     = x0 * c - x1 * sn;
  qb[2 * d + 1] = x0 * sn + x1 * c;
  if (tid < 32) {
    const float* kb = kvd + (size_t)row * 640 + 512;
    float y0 = kb[2 * d], y1 = kb[2 * d + 1];
    union { unsigned int u; ushort_t s2[2]; } pk;
    pk.s2[0] = f2bf(y0 * c - y1 * sn);
    pk.s2[1] = f2bf(y0 * sn + y1 * c);
    *(unsigned int*)&krope16[(size_t)row * 64 + 2 * d] = pk.u;
  }
}

// ---------------- MFMA flash attention ----------------
// Round 4: zero-register async staging via global_load_lds (DMA, vmcnt-counted).
// LDS K/V contiguous (gload_lds needs linear dest); bank spread restored by
// XOR-swizzling the per-lane global SOURCE slot (slot ^= row&7) and applying
// the same XOR on ds_read (m173 / T2 both-sides pattern).
// Loop: raw s_barrier + counted vmcnt so prefetch DMAs stay in flight across
// barriers: K(c+1) issued after QK(c), V(c+1) after PV(c).
#define QT 128
#define KC 64
__global__ __launch_bounds__(256, 2) void attn_k(const float* __restrict__ qall,
                                                 const ushort_t* __restrict__ kb16,
                                                 const ushort_t* __restrict__ vT,
                                                 const ushort_t* __restrict__ krope16,
                                                 ushort_t* __restrict__ outp) {
  const int bx = blockIdx.x;
  const int second = bx >> 8;
  const int h = (bx >> 4) & 15;
  int tile = bx & 15;
  if (second) tile = 15 - tile;       // complementary pairing across grid halves
  const int b = second;
  const int q0 = tile * QT;
  const int tid = threadIdx.x;
  const int lane = tid & 63;
  const int wq = tid >> 6;
  const int l15 = lane & 15, quad = lane >> 4;

  __shared__ __align__(16) ushort_t Kn[64 * 128];   // 16 KB, swizzled slots
  __shared__ __align__(16) ushort_t Kr[64 * 64];    //  8 KB, swizzled slots
  __shared__ __align__(16) ushort_t Vt[128 * 64];   // 16 KB, swizzled slots
  __shared__ __align__(16) ushort_t Pb[4][32 * 72]; // 18 KB, per-wave private

  const int qbase = q0 + wq * 32;
  const size_t growq = (size_t)b * S_LEN + qbase;
  const ushort_t* vTh = vT + ((size_t)(b * NHEAD + h) * 128) * 2048;
  const size_t bbase = (size_t)b * S_LEN;

  typedef AS3 ushort_t lds_us;
  lds_us* KnL = (lds_us*)Kn;
  lds_us* KrL = (lds_us*)Kr;
  lds_us* VtL = (lds_us*)Vt;
  const int wbase = wq * 512;   // shorts (64 lanes x 8 shorts)

  // --- async staging issue (6 K-instrs + 4 V-instrs per wave, no VGPRs) ---
  auto issueK = [&](int c) {
    const size_t growk = bbase + (size_t)c * KC;
#pragma unroll
    for (int it = 0; it < 4; ++it) {
      const int u = tid + (it << 8);
      const int key = u >> 4, s = u & 15;
      const int ss = s ^ (key & 7);
      __builtin_amdgcn_global_load_lds(
          (const AS1 void*)&kb16[(growk + key) * 2048 + h * 128 + ss * 8],
          (AS3 void*)(KnL + wbase + it * 2048), 16, 0, 0);
    }
#pragma unroll
    for (int it = 0; it < 2; ++it) {
      const int u = tid + (it << 8);
      const int key = u >> 3, s = u & 7;
      const int ss = s ^ (key & 7);
      __builtin_amdgcn_global_load_lds(
          (const AS1 void*)&krope16[(growk + key) * 64 + ss * 8],
          (AS3 void*)(KrL + wbase + it * 2048), 16, 0, 0);
    }
  };
  auto issueV = [&](int c) {
    const int j0 = c * KC;
#pragma unroll
    for (int it = 0; it < 4; ++it) {
      const int u = tid + (it << 8);
      const int vd = u >> 3, s = u & 7;
      const int ss = s ^ (vd & 7);
      __builtin_amdgcn_global_load_lds(
          (const AS1 void*)&vTh[(size_t)vd * 2048 + j0 + ss * 8],
          (AS3 void*)(VtL + wbase + it * 2048), 16, 0, 0);
    }
  };

  // ---- prologue: issue K(0), V(0); Q prep hides the DMA latency ----
  issueK(0);
  issueV(0);
  __builtin_amdgcn_sched_barrier(0);

  // Q fragments (bf16) in registers: [mt][ks]
  short8 qf[2][6];
#pragma unroll
  for (int mt = 0; mt < 2; ++mt)
#pragma unroll
    for (int ks = 0; ks < 6; ++ks) {
      const float* src = &qall[(growq + mt * 16 + l15) * 3072 + h * HD + ks * 32 + quad * 8];
      const float4 v0 = *(const float4*)src;
      const float4 v1 = *(const float4*)(src + 4);
      union { short8 s8; ushort_t u[8]; } pk;
      pk.u[0] = f2bf(v0.x); pk.u[1] = f2bf(v0.y); pk.u[2] = f2bf(v0.z); pk.u[3] = f2bf(v0.w);
      pk.u[4] = f2bf(v1.x); pk.u[5] = f2bf(v1.y); pk.u[6] = f2bf(v1.z); pk.u[7] = f2bf(v1.w);
      qf[mt][ks] = pk.s8;
    }

  f32x4 oacc[2][8] = {};
  float mrow[2][4], lrow[2][4];
  int q_r[2][4];
#pragma unroll
  for (int mt = 0; mt < 2; ++mt)
#pragma unroll
    for (int r = 0; r < 4; ++r) {
      mrow[mt][r] = -1e30f; lrow[mt][r] = 0.f;
      q_r[mt][r] = qbase + mt * 16 + quad * 4 + r;
    }

  const float scale = 0.07216878364870323f;  // 1/sqrt(192)
  const int nchunk = (q0 + QT) / KC;

  asm volatile("s_waitcnt vmcnt(4)" ::: "memory");   // K(0) landed (V may fly)
  __builtin_amdgcn_s_barrier();
  __builtin_amdgcn_sched_barrier(0);

  for (int c = 0; c < nchunk; ++c) {
    const int j0 = c * KC;
    const bool more = (c + 1 < nchunk);

    // ---- QK^T on K(c) ----
    f32x4 sacc[2][4] = {};
    __builtin_amdgcn_s_setprio(1);
#pragma unroll
    for (int ks = 0; ks < 6; ++ks) {
      short8 kf[4];
      if (ks < 4) {
#pragma unroll
        for (int kt = 0; kt < 4; ++kt)
          kf[kt] = *(const short8*)&Kn[(kt * 16 + l15) * 128 + (((ks * 4 + quad) ^ (l15 & 7)) << 3)];
      } else {
#pragma unroll
        for (int kt = 0; kt < 4; ++kt)
          kf[kt] = *(const short8*)&Kr[(kt * 16 + l15) * 64 + ((((ks - 4) * 4 + quad) ^ (l15 & 7)) << 3)];
      }
#pragma unroll
      for (int mt = 0; mt < 2; ++mt)
#pragma unroll
        for (int kt = 0; kt < 4; ++kt)
          sacc[mt][kt] = __builtin_amdgcn_mfma_f32_16x16x32_bf16(qf[mt][ks], kf[kt], sacc[mt][kt], 0, 0, 0);
    }
    __builtin_amdgcn_s_setprio(0);

    __builtin_amdgcn_s_barrier();          // all waves done reading Kn/Kr
    if (more) issueK(c + 1);               // DMA into Kn/Kr, flies under softmax+PV
    __builtin_amdgcn_sched_barrier(0);

    // ---- mask + scale ----
#pragma unroll
    for (int mt = 0; mt < 2; ++mt)
#pragma unroll
      for (int kt = 0; kt < 4; ++kt) {
        const int key = j0 + kt * 16 + l15;
#pragma unroll
        for (int r = 0; r < 4; ++r)
          sacc[mt][kt][r] = (key <= q_r[mt][r]) ? sacc[mt][kt][r] * scale : -1e30f;
      }
    // ---- online softmax (wave-internal, per quad group) ----
    float alpha[2][4];
#pragma unroll
    for (int mt = 0; mt < 2; ++mt)
#pragma unroll
      for (int r = 0; r < 4; ++r) {
        float mx = fmaxf(fmaxf(sacc[mt][0][r], sacc[mt][1][r]),
                         fmaxf(sacc[mt][2][r], sacc[mt][3][r]));
        mx = fmaxf(mx, __shfl_xor(mx, 1));
        mx = fmaxf(mx, __shfl_xor(mx, 2));
        mx = fmaxf(mx, __shfl_xor(mx, 4));
        mx = fmaxf(mx, __shfl_xor(mx, 8));
        const float mn = fmaxf(mrow[mt][r], mx);
        alpha[mt][r] = __expf(mrow[mt][r] - mn);
        mrow[mt][r] = mn;
      }
#pragma unroll
    for (int mt = 0; mt < 2; ++mt)
#pragma unroll
      for (int kt = 0; kt < 4; ++kt)
#pragma unroll
        for (int r = 0; r < 4; ++r)
          sacc[mt][kt][r] = __expf(sacc[mt][kt][r] - mrow[mt][r]);
#pragma unroll
    for (int mt = 0; mt < 2; ++mt)
#pragma unroll
      for (int r = 0; r < 4; ++r) {
        float rs = sacc[mt][0][r] + sacc[mt][1][r] + sacc[mt][2][r] + sacc[mt][3][r];
        rs += __shfl_xor(rs, 1);
        rs += __shfl_xor(rs, 2);
        rs += __shfl_xor(rs, 4);
        rs += __shfl_xor(rs, 8);
        lrow[mt][r] = lrow[mt][r] * alpha[mt][r] + rs;
      }
    // ---- write P (bf16) to per-wave-private LDS ----
#pragma unroll
    for (int mt = 0; mt < 2; ++mt)
#pragma unroll
      for (int kt = 0; kt < 4; ++kt)
#pragma unroll
        for (int r = 0; r < 4; ++r)
          Pb[wq][(mt * 16 + quad * 4 + r) * 72 + kt * 16 + l15] = f2bf(sacc[mt][kt][r]);
    // ---- rescale O ----
#pragma unroll
    for (int mt = 0; mt < 2; ++mt)
#pragma unroll
      for (int nt = 0; nt < 8; ++nt)
#pragma unroll
        for (int r = 0; r < 4; ++r)
          oacc[mt][nt][r] *= alpha[mt][r];

    if (more) asm volatile("s_waitcnt vmcnt(6)" ::: "memory");  // V(c) landed; K(c+1) flying
    else      asm volatile("s_waitcnt vmcnt(0)" ::: "memory");
    __builtin_amdgcn_s_barrier();          // V(c) visible blockwide
    __builtin_amdgcn_sched_barrier(0);

    // ---- PV on V(c) ----
    __builtin_amdgcn_s_setprio(1);
#pragma unroll
    for (int st = 0; st < 2; ++st) {
      short8 pf[2];
#pragma unroll
      for (int mt = 0; mt < 2; ++mt)
        pf[mt] = *(const short8*)&Pb[wq][(mt * 16 + l15) * 72 + st * 32 + quad * 8];
#pragma unroll
      for (int nt = 0; nt < 8; ++nt) {
        const short8 vf = *(const short8*)&Vt[(nt * 16 + l15) * 64 + (((st * 4 + quad) ^ (l15 & 7)) << 3)];
#pragma unroll
        for (int mt = 0; mt < 2; ++mt)
          oacc[mt][nt] = __builtin_amdgcn_mfma_f32_16x16x32_bf16(pf[mt], vf, oacc[mt][nt], 0, 0, 0);
      }
    }
    __builtin_amdgcn_s_setprio(0);

    __builtin_amdgcn_s_barrier();          // all waves done reading Vt
    if (more) {
      issueV(c + 1);                       // DMA into Vt, flies under next QK
      __builtin_amdgcn_sched_barrier(0);
      asm volatile("s_waitcnt vmcnt(4)" ::: "memory");  // K(c+1) landed; V(c+1) flying
      __builtin_amdgcn_s_barrier();        // K(c+1) visible blockwide
      __builtin_amdgcn_sched_barrier(0);
    }
  }

  // ---- store (bf16) ----
#pragma unroll
  for (int mt = 0; mt < 2; ++mt)
#pragma unroll
    for (int r = 0; r < 4; ++r) {
      const float inv = 1.0f / lrow[mt][r];
      const size_t orow = growq + mt * 16 + quad * 4 + r;
#pragma unroll
      for (int nt = 0; nt < 8; ++nt)
        outp[orow * 2048 + h * 128 + nt * 16 + l15] = f2bf(oacc[mt][nt][r] * inv);
    }
}

extern "C" void kernel_launch(void* const* d_in, const int* in_sizes, int n_in,
                              void* d_out, int out_size, void* d_ws, size_t ws_size,
                              hipStream_t stream) {
  const float* x        = (const float*)d_in[0];
  const float* wd_q     = (const float*)d_in[1];
  const float* wu_q     = (const float*)d_in[2];
  const float* q_norm_w = (const float*)d_in[3];
  const float* wd_kv    = (const float*)d_in[4];
  const float* wu_kv    = (const float*)d_in[5];
  const float* kv_norm_w= (const float*)d_in[6];
  const float* wo       = (const float*)d_in[7];
  const float* cosb     = (const float*)d_in[8];
  const float* sinb     = (const float*)d_in[9];
  float* out = (float*)d_out;

  char* ws = (char*)d_ws;
  float*    qall  = (float*)(ws + 0);            // 4096x3072 f32; cq aliases @0
  float*    cq    = (float*)(ws + 0);
  ushort_t* kb16  = (ushort_t*)(ws + 50331648);  // 4096x2048 bf16 K rows (16MB)
  ushort_t* vT    = (ushort_t*)(ws + 67108864);  // [b*16+h][128 vd][2048 tok] bf16 (16MB)
  ushort_t* xb    = (ushort_t*)(ws + 83886080);  // 4096x2048 bf16 pre-cast x (16MB)
  ushort_t* cqn   = (ushort_t*)(ws + 117440512); // 4096x1536 bf16
  float*    kvd   = (float*)(ws + 130023424);    // 4096x640 f32 (dead after rope)
  ushort_t* ckvn  = (ushort_t*)(ws + 140509184); // 4096x512 bf16 (dead after kvu gemm)
  ushort_t* aoutb = (ushort_t*)(ws + 130023424); // 4096x2048 bf16, aliases kvd+ckvn
  ushort_t* krope16 = (ushort_t*)(ws + 146800640); // 4096x64 bf16
  ushort_t* wdqt  = (ushort_t*)(ws + 147849216); // 1536x2048 bf16
  ushort_t* wdkvt = (ushort_t*)(ws + 154140672); // 640x2048 bf16
  ushort_t* wuqt  = (ushort_t*)(ws + 156762112); // 3072x1536 bf16
  ushort_t* wukvt = (ushort_t*)(ws + 166199296); // 4096x512 bf16
  ushort_t* wot   = (ushort_t*)(ws + 170393600); // 2048x2048 bf16

  const int M = 2 * S_LEN;  // 4096
  dim3 blk(256);

  cast_f32_bf16_k<<<4096, blk, 0, stream>>>(x, xb);

  transpose_cast_k<<<dim3(1536 / 32, 2048 / 32), blk, 0, stream>>>(wd_q, wdqt, 2048, 1536);
  transpose_cast_k<<<dim3(640 / 32, 2048 / 32), blk, 0, stream>>>(wd_kv, wdkvt, 2048, 576);
  transpose_cast_k<<<dim3(3072 / 32, 1536 / 32), blk, 0, stream>>>(wu_q, wuqt, 1536, 3072);
  transpose_cast_k<<<dim3(4096 / 32, 512 / 32), blk, 0, stream>>>(wu_kv, wukvt, 512, 4096);
  transpose_cast_k<<<dim3(2048 / 32, 2048 / 32), blk, 0, stream>>>(wo, wot, 2048, 2048);

  mfma_gemm<0><<<dim3(1536 / 128, M / 128), blk, 0, stream>>>(
      xb, wdqt, cq, M, 1536, 2048, 1536, nullptr, nullptr);
  mfma_gemm<0><<<dim3(640 / 128, M / 128), blk, 0, stream>>>(
      xb, wdkvt, kvd, M, 640, 2048, 640, nullptr, nullptr);
  rmsnorm_k<<<M, 256, 0, stream>>>(cq, 1536, cqn, 1536, q_norm_w, 1536);
  rmsnorm_k<<<M, 256, 0, stream>>>(kvd, 640, ckvn, 512, kv_norm_w, 512);
  mfma_gemm<0><<<dim3(3072 / 128, M / 128), blk, 0, stream>>>(
      cqn, wuqt, qall, M, 3072, 1536, 3072, nullptr, nullptr);
  mfma_gemm<1><<<dim3(4096 / 128, M / 128), blk, 0, stream>>>(
      ckvn, wukvt, nullptr, M, 4096, 512, 0, kb16, vT);
  rope_k<<<M, 512, 0, stream>>>(qall, kvd, krope16, cosb, sinb);
  attn_k<<<2 * NHEAD * (S_LEN / QT), 256, 0, stream>>>(qall, kb16, vT, krope16, aoutb);
  mfma_gemm<0><<<dim3(2048 / 128, M / 128), blk, 0, stream>>>(
      aoutb, wot, out, M, 2048, 2048, 2048, nullptr, nullptr);
}

// Round 5
// 511.733 us; speedup vs baseline: 1.7067x; 1.0844x over previous
//
#include <hip/hip_runtime.h>
#include <hip/hip_bf16.h>

#define S_LEN 2048
#define NHEAD 16
#define NOPE 128
#define ROPE 64
#define HD 192   // nope + rope

typedef unsigned short ushort_t;
typedef __attribute__((ext_vector_type(8))) short short8;
typedef __attribute__((ext_vector_type(4))) float f32x4;

#define AS1 __attribute__((address_space(1)))
#define AS3 __attribute__((address_space(3)))

__device__ __forceinline__ unsigned short f2bf(float f) {
  unsigned int u = __float_as_uint(f);
  return (unsigned short)((u + 0x7FFFu + ((u >> 16) & 1u)) >> 16);
}

// ---------------- cast f32 -> bf16 ----------------
__global__ __launch_bounds__(256) void cast_f32_bf16_k(const float* __restrict__ in,
                                                       ushort_t* __restrict__ out) {
  const int i = blockIdx.x * 256 + threadIdx.x;
  const float4 v0 = *(const float4*)&in[(size_t)i * 8];
  const float4 v1 = *(const float4*)&in[(size_t)i * 8 + 4];
  union { uint4 u; ushort_t s[8]; } pk;
  pk.s[0] = f2bf(v0.x); pk.s[1] = f2bf(v0.y); pk.s[2] = f2bf(v0.z); pk.s[3] = f2bf(v0.w);
  pk.s[4] = f2bf(v1.x); pk.s[5] = f2bf(v1.y); pk.s[6] = f2bf(v1.z); pk.s[7] = f2bf(v1.w);
  *(uint4*)&out[(size_t)i * 8] = pk.u;
}

// ---------------- transpose + cast: B f32 [K][N] -> Bt bf16 [Npad][K] ----------------
__global__ __launch_bounds__(256) void transpose_cast_k(const float* __restrict__ B,
                                                        ushort_t* __restrict__ Bt,
                                                        int K, int N) {
  __shared__ float tile[32][33];
  const int tx = threadIdx.x & 31, ty = threadIdx.x >> 5;  // 32 x 8
  const int n0 = blockIdx.x * 32, k0 = blockIdx.y * 32;
  if (n0 >= N) {
#pragma unroll
    for (int r = 0; r < 4; ++r)
      Bt[(size_t)(n0 + ty + 8 * r) * K + k0 + tx] = 0;
    return;
  }
#pragma unroll
  for (int r = 0; r < 4; ++r)
    tile[ty + 8 * r][tx] = B[(size_t)(k0 + ty + 8 * r) * N + n0 + tx];
  __syncthreads();
#pragma unroll
  for (int r = 0; r < 4; ++r)
    Bt[(size_t)(n0 + ty + 8 * r) * K + k0 + tx] = f2bf(tile[tx][ty + 8 * r]);
}

// ---------------- MFMA GEMM (bf16 A/B; global_load_lds staging; XCD swizzle) ----------
// EPI=0: f32 row-major C.
// EPI=1: KV split epilogue (kvu GEMM, N=4096 = 16 heads x [128 K | 128 V]).
// EPI=2: fused down-proj epilogue: n0<1536 -> C (cq, ld 1536); else C2 (kvd, ld 640).
template<int EPI>
__global__ __launch_bounds__(256) void mfma_gemm(const ushort_t* __restrict__ A,
                                                 const ushort_t* __restrict__ Bt,
                                                 float* __restrict__ C,
                                                 int M, int N, int K, int ldc,
                                                 ushort_t* __restrict__ kb16o,
                                                 ushort_t* __restrict__ vto,
                                                 float* __restrict__ C2) {
  __shared__ ushort_t As[128 * 32];
  __shared__ ushort_t Bs[128 * 32];
  const int tid = threadIdx.x;
  const int lane = tid & 63;
  const int wave = tid >> 6;
  const int wm = wave & 1, wn = wave >> 1;

  // XCD-aware bijective swizzle (grids here all have nwg % 8 == 0)
  unsigned bxu = blockIdx.x, byu = blockIdx.y;
  {
    const unsigned gx = gridDim.x;
    const unsigned nwg = gx * gridDim.y;
    if ((nwg & 7u) == 0u) {
      unsigned flat = byu * gx + bxu;
      const unsigned cpx = nwg >> 3;
      flat = (flat & 7u) * cpx + (flat >> 3);
      bxu = flat % gx; byu = flat / gx;
    }
  }
  const int m0 = byu * 128, n0 = bxu * 128;
  const int l15 = lane & 15, quad = lane >> 4;

  f32x4 acc[4][4] = {};

  const int it0 = tid, it1 = tid + 256;
  const int ma0 = it0 >> 2, kc0 = it0 & 3;
  const int ma1 = it1 >> 2, kc1 = it1 & 3;

  typedef AS3 ushort_t lds_us;
  lds_us* AsL = (lds_us*)As;
  lds_us* BsL = (lds_us*)Bs;
  const int wbase = wave * 512;   // shorts: 64 lanes * 8 shorts

  for (int k0 = 0; k0 < K; k0 += 32) {
    __builtin_amdgcn_global_load_lds(
        (const AS1 void*)&A[(size_t)(m0 + ma0) * K + k0 + kc0 * 8],
        (AS3 void*)(AsL + wbase), 16, 0, 0);
    __builtin_amdgcn_global_load_lds(
        (const AS1 void*)&A[(size_t)(m0 + ma1) * K + k0 + kc1 * 8],
        (AS3 void*)(AsL + 2048 + wbase), 16, 0, 0);
    __builtin_amdgcn_global_load_lds(
        (const AS1 void*)&Bt[(size_t)(n0 + ma0) * K + k0 + kc0 * 8],
        (AS3 void*)(BsL + wbase), 16, 0, 0);
    __builtin_amdgcn_global_load_lds(
        (const AS1 void*)&Bt[(size_t)(n0 + ma1) * K + k0 + kc1 * 8],
        (AS3 void*)(BsL + 2048 + wbase), 16, 0, 0);
    __syncthreads();

    short8 af[4], bf[4];
#pragma unroll
    for (int i = 0; i < 4; ++i)
      af[i] = *(const short8*)&As[(wm * 64 + i * 16 + l15) * 32 + quad * 8];
#pragma unroll
    for (int j = 0; j < 4; ++j)
      bf[j] = *(const short8*)&Bs[(wn * 64 + j * 16 + l15) * 32 + quad * 8];
#pragma unroll
    for (int i = 0; i < 4; ++i)
#pragma unroll
      for (int j = 0; j < 4; ++j)
        acc[i][j] = __builtin_amdgcn_mfma_f32_16x16x32_bf16(af[i], bf[j], acc[i][j], 0, 0, 0);
    __syncthreads();
  }

  if constexpr (EPI == 0) {
#pragma unroll
    for (int i = 0; i < 4; ++i)
#pragma unroll
      for (int r = 0; r < 4; ++r) {
        const size_t rg = (size_t)(m0 + wm * 64 + i * 16 + quad * 4 + r);
#pragma unroll
        for (int j = 0; j < 4; ++j)
          C[rg * ldc + n0 + wn * 64 + j * 16 + l15] = acc[i][j][r];
      }
  } else if constexpr (EPI == 1) {
    const int h = n0 >> 8;
    const bool is_v = (n0 >> 7) & 1;
    if (!is_v) {
#pragma unroll
      for (int i = 0; i < 4; ++i)
#pragma unroll
        for (int r = 0; r < 4; ++r) {
          const size_t rg = (size_t)(m0 + wm * 64 + i * 16 + quad * 4 + r);
#pragma unroll
          for (int j = 0; j < 4; ++j)
            kb16o[rg * 2048 + h * 128 + wn * 64 + j * 16 + l15] = f2bf(acc[i][j][r]);
        }
    } else {
      __shared__ __align__(16) ushort_t trb[64 * 136];
      const int bb = m0 >> 11;
      const int m0loc = m0 & 2047;
      ushort_t* vbase = vto + ((size_t)(bb * NHEAD + h) * 128) * 2048;
#pragma unroll
      for (int vh = 0; vh < 2; ++vh) {
        if (wn == vh) {
#pragma unroll
          for (int i = 0; i < 4; ++i)
#pragma unroll
            for (int r = 0; r < 4; ++r) {
              const int tloc = wm * 64 + i * 16 + quad * 4 + r;
#pragma unroll
              for (int j = 0; j < 4; ++j)
                trb[(j * 16 + l15) * 136 + tloc] = f2bf(acc[i][j][r]);
            }
        }
        __syncthreads();
#pragma unroll
        for (int it = 0; it < 4; ++it) {
          const int u = tid + (it << 8);
          const int vdl = u >> 4, tc = u & 15;
          *(uint4*)&vbase[(size_t)(vh * 64 + vdl) * 2048 + m0loc + tc * 8] =
              *(const uint4*)&trb[vdl * 136 + tc * 8];
        }
        __syncthreads();
      }
    }
  } else {  // EPI == 2: fused down-proj routing
    float* Cd;
    int ldd, nc;
    if (n0 < 1536) { Cd = C;  ldd = 1536; nc = n0; }
    else           { Cd = C2; ldd = 640;  nc = n0 - 1536; }
#pragma unroll
    for (int i = 0; i < 4; ++i)
#pragma unroll
      for (int r = 0; r < 4; ++r) {
        const size_t rg = (size_t)(m0 + wm * 64 + i * 16 + quad * 4 + r);
#pragma unroll
        for (int j = 0; j < 4; ++j)
          Cd[rg * ldd + nc + wn * 64 + j * 16 + l15] = acc[i][j][r];
      }
  }
}

// ---------------- merged RMSNorm (q rows then kv rows): f32 in -> bf16 out --------
__global__ __launch_bounds__(256) void rmsnorm2_k(const float* __restrict__ cq,
                                                  ushort_t* __restrict__ cqn,
                                                  const float* __restrict__ qw,
                                                  const float* __restrict__ kvd,
                                                  ushort_t* __restrict__ ckvn,
                                                  const float* __restrict__ kvw) {
  const bool is_q = blockIdx.x < 4096;
  const int row = blockIdx.x & 4095;
  const int tid = threadIdx.x;
  const float* ip = is_q ? cq + (size_t)row * 1536 : kvd + (size_t)row * 640;
  ushort_t* op = is_q ? cqn + (size_t)row * 1536 : ckvn + (size_t)row * 512;
  const float* w = is_q ? qw : kvw;
  const int L = is_q ? 1536 : 512;
  const int nper = L >> 8;
  float r[6];
  float ss = 0.f;
  for (int j = 0; j < nper; ++j) {
    r[j] = ip[tid + (j << 8)];
    ss += r[j] * r[j];
  }
  for (int off = 32; off; off >>= 1) ss += __shfl_down(ss, off);
  __shared__ float wsum[4];
  __shared__ float scale_s;
  if ((tid & 63) == 0) wsum[tid >> 6] = ss;
  __syncthreads();
  if (tid == 0) {
    float t = wsum[0] + wsum[1] + wsum[2] + wsum[3];
    scale_s = rsqrtf(t / (float)L + 1e-5f);
  }
  __syncthreads();
  const float sc = scale_s;
  for (int j = 0; j < nper; ++j)
    op[tid + (j << 8)] = f2bf(r[j] * sc * w[tid + (j << 8)]);
}

// ---------------- RoPE (krope emitted as bf16) ----------------
__global__ __launch_bounds__(512) void rope_k(float* __restrict__ qall,
                                              const float* __restrict__ kvd,
                                              ushort_t* __restrict__ krope16,
                                              const float* __restrict__ cosb,
                                              const float* __restrict__ sinb) {
  const int row = blockIdx.x;
  const int s = row & (S_LEN - 1);
  const int tid = threadIdx.x;
  const int d = tid & 31, h = tid >> 5;
  const float c = cosb[s * 32 + d];
  const float sn = sinb[s * 32 + d];
  float* qb = qall + (size_t)row * 3072 + h * HD + NOPE;
  float x0 = qb[2 * d], x1 = qb[2 * d + 1];
  qb[2 * d]     = x0 * c - x1 * sn;
  qb[2 * d + 1] = x0 * sn + x1 * c;
  if (tid < 32) {
    const float* kb = kvd + (size_t)row * 640 + 512;
    float y0 = kb[2 * d], y1 = kb[2 * d + 1];
    union { unsigned int u; ushort_t s2[2]; } pk;
    pk.s2[0] = f2bf(y0 * c - y1 * sn);
    pk.s2[1] = f2bf(y0 * sn + y1 * c);
    *(unsigned int*)&krope16[(size_t)row * 64 + 2 * d] = pk.u;
  }
}

// ---------------- MFMA flash attention ----------------
// Round 5: V double-buffered in LDS (one fewer barrier/chunk); scale folded
// into Q fragments; mask applied only on diagonal chunks; fully-masked
// wave-chunks skip all compute (wave-uniform); T13 defer-max (THR=8) skips
// alpha + O-rescale when the chunk max doesn't grow.
#define QT 128
#define KC 64
__global__ __launch_bounds__(256, 2) void attn_k(const float* __restrict__ qall,
                                                 const ushort_t* __restrict__ kb16,
                                                 const ushort_t* __restrict__ vT,
                                                 const ushort_t* __restrict__ krope16,
                                                 ushort_t* __restrict__ outp) {
  const int bx = blockIdx.x;
  const int second = bx >> 8;
  const int h = (bx >> 4) & 15;
  int tile = bx & 15;
  if (second) tile = 15 - tile;       // complementary pairing across grid halves
  const int b = second;
  const int q0 = tile * QT;
  const int tid = threadIdx.x;
  const int lane = tid & 63;
  const int wq = tid >> 6;
  const int l15 = lane & 15, quad = lane >> 4;

  __shared__ __align__(16) ushort_t Kn[64 * 128];    // 16 KB
  __shared__ __align__(16) ushort_t Kr[64 * 64];     //  8 KB
  __shared__ __align__(16) ushort_t Vt[2][128 * 64]; // 32 KB (double buffer)
  __shared__ __align__(16) ushort_t Pb[4][32 * 72];  // 18 KB

  const int qbase = q0 + wq * 32;
  const size_t growq = (size_t)b * S_LEN + qbase;
  const ushort_t* vTh = vT + ((size_t)(b * NHEAD + h) * 128) * 2048;
  const size_t bbase = (size_t)b * S_LEN;

  typedef AS3 ushort_t lds_us;
  lds_us* KnL = (lds_us*)Kn;
  lds_us* KrL = (lds_us*)Kr;
  lds_us* VtL = (lds_us*)Vt;
  const int wbase = wq * 512;   // shorts (64 lanes x 8 shorts)

  auto issueK = [&](int c) {
    const size_t growk = bbase + (size_t)c * KC;
#pragma unroll
    for (int it = 0; it < 4; ++it) {
      const int u = tid + (it << 8);
      const int key = u >> 4, s = u & 15;
      const int ss = s ^ (key & 7);
      __builtin_amdgcn_global_load_lds(
          (const AS1 void*)&kb16[(growk + key) * 2048 + h * 128 + ss * 8],
          (AS3 void*)(KnL + wbase + it * 2048), 16, 0, 0);
    }
#pragma unroll
    for (int it = 0; it < 2; ++it) {
      const int u = tid + (it << 8);
      const int key = u >> 3, s = u & 7;
      const int ss = s ^ (key & 7);
      __builtin_amdgcn_global_load_lds(
          (const AS1 void*)&krope16[(growk + key) * 64 + ss * 8],
          (AS3 void*)(KrL + wbase + it * 2048), 16, 0, 0);
    }
  };
  auto issueV = [&](int c, int buf) {
    const int j0 = c * KC;
#pragma unroll
    for (int it = 0; it < 4; ++it) {
      const int u = tid + (it << 8);
      const int vd = u >> 3, s = u & 7;
      const int ss = s ^ (vd & 7);
      __builtin_amdgcn_global_load_lds(
          (const AS1 void*)&vTh[(size_t)vd * 2048 + j0 + ss * 8],
          (AS3 void*)(VtL + buf * 8192 + wbase + it * 2048), 16, 0, 0);
    }
  };

  // ---- prologue: issue K(0), V(0->buf0); Q prep hides DMA latency ----
  issueK(0);
  issueV(0, 0);
  __builtin_amdgcn_sched_barrier(0);

  const float scale = 0.07216878364870323f;  // 1/sqrt(192), folded into Q
  short8 qf[2][6];
#pragma unroll
  for (int mt = 0; mt < 2; ++mt)
#pragma unroll
    for (int ks = 0; ks < 6; ++ks) {
      const float* src = &qall[(growq + mt * 16 + l15) * 3072 + h * HD + ks * 32 + quad * 8];
      const float4 v0 = *(const float4*)src;
      const float4 v1 = *(const float4*)(src + 4);
      union { short8 s8; ushort_t u[8]; } pk;
      pk.u[0] = f2bf(v0.x * scale); pk.u[1] = f2bf(v0.y * scale);
      pk.u[2] = f2bf(v0.z * scale); pk.u[3] = f2bf(v0.w * scale);
      pk.u[4] = f2bf(v1.x * scale); pk.u[5] = f2bf(v1.y * scale);
      pk.u[6] = f2bf(v1.z * scale); pk.u[7] = f2bf(v1.w * scale);
      qf[mt][ks] = pk.s8;
    }

  f32x4 oacc[2][8] = {};
  float mrow[2][4], lrow[2][4];
  int q_r[2][4];
#pragma unroll
  for (int mt = 0; mt < 2; ++mt)
#pragma unroll
    for (int r = 0; r < 4; ++r) {
      mrow[mt][r] = -1e30f; lrow[mt][r] = 0.f;
      q_r[mt][r] = qbase + mt * 16 + quad * 4 + r;
    }

  const int nchunk = (q0 + QT) / KC;

  asm volatile("s_waitcnt vmcnt(4)" ::: "memory");   // K(0) landed (V may fly)
  __builtin_amdgcn_s_barrier();
  __builtin_amdgcn_sched_barrier(0);

  for (int c = 0; c < nchunk; ++c) {
    const int j0 = c * KC;
    const bool more = (c + 1 < nchunk);
    const int buf = c & 1;
    const bool skipw = (j0 > qbase + 31);       // chunk entirely above diagonal for this wave

    // ---- QK^T on K(c) ----
    f32x4 sacc[2][4] = {};
    if (!skipw) {
      __builtin_amdgcn_s_setprio(1);
#pragma unroll
      for (int ks = 0; ks < 6; ++ks) {
        short8 kf[4];
        if (ks < 4) {
#pragma unroll
          for (int kt = 0; kt < 4; ++kt)
            kf[kt] = *(const short8*)&Kn[(kt * 16 + l15) * 128 + (((ks * 4 + quad) ^ (l15 & 7)) << 3)];
        } else {
#pragma unroll
          for (int kt = 0; kt < 4; ++kt)
            kf[kt] = *(const short8*)&Kr[(kt * 16 + l15) * 64 + ((((ks - 4) * 4 + quad) ^ (l15 & 7)) << 3)];
        }
#pragma unroll
        for (int mt = 0; mt < 2; ++mt)
#pragma unroll
          for (int kt = 0; kt < 4; ++kt)
            sacc[mt][kt] = __builtin_amdgcn_mfma_f32_16x16x32_bf16(qf[mt][ks], kf[kt], sacc[mt][kt], 0, 0, 0);
      }
      __builtin_amdgcn_s_setprio(0);
    }

    __builtin_amdgcn_s_barrier();          // all waves done reading Kn/Kr
    if (more) issueK(c + 1);               // DMA into Kn/Kr, flies under softmax+PV
    __builtin_amdgcn_sched_barrier(0);

    if (!skipw) {
      // ---- mask (diagonal chunks only; scale already folded into Q) ----
      if (j0 + KC - 1 > qbase) {
#pragma unroll
        for (int mt = 0; mt < 2; ++mt)
#pragma unroll
          for (int kt = 0; kt < 4; ++kt) {
            const int key = j0 + kt * 16 + l15;
#pragma unroll
            for (int r = 0; r < 4; ++r)
              sacc[mt][kt][r] = (key <= q_r[mt][r]) ? sacc[mt][kt][r] : -1e30f;
          }
      }
      // ---- chunk max ----
      float pmax[2][4];
#pragma unroll
      for (int mt = 0; mt < 2; ++mt)
#pragma unroll
        for (int r = 0; r < 4; ++r) {
          float mx = fmaxf(fmaxf(sacc[mt][0][r], sacc[mt][1][r]),
                           fmaxf(sacc[mt][2][r], sacc[mt][3][r]));
          mx = fmaxf(mx, __shfl_xor(mx, 1));
          mx = fmaxf(mx, __shfl_xor(mx, 2));
          mx = fmaxf(mx, __shfl_xor(mx, 4));
          mx = fmaxf(mx, __shfl_xor(mx, 8));
          pmax[mt][r] = mx;
        }
      // ---- T13 defer-max: only rescale when max grew past THR ----
      bool need = false;
#pragma unroll
      for (int mt = 0; mt < 2; ++mt)
#pragma unroll
        for (int r = 0; r < 4; ++r)
          need = need || (pmax[mt][r] > mrow[mt][r] + 8.0f);
      const bool upd = __any(need);
      float alpha[2][4];
      if (upd) {
#pragma unroll
        for (int mt = 0; mt < 2; ++mt)
#pragma unroll
          for (int r = 0; r < 4; ++r) {
            const float mn = fmaxf(mrow[mt][r], pmax[mt][r]);
            alpha[mt][r] = __expf(mrow[mt][r] - mn);
            mrow[mt][r] = mn;
          }
      }
      // ---- exp + row sums ----
#pragma unroll
      for (int mt = 0; mt < 2; ++mt)
#pragma unroll
        for (int kt = 0; kt < 4; ++kt)
#pragma unroll
          for (int r = 0; r < 4; ++r)
            sacc[mt][kt][r] = __expf(sacc[mt][kt][r] - mrow[mt][r]);
#pragma unroll
      for (int mt = 0; mt < 2; ++mt)
#pragma unroll
        for (int r = 0; r < 4; ++r) {
          float rs = sacc[mt][0][r] + sacc[mt][1][r] + sacc[mt][2][r] + sacc[mt][3][r];
          rs += __shfl_xor(rs, 1);
          rs += __shfl_xor(rs, 2);
          rs += __shfl_xor(rs, 4);
          rs += __shfl_xor(rs, 8);
          lrow[mt][r] = upd ? lrow[mt][r] * alpha[mt][r] + rs : lrow[mt][r] + rs;
        }
      // ---- write P (bf16) to per-wave-private LDS ----
#pragma unroll
      for (int mt = 0; mt < 2; ++mt)
#pragma unroll
        for (int kt = 0; kt < 4; ++kt)
#pragma unroll
          for (int r = 0; r < 4; ++r)
            Pb[wq][(mt * 16 + quad * 4 + r) * 72 + kt * 16 + l15] = f2bf(sacc[mt][kt][r]);
      // ---- rescale O (only when max grew) ----
      if (upd) {
#pragma unroll
        for (int mt = 0; mt < 2; ++mt)
#pragma unroll
          for (int nt = 0; nt < 8; ++nt)
#pragma unroll
            for (int r = 0; r < 4; ++r)
              oacc[mt][nt][r] *= alpha[mt][r];
      }
    }

    if (more) asm volatile("s_waitcnt vmcnt(6)" ::: "memory");  // V(c) landed; K(c+1) flying
    else      asm volatile("s_waitcnt vmcnt(0)" ::: "memory");
    __builtin_amdgcn_s_barrier();          // Vt[buf] visible blockwide
    __builtin_amdgcn_sched_barrier(0);

    // ---- PV on Vt[buf] ----
    if (!skipw) {
      __builtin_amdgcn_s_setprio(1);
#pragma unroll
      for (int st = 0; st < 2; ++st) {
        short8 pf[2];
#pragma unroll
        for (int mt = 0; mt < 2; ++mt)
          pf[mt] = *(const short8*)&Pb[wq][(mt * 16 + l15) * 72 + st * 32 + quad * 8];
#pragma unroll
        for (int nt = 0; nt < 8; ++nt) {
          const short8 vf = *(const short8*)&Vt[buf][(nt * 16 + l15) * 64 + (((st * 4 + quad) ^ (l15 & 7)) << 3)];
#pragma unroll
          for (int mt = 0; mt < 2; ++mt)
            oacc[mt][nt] = __builtin_amdgcn_mfma_f32_16x16x32_bf16(pf[mt], vf, oacc[mt][nt], 0, 0, 0);
        }
      }
      __builtin_amdgcn_s_setprio(0);
    }

    if (more) {
      issueV(c + 1, buf ^ 1);              // writes the OTHER buffer; no barrier needed
      __builtin_amdgcn_sched_barrier(0);
      asm volatile("s_waitcnt vmcnt(4)" ::: "memory");  // K(c+1) landed; V(c+1) flying
      __builtin_amdgcn_s_barrier();        // K(c+1) visible blockwide
      __builtin_amdgcn_sched_barrier(0);
    }
  }

  // ---- store (bf16) ----
#pragma unroll
  for (int mt = 0; mt < 2; ++mt)
#pragma unroll
    for (int r = 0; r < 4; ++r) {
      const float inv = 1.0f / lrow[mt][r];
      const size_t orow = growq + mt * 16 + quad * 4 + r;
#pragma unroll
      for (int nt = 0; nt < 8; ++nt)
        outp[orow * 2048 + h * 128 + nt * 16 + l15] = f2bf(oacc[mt][nt][r] * inv);
    }
}

extern "C" void kernel_launch(void* const* d_in, const int* in_sizes, int n_in,
                              void* d_out, int out_size, void* d_ws, size_t ws_size,
                              hipStream_t stream) {
  const float* x        = (const float*)d_in[0];
  const float* wd_q     = (const float*)d_in[1];
  const float* wu_q     = (const float*)d_in[2];
  const float* q_norm_w = (const float*)d_in[3];
  const float* wd_kv    = (const float*)d_in[4];
  const float* wu_kv    = (const float*)d_in[5];
  const float* kv_norm_w= (const float*)d_in[6];
  const float* wo       = (const float*)d_in[7];
  const float* cosb     = (const float*)d_in[8];
  const float* sinb     = (const float*)d_in[9];
  float* out = (float*)d_out;

  char* ws = (char*)d_ws;
  float*    qall  = (float*)(ws + 0);            // 4096x3072 f32; cq aliases @0
  float*    cq    = (float*)(ws + 0);
  ushort_t* kb16  = (ushort_t*)(ws + 50331648);  // 4096x2048 bf16 K rows (16MB)
  ushort_t* vT    = (ushort_t*)(ws + 67108864);  // [b*16+h][128 vd][2048 tok] bf16 (16MB)
  ushort_t* xb    = (ushort_t*)(ws + 83886080);  // 4096x2048 bf16 pre-cast x (16MB)
  ushort_t* cqn   = (ushort_t*)(ws + 117440512); // 4096x1536 bf16
  float*    kvd   = (float*)(ws + 130023424);    // 4096x640 f32 (dead after rope)
  ushort_t* ckvn  = (ushort_t*)(ws + 140509184); // 4096x512 bf16 (dead after kvu gemm)
  ushort_t* aoutb = (ushort_t*)(ws + 130023424); // 4096x2048 bf16, aliases kvd+ckvn
  ushort_t* krope16 = (ushort_t*)(ws + 146800640); // 4096x64 bf16
  ushort_t* wdqt  = (ushort_t*)(ws + 147849216); // 1536x2048 bf16  (contiguous with ->)
  ushort_t* wdkvt = (ushort_t*)(ws + 154140672); // 640x2048 bf16   (fused B = [wdqt;wdkvt])
  ushort_t* wuqt  = (ushort_t*)(ws + 156762112); // 3072x1536 bf16
  ushort_t* wukvt = (ushort_t*)(ws + 166199296); // 4096x512 bf16
  ushort_t* wot   = (ushort_t*)(ws + 170393600); // 2048x2048 bf16

  const int M = 2 * S_LEN;  // 4096
  dim3 blk(256);

  cast_f32_bf16_k<<<4096, blk, 0, stream>>>(x, xb);

  transpose_cast_k<<<dim3(1536 / 32, 2048 / 32), blk, 0, stream>>>(wd_q, wdqt, 2048, 1536);
  transpose_cast_k<<<dim3(640 / 32, 2048 / 32), blk, 0, stream>>>(wd_kv, wdkvt, 2048, 576);
  transpose_cast_k<<<dim3(3072 / 32, 1536 / 32), blk, 0, stream>>>(wu_q, wuqt, 1536, 3072);
  transpose_cast_k<<<dim3(4096 / 32, 512 / 32), blk, 0, stream>>>(wu_kv, wukvt, 512, 4096);
  transpose_cast_k<<<dim3(2048 / 32, 2048 / 32), blk, 0, stream>>>(wo, wot, 2048, 2048);

  // fused q-down + kv-down: N = 1536 + 640 = 2176 (Bt rows contiguous in ws)
  mfma_gemm<2><<<dim3(2176 / 128, M / 128), blk, 0, stream>>>(
      xb, wdqt, cq, M, 2176, 2048, 1536, nullptr, nullptr, kvd);
  rmsnorm2_k<<<2 * M, 256, 0, stream>>>(cq, cqn, q_norm_w, kvd, ckvn, kv_norm_w);
  mfma_gemm<0><<<dim3(3072 / 128, M / 128), blk, 0, stream>>>(
      cqn, wuqt, qall, M, 3072, 1536, 3072, nullptr, nullptr, nullptr);
  mfma_gemm<1><<<dim3(4096 / 128, M / 128), blk, 0, stream>>>(
      ckvn, wukvt, nullptr, M, 4096, 512, 0, kb16, vT, nullptr);
  rope_k<<<M, 512, 0, stream>>>(qall, kvd, krope16, cosb, sinb);
  attn_k<<<2 * NHEAD * (S_LEN / QT), 256, 0, stream>>>(qall, kb16, vT, krope16, aoutb);
  mfma_gemm<0><<<dim3(2048 / 128, M / 128), blk, 0, stream>>>(
      aoutb, wot, out, M, 2048, 2048, 2048, nullptr, nullptr, nullptr);
}

// Round 6
// 496.499 us; speedup vs baseline: 1.7591x; 1.0307x over previous
//
#include <hip/hip_runtime.h>
#include <hip/hip_bf16.h>

#define S_LEN 2048
#define NHEAD 16
#define NOPE 128
#define ROPE 64
#define HD 192   // nope + rope

typedef unsigned short ushort_t;
typedef __attribute__((ext_vector_type(8))) short short8;
typedef __attribute__((ext_vector_type(4))) float f32x4;

#define AS1 __attribute__((address_space(1)))
#define AS3 __attribute__((address_space(3)))

__device__ __forceinline__ unsigned short f2bf(float f) {
  unsigned int u = __float_as_uint(f);
  return (unsigned short)((u + 0x7FFFu + ((u >> 16) & 1u)) >> 16);
}

// ---------------- fused prep: cast x -> bf16  +  5x transpose_cast ----------------
// id < 4096: cast x (4096 blk x 256 thr x 8 elems).
// then 5 transpose jobs, 32x32 tiles: (B f32 [K][N]) -> (Bt bf16 [Npad][K]).
__global__ __launch_bounds__(256) void prep_k(const float* __restrict__ x, ushort_t* __restrict__ xb,
                                              const float* __restrict__ wd_q, ushort_t* __restrict__ wdqt,
                                              const float* __restrict__ wd_kv, ushort_t* __restrict__ wdkvt,
                                              const float* __restrict__ wu_q, ushort_t* __restrict__ wuqt,
                                              const float* __restrict__ wu_kv, ushort_t* __restrict__ wukvt,
                                              const float* __restrict__ wo, ushort_t* __restrict__ wot) {
  int id = blockIdx.x;
  if (id < 4096) {
    const int i = id * 256 + threadIdx.x;
    const float4 v0 = *(const float4*)&x[(size_t)i * 8];
    const float4 v1 = *(const float4*)&x[(size_t)i * 8 + 4];
    union { uint4 u; ushort_t s[8]; } pk;
    pk.s[0] = f2bf(v0.x); pk.s[1] = f2bf(v0.y); pk.s[2] = f2bf(v0.z); pk.s[3] = f2bf(v0.w);
    pk.s[4] = f2bf(v1.x); pk.s[5] = f2bf(v1.y); pk.s[6] = f2bf(v1.z); pk.s[7] = f2bf(v1.w);
    *(uint4*)&xb[(size_t)i * 8] = pk.u;
    return;
  }
  id -= 4096;
  const float* B; ushort_t* Bt; int K, N, gx;
  if (id < 3072)               { B = wd_q;  Bt = wdqt;  K = 2048; N = 1536; gx = 48;  }
  else if ((id -= 3072) < 1280){ B = wd_kv; Bt = wdkvt; K = 2048; N = 576;  gx = 20;  }
  else if ((id -= 1280) < 4608){ B = wu_q;  Bt = wuqt;  K = 1536; N = 3072; gx = 96;  }
  else if ((id -= 4608) < 2048){ B = wu_kv; Bt = wukvt; K = 512;  N = 4096; gx = 128; }
  else { id -= 2048;             B = wo;    Bt = wot;   K = 2048; N = 2048; gx = 64;  }
  __shared__ float tile[32][33];
  const int tx = threadIdx.x & 31, ty = threadIdx.x >> 5;  // 32 x 8
  const int n0 = (id % gx) * 32, k0 = (id / gx) * 32;
  if (n0 >= N) {
#pragma unroll
    for (int r = 0; r < 4; ++r)
      Bt[(size_t)(n0 + ty + 8 * r) * K + k0 + tx] = 0;
    return;
  }
#pragma unroll
  for (int r = 0; r < 4; ++r)
    tile[ty + 8 * r][tx] = B[(size_t)(k0 + ty + 8 * r) * N + n0 + tx];
  __syncthreads();
#pragma unroll
  for (int r = 0; r < 4; ++r)
    Bt[(size_t)(n0 + ty + 8 * r) * K + k0 + tx] = f2bf(tile[tx][ty + 8 * r]);
}

// ---------------- MFMA GEMM (bf16 A/B; global_load_lds staging; XCD swizzle) ----------
// EPI=0: f32 row-major C.
// EPI=1: KV split epilogue (kvu GEMM, N=4096 = 16 heads x [128 K | 128 V]).
// EPI=2: fused down-proj: n0<1536 -> C (cq, ld 1536); else C2 (kvd, ld 640).
// EPI=3: q-up: scale + RoPE + bf16 -> qo16 [row][3072].
template<int EPI>
__global__ __launch_bounds__(256) void mfma_gemm(const ushort_t* __restrict__ A,
                                                 const ushort_t* __restrict__ Bt,
                                                 float* __restrict__ C,
                                                 int M, int N, int K, int ldc,
                                                 ushort_t* __restrict__ kb16o,
                                                 ushort_t* __restrict__ vto,
                                                 float* __restrict__ C2,
                                                 const float* __restrict__ cosb,
                                                 const float* __restrict__ sinb) {
  __shared__ ushort_t As[128 * 32];
  __shared__ ushort_t Bs[128 * 32];
  const int tid = threadIdx.x;
  const int lane = tid & 63;
  const int wave = tid >> 6;
  const int wm = wave & 1, wn = wave >> 1;

  // XCD-aware bijective swizzle (grids here all have nwg % 8 == 0)
  unsigned bxu = blockIdx.x, byu = blockIdx.y;
  {
    const unsigned gx = gridDim.x;
    const unsigned nwg = gx * gridDim.y;
    if ((nwg & 7u) == 0u) {
      unsigned flat = byu * gx + bxu;
      const unsigned cpx = nwg >> 3;
      flat = (flat & 7u) * cpx + (flat >> 3);
      bxu = flat % gx; byu = flat / gx;
    }
  }
  const int m0 = byu * 128, n0 = bxu * 128;
  const int l15 = lane & 15, quad = lane >> 4;

  f32x4 acc[4][4] = {};

  const int it0 = tid, it1 = tid + 256;
  const int ma0 = it0 >> 2, kc0 = it0 & 3;
  const int ma1 = it1 >> 2, kc1 = it1 & 3;

  typedef AS3 ushort_t lds_us;
  lds_us* AsL = (lds_us*)As;
  lds_us* BsL = (lds_us*)Bs;
  const int wbase = wave * 512;   // shorts: 64 lanes * 8 shorts

  for (int k0 = 0; k0 < K; k0 += 32) {
    __builtin_amdgcn_global_load_lds(
        (const AS1 void*)&A[(size_t)(m0 + ma0) * K + k0 + kc0 * 8],
        (AS3 void*)(AsL + wbase), 16, 0, 0);
    __builtin_amdgcn_global_load_lds(
        (const AS1 void*)&A[(size_t)(m0 + ma1) * K + k0 + kc1 * 8],
        (AS3 void*)(AsL + 2048 + wbase), 16, 0, 0);
    __builtin_amdgcn_global_load_lds(
        (const AS1 void*)&Bt[(size_t)(n0 + ma0) * K + k0 + kc0 * 8],
        (AS3 void*)(BsL + wbase), 16, 0, 0);
    __builtin_amdgcn_global_load_lds(
        (const AS1 void*)&Bt[(size_t)(n0 + ma1) * K + k0 + kc1 * 8],
        (AS3 void*)(BsL + 2048 + wbase), 16, 0, 0);
    __syncthreads();

    short8 af[4], bf[4];
#pragma unroll
    for (int i = 0; i < 4; ++i)
      af[i] = *(const short8*)&As[(wm * 64 + i * 16 + l15) * 32 + quad * 8];
#pragma unroll
    for (int j = 0; j < 4; ++j)
      bf[j] = *(const short8*)&Bs[(wn * 64 + j * 16 + l15) * 32 + quad * 8];
#pragma unroll
    for (int i = 0; i < 4; ++i)
#pragma unroll
      for (int j = 0; j < 4; ++j)
        acc[i][j] = __builtin_amdgcn_mfma_f32_16x16x32_bf16(af[i], bf[j], acc[i][j], 0, 0, 0);
    __syncthreads();
  }

  if constexpr (EPI == 0) {
#pragma unroll
    for (int i = 0; i < 4; ++i)
#pragma unroll
      for (int r = 0; r < 4; ++r) {
        const size_t rg = (size_t)(m0 + wm * 64 + i * 16 + quad * 4 + r);
#pragma unroll
        for (int j = 0; j < 4; ++j)
          C[rg * ldc + n0 + wn * 64 + j * 16 + l15] = acc[i][j][r];
      }
  } else if constexpr (EPI == 1) {
    const int h = n0 >> 8;
    const bool is_v = (n0 >> 7) & 1;
    if (!is_v) {
#pragma unroll
      for (int i = 0; i < 4; ++i)
#pragma unroll
        for (int r = 0; r < 4; ++r) {
          const size_t rg = (size_t)(m0 + wm * 64 + i * 16 + quad * 4 + r);
#pragma unroll
          for (int j = 0; j < 4; ++j)
            kb16o[rg * 2048 + h * 128 + wn * 64 + j * 16 + l15] = f2bf(acc[i][j][r]);
        }
    } else {
      __shared__ __align__(16) ushort_t trb[64 * 136];
      const int bb = m0 >> 11;
      const int m0loc = m0 & 2047;
      ushort_t* vbase = vto + ((size_t)(bb * NHEAD + h) * 128) * 2048;
#pragma unroll
      for (int vh = 0; vh < 2; ++vh) {
        if (wn == vh) {
#pragma unroll
          for (int i = 0; i < 4; ++i)
#pragma unroll
            for (int r = 0; r < 4; ++r) {
              const int tloc = wm * 64 + i * 16 + quad * 4 + r;
#pragma unroll
              for (int j = 0; j < 4; ++j)
                trb[(j * 16 + l15) * 136 + tloc] = f2bf(acc[i][j][r]);
            }
        }
        __syncthreads();
#pragma unroll
        for (int it = 0; it < 4; ++it) {
          const int u = tid + (it << 8);
          const int vdl = u >> 4, tc = u & 15;
          *(uint4*)&vbase[(size_t)(vh * 64 + vdl) * 2048 + m0loc + tc * 8] =
              *(const uint4*)&trb[vdl * 136 + tc * 8];
        }
        __syncthreads();
      }
    }
  } else if constexpr (EPI == 2) {  // fused down-proj routing
    float* Cd;
    int ldd, nc;
    if (n0 < 1536) { Cd = C;  ldd = 1536; nc = n0; }
    else           { Cd = C2; ldd = 640;  nc = n0 - 1536; }
#pragma unroll
    for (int i = 0; i < 4; ++i)
#pragma unroll
      for (int r = 0; r < 4; ++r) {
        const size_t rg = (size_t)(m0 + wm * 64 + i * 16 + quad * 4 + r);
#pragma unroll
        for (int j = 0; j < 4; ++j)
          Cd[rg * ldd + nc + wn * 64 + j * 16 + l15] = acc[i][j][r];
      }
  } else {  // EPI == 3: q-up epilogue: scale + RoPE + bf16 -> qo16 (kb16o arg)
    const float qscale = 0.07216878364870323f;  // 1/sqrt(192)
#pragma unroll
    for (int i = 0; i < 4; ++i)
#pragma unroll
      for (int r = 0; r < 4; ++r) {
        const int rg = m0 + wm * 64 + i * 16 + quad * 4 + r;
        const int sp = rg & (S_LEN - 1);
#pragma unroll
        for (int j = 0; j < 4; ++j) {
          const int col = n0 + wn * 64 + j * 16 + l15;
          float val = acc[i][j][r] * qscale;
          const float pr = __shfl_xor(val, 1);   // adjacent column (same row)
          const int dd = col % HD;               // 0..191 within head
          float o = val;
          if (dd >= NOPE) {
            const int d = (dd - NOPE) >> 1;
            const float cc = cosb[sp * 32 + d];
            const float sn = sinb[sp * 32 + d];
            o = (lane & 1) ? (pr * sn + val * cc) : (val * cc - pr * sn);
          }
          kb16o[(size_t)rg * 3072 + col] = f2bf(o);
        }
      }
  }
}

// ---------------- merged RMSNorm (q rows then kv rows): f32 in -> bf16 out --------
__global__ __launch_bounds__(256) void rmsnorm2_k(const float* __restrict__ cq,
                                                  ushort_t* __restrict__ cqn,
                                                  const float* __restrict__ qw,
                                                  const float* __restrict__ kvd,
                                                  ushort_t* __restrict__ ckvn,
                                                  const float* __restrict__ kvw) {
  const bool is_q = blockIdx.x < 4096;
  const int row = blockIdx.x & 4095;
  const int tid = threadIdx.x;
  const float* ip = is_q ? cq + (size_t)row * 1536 : kvd + (size_t)row * 640;
  ushort_t* op = is_q ? cqn + (size_t)row * 1536 : ckvn + (size_t)row * 512;
  const float* w = is_q ? qw : kvw;
  const int L = is_q ? 1536 : 512;
  const int nper = L >> 8;
  float r[6];
  float ss = 0.f;
  for (int j = 0; j < nper; ++j) {
    r[j] = ip[tid + (j << 8)];
    ss += r[j] * r[j];
  }
  for (int off = 32; off; off >>= 1) ss += __shfl_down(ss, off);
  __shared__ float wsum[4];
  __shared__ float scale_s;
  if ((tid & 63) == 0) wsum[tid >> 6] = ss;
  __syncthreads();
  if (tid == 0) {
    float t = wsum[0] + wsum[1] + wsum[2] + wsum[3];
    scale_s = rsqrtf(t / (float)L + 1e-5f);
  }
  __syncthreads();
  const float sc = scale_s;
  for (int j = 0; j < nper; ++j)
    op[tid + (j << 8)] = f2bf(r[j] * sc * w[tid + (j << 8)]);
}

// ---------------- slim RoPE for k_rope only (kvd cols 512..639 -> krope16) --------
__global__ __launch_bounds__(256) void rope_kr_k(const float* __restrict__ kvd,
                                                 ushort_t* __restrict__ krope16,
                                                 const float* __restrict__ cosb,
                                                 const float* __restrict__ sinb) {
  const int tid = threadIdx.x;
  const int row = blockIdx.x * 8 + (tid >> 5);
  const int d = tid & 31;
  const int s = row & (S_LEN - 1);
  const float c = cosb[s * 32 + d];
  const float sn = sinb[s * 32 + d];
  const float* kb = kvd + (size_t)row * 640 + 512;
  const float y0 = kb[2 * d], y1 = kb[2 * d + 1];
  union { unsigned int u; ushort_t s2[2]; } pk;
  pk.s2[0] = f2bf(y0 * c - y1 * sn);
  pk.s2[1] = f2bf(y0 * sn + y1 * c);
  *(unsigned int*)&krope16[(size_t)row * 64 + 2 * d] = pk.u;
}

// ---------------- MFMA flash attention ----------------
// Round 6: XCD-locality block mapping — bx = slot*32 + g (g = b*16+h) puts all
// 16 q-tiles of a (b,h) group on ONE XCD (g%8): its K/V (~1MB/group x 4 groups)
// becomes L2-resident, turning the exposed K-prefetch wait from an HBM miss
// (~900cy) into an L2 hit (~200cy). Balanced CU pairing kept: slot s and s+8
// (same CU, grid 512) carry tiles s and 15-s -> 17+17 chunks.
// Q arrives pre-scaled, pre-roped, bf16 from the q-up GEMM epilogue.
#define QT 128
#define KC 64
__global__ __launch_bounds__(256, 2) void attn_k(const ushort_t* __restrict__ q16,
                                                 const ushort_t* __restrict__ kb16,
                                                 const ushort_t* __restrict__ vT,
                                                 const ushort_t* __restrict__ krope16,
                                                 ushort_t* __restrict__ outp) {
  const int bx = blockIdx.x;
  const int g = bx & 31;            // (b,h) group -> XCD g%8
  const int s = bx >> 5;            // slot 0..15
  const int tile = (s < 8) ? s : 23 - s;
  const int b = g >> 4, h = g & 15;
  const int q0 = tile * QT;
  const int tid = threadIdx.x;
  const int lane = tid & 63;
  const int wq = tid >> 6;
  const int l15 = lane & 15, quad = lane >> 4;

  __shared__ __align__(16) ushort_t Kn[64 * 128];    // 16 KB
  __shared__ __align__(16) ushort_t Kr[64 * 64];     //  8 KB
  __shared__ __align__(16) ushort_t Vt[2][128 * 64]; // 32 KB (double buffer)
  __shared__ __align__(16) ushort_t Pb[4][32 * 72];  // 18 KB

  const int qbase = q0 + wq * 32;
  const size_t growq = (size_t)b * S_LEN + qbase;
  const ushort_t* vTh = vT + ((size_t)(b * NHEAD + h) * 128) * 2048;
  const size_t bbase = (size_t)b * S_LEN;

  typedef AS3 ushort_t lds_us;
  lds_us* KnL = (lds_us*)Kn;
  lds_us* KrL = (lds_us*)Kr;
  lds_us* VtL = (lds_us*)Vt;
  const int wbase = wq * 512;   // shorts (64 lanes x 8 shorts)

  auto issueK = [&](int c) {
    const size_t growk = bbase + (size_t)c * KC;
#pragma unroll
    for (int it = 0; it < 4; ++it) {
      const int u = tid + (it << 8);
      const int key = u >> 4, sl = u & 15;
      const int ss = sl ^ (key & 7);
      __builtin_amdgcn_global_load_lds(
          (const AS1 void*)&kb16[(growk + key) * 2048 + h * 128 + ss * 8],
          (AS3 void*)(KnL + wbase + it * 2048), 16, 0, 0);
    }
#pragma unroll
    for (int it = 0; it < 2; ++it) {
      const int u = tid + (it << 8);
      const int key = u >> 3, sl = u & 7;
      const int ss = sl ^ (key & 7);
      __builtin_amdgcn_global_load_lds(
          (const AS1 void*)&krope16[(growk + key) * 64 + ss * 8],
          (AS3 void*)(KrL + wbase + it * 2048), 16, 0, 0);
    }
  };
  auto issueV = [&](int c, int buf) {
    const int j0 = c * KC;
#pragma unroll
    for (int it = 0; it < 4; ++it) {
      const int u = tid + (it << 8);
      const int vd = u >> 3, sl = u & 7;
      const int ss = sl ^ (vd & 7);
      __builtin_amdgcn_global_load_lds(
          (const AS1 void*)&vTh[(size_t)vd * 2048 + j0 + ss * 8],
          (AS3 void*)(VtL + buf * 8192 + wbase + it * 2048), 16, 0, 0);
    }
  };

  // ---- prologue: issue K(0), V(0->buf0); Q load hides DMA latency ----
  issueK(0);
  issueV(0, 0);
  __builtin_amdgcn_sched_barrier(0);

  // Q fragments (pre-scaled, pre-roped bf16) straight from global
  short8 qf[2][6];
#pragma unroll
  for (int mt = 0; mt < 2; ++mt)
#pragma unroll
    for (int ks = 0; ks < 6; ++ks)
      qf[mt][ks] = *(const short8*)&q16[(growq + mt * 16 + l15) * 3072 + h * HD + ks * 32 + quad * 8];

  f32x4 oacc[2][8] = {};
  float mrow[2][4], lrow[2][4];
  int q_r[2][4];
#pragma unroll
  for (int mt = 0; mt < 2; ++mt)
#pragma unroll
    for (int r = 0; r < 4; ++r) {
      mrow[mt][r] = -1e30f; lrow[mt][r] = 0.f;
      q_r[mt][r] = qbase + mt * 16 + quad * 4 + r;
    }

  const int nchunk = (q0 + QT) / KC;

  asm volatile("s_waitcnt vmcnt(4)" ::: "memory");   // K(0) landed (V may fly)
  __builtin_amdgcn_s_barrier();
  __builtin_amdgcn_sched_barrier(0);

  for (int c = 0; c < nchunk; ++c) {
    const int j0 = c * KC;
    const bool more = (c + 1 < nchunk);
    const int buf = c & 1;
    const bool skipw = (j0 > qbase + 31);       // chunk entirely above diagonal for this wave

    // ---- QK^T on K(c) ----
    f32x4 sacc[2][4] = {};
    if (!skipw) {
      __builtin_amdgcn_s_setprio(1);
#pragma unroll
      for (int ks = 0; ks < 6; ++ks) {
        short8 kf[4];
        if (ks < 4) {
#pragma unroll
          for (int kt = 0; kt < 4; ++kt)
            kf[kt] = *(const short8*)&Kn[(kt * 16 + l15) * 128 + (((ks * 4 + quad) ^ (l15 & 7)) << 3)];
        } else {
#pragma unroll
          for (int kt = 0; kt < 4; ++kt)
            kf[kt] = *(const short8*)&Kr[(kt * 16 + l15) * 64 + ((((ks - 4) * 4 + quad) ^ (l15 & 7)) << 3)];
        }
#pragma unroll
        for (int mt = 0; mt < 2; ++mt)
#pragma unroll
          for (int kt = 0; kt < 4; ++kt)
            sacc[mt][kt] = __builtin_amdgcn_mfma_f32_16x16x32_bf16(qf[mt][ks], kf[kt], sacc[mt][kt], 0, 0, 0);
      }
      __builtin_amdgcn_s_setprio(0);
    }

    __builtin_amdgcn_s_barrier();          // all waves done reading Kn/Kr
    if (more) issueK(c + 1);               // DMA into Kn/Kr, flies under softmax+PV
    __builtin_amdgcn_sched_barrier(0);

    if (!skipw) {
      // ---- mask (diagonal chunks only; scale folded upstream) ----
      if (j0 + KC - 1 > qbase) {
#pragma unroll
        for (int mt = 0; mt < 2; ++mt)
#pragma unroll
          for (int kt = 0; kt < 4; ++kt) {
            const int key = j0 + kt * 16 + l15;
#pragma unroll
            for (int r = 0; r < 4; ++r)
              sacc[mt][kt][r] = (key <= q_r[mt][r]) ? sacc[mt][kt][r] : -1e30f;
          }
      }
      // ---- chunk max ----
      float pmax[2][4];
#pragma unroll
      for (int mt = 0; mt < 2; ++mt)
#pragma unroll
        for (int r = 0; r < 4; ++r) {
          float mx = fmaxf(fmaxf(sacc[mt][0][r], sacc[mt][1][r]),
                           fmaxf(sacc[mt][2][r], sacc[mt][3][r]));
          mx = fmaxf(mx, __shfl_xor(mx, 1));
          mx = fmaxf(mx, __shfl_xor(mx, 2));
          mx = fmaxf(mx, __shfl_xor(mx, 4));
          mx = fmaxf(mx, __shfl_xor(mx, 8));
          pmax[mt][r] = mx;
        }
      // ---- T13 defer-max ----
      bool need = false;
#pragma unroll
      for (int mt = 0; mt < 2; ++mt)
#pragma unroll
        for (int r = 0; r < 4; ++r)
          need = need || (pmax[mt][r] > mrow[mt][r] + 8.0f);
      const bool upd = __any(need);
      float alpha[2][4];
      if (upd) {
#pragma unroll
        for (int mt = 0; mt < 2; ++mt)
#pragma unroll
          for (int r = 0; r < 4; ++r) {
            const float mn = fmaxf(mrow[mt][r], pmax[mt][r]);
            alpha[mt][r] = __expf(mrow[mt][r] - mn);
            mrow[mt][r] = mn;
          }
      }
      // ---- exp + row sums ----
#pragma unroll
      for (int mt = 0; mt < 2; ++mt)
#pragma unroll
        for (int kt = 0; kt < 4; ++kt)
#pragma unroll
          for (int r = 0; r < 4; ++r)
            sacc[mt][kt][r] = __expf(sacc[mt][kt][r] - mrow[mt][r]);
#pragma unroll
      for (int mt = 0; mt < 2; ++mt)
#pragma unroll
        for (int r = 0; r < 4; ++r) {
          float rs = sacc[mt][0][r] + sacc[mt][1][r] + sacc[mt][2][r] + sacc[mt][3][r];
          rs += __shfl_xor(rs, 1);
          rs += __shfl_xor(rs, 2);
          rs += __shfl_xor(rs, 4);
          rs += __shfl_xor(rs, 8);
          lrow[mt][r] = upd ? lrow[mt][r] * alpha[mt][r] + rs : lrow[mt][r] + rs;
        }
      // ---- write P (bf16) to per-wave-private LDS ----
#pragma unroll
      for (int mt = 0; mt < 2; ++mt)
#pragma unroll
        for (int kt = 0; kt < 4; ++kt)
#pragma unroll
          for (int r = 0; r < 4; ++r)
            Pb[wq][(mt * 16 + quad * 4 + r) * 72 + kt * 16 + l15] = f2bf(sacc[mt][kt][r]);
      // ---- rescale O (only when max grew) ----
      if (upd) {
#pragma unroll
        for (int mt = 0; mt < 2; ++mt)
#pragma unroll
          for (int nt = 0; nt < 8; ++nt)
#pragma unroll
            for (int r = 0; r < 4; ++r)
              oacc[mt][nt][r] *= alpha[mt][r];
      }
    }

    if (more) asm volatile("s_waitcnt vmcnt(6)" ::: "memory");  // V(c) landed; K(c+1) flying
    else      asm volatile("s_waitcnt vmcnt(0)" ::: "memory");
    __builtin_amdgcn_s_barrier();          // Vt[buf] visible blockwide
    __builtin_amdgcn_sched_barrier(0);

    // ---- PV on Vt[buf] ----
    if (!skipw) {
      __builtin_amdgcn_s_setprio(1);
#pragma unroll
      for (int st = 0; st < 2; ++st) {
        short8 pf[2];
#pragma unroll
        for (int mt = 0; mt < 2; ++mt)
          pf[mt] = *(const short8*)&Pb[wq][(mt * 16 + l15) * 72 + st * 32 + quad * 8];
#pragma unroll
        for (int nt = 0; nt < 8; ++nt) {
          const short8 vf = *(const short8*)&Vt[buf][(nt * 16 + l15) * 64 + (((st * 4 + quad) ^ (l15 & 7)) << 3)];
#pragma unroll
          for (int mt = 0; mt < 2; ++mt)
            oacc[mt][nt] = __builtin_amdgcn_mfma_f32_16x16x32_bf16(pf[mt], vf, oacc[mt][nt], 0, 0, 0);
        }
      }
      __builtin_amdgcn_s_setprio(0);
    }

    if (more) {
      issueV(c + 1, buf ^ 1);              // writes the OTHER buffer; no barrier needed
      __builtin_amdgcn_sched_barrier(0);
      asm volatile("s_waitcnt vmcnt(4)" ::: "memory");  // K(c+1) landed; V(c+1) flying
      __builtin_amdgcn_s_barrier();        // K(c+1) visible blockwide
      __builtin_amdgcn_sched_barrier(0);
    }
  }

  // ---- store (bf16) ----
#pragma unroll
  for (int mt = 0; mt < 2; ++mt)
#pragma unroll
    for (int r = 0; r < 4; ++r) {
      const float inv = 1.0f / lrow[mt][r];
      const size_t orow = growq + mt * 16 + quad * 4 + r;
#pragma unroll
      for (int nt = 0; nt < 8; ++nt)
        outp[orow * 2048 + h * 128 + nt * 16 + l15] = f2bf(oacc[mt][nt][r] * inv);
    }
}

extern "C" void kernel_launch(void* const* d_in, const int* in_sizes, int n_in,
                              void* d_out, int out_size, void* d_ws, size_t ws_size,
                              hipStream_t stream) {
  const float* x        = (const float*)d_in[0];
  const float* wd_q     = (const float*)d_in[1];
  const float* wu_q     = (const float*)d_in[2];
  const float* q_norm_w = (const float*)d_in[3];
  const float* wd_kv    = (const float*)d_in[4];
  const float* wu_kv    = (const float*)d_in[5];
  const float* kv_norm_w= (const float*)d_in[6];
  const float* wo       = (const float*)d_in[7];
  const float* cosb     = (const float*)d_in[8];
  const float* sinb     = (const float*)d_in[9];
  float* out = (float*)d_out;

  char* ws = (char*)d_ws;
  float*    cq    = (float*)(ws + 0);            // 4096x1536 f32 (dead after rmsnorm)
  ushort_t* q16   = (ushort_t*)(ws + 0);         // 4096x3072 bf16 (overwrites cq in q-up)
  ushort_t* kb16  = (ushort_t*)(ws + 50331648);  // 4096x2048 bf16 K rows (16MB)
  ushort_t* vT    = (ushort_t*)(ws + 67108864);  // [b*16+h][128 vd][2048 tok] bf16 (16MB)
  ushort_t* xb    = (ushort_t*)(ws + 83886080);  // 4096x2048 bf16 pre-cast x (16MB)
  ushort_t* cqn   = (ushort_t*)(ws + 117440512); // 4096x1536 bf16
  float*    kvd   = (float*)(ws + 130023424);    // 4096x640 f32 (dead after rope_kr)
  ushort_t* ckvn  = (ushort_t*)(ws + 140509184); // 4096x512 bf16 (dead after kvu gemm)
  ushort_t* aoutb = (ushort_t*)(ws + 130023424); // 4096x2048 bf16, aliases kvd+ckvn
  ushort_t* krope16 = (ushort_t*)(ws + 146800640); // 4096x64 bf16
  ushort_t* wdqt  = (ushort_t*)(ws + 147849216); // 1536x2048 bf16  (contiguous with ->)
  ushort_t* wdkvt = (ushort_t*)(ws + 154140672); // 640x2048 bf16   (fused B = [wdqt;wdkvt])
  ushort_t* wuqt  = (ushort_t*)(ws + 156762112); // 3072x1536 bf16
  ushort_t* wukvt = (ushort_t*)(ws + 166199296); // 4096x512 bf16
  ushort_t* wot   = (ushort_t*)(ws + 170393600); // 2048x2048 bf16

  const int M = 2 * S_LEN;  // 4096
  dim3 blk(256);

  // fused prep: cast x + 5 transposes (4096 + 15104 blocks)
  prep_k<<<19200, blk, 0, stream>>>(x, xb, wd_q, wdqt, wd_kv, wdkvt,
                                    wu_q, wuqt, wu_kv, wukvt, wo, wot);

  // fused q-down + kv-down: N = 1536 + 640 = 2176 (Bt rows contiguous in ws)
  mfma_gemm<2><<<dim3(2176 / 128, M / 128), blk, 0, stream>>>(
      xb, wdqt, cq, M, 2176, 2048, 1536, nullptr, nullptr, kvd, nullptr, nullptr);
  rmsnorm2_k<<<2 * M, 256, 0, stream>>>(cq, cqn, q_norm_w, kvd, ckvn, kv_norm_w);
  // q-up with fused scale + RoPE + bf16 epilogue -> q16
  mfma_gemm<3><<<dim3(3072 / 128, M / 128), blk, 0, stream>>>(
      cqn, wuqt, nullptr, M, 3072, 1536, 0, q16, nullptr, nullptr, cosb, sinb);
  mfma_gemm<1><<<dim3(4096 / 128, M / 128), blk, 0, stream>>>(
      ckvn, wukvt, nullptr, M, 4096, 512, 0, kb16, vT, nullptr, nullptr, nullptr);
  rope_kr_k<<<512, blk, 0, stream>>>(kvd, krope16, cosb, sinb);
  attn_k<<<2 * NHEAD * (S_LEN / QT), 256, 0, stream>>>(q16, kb16, vT, krope16, aoutb);
  mfma_gemm<0><<<dim3(2048 / 128, M / 128), blk, 0, stream>>>(
      aoutb, wot, out, M, 2048, 2048, 2048, nullptr, nullptr, nullptr, nullptr, nullptr);
}

// Round 7
// 482.569 us; speedup vs baseline: 1.8098x; 1.0289x over previous
//
#include <hip/hip_runtime.h>
#include <hip/hip_bf16.h>

#define S_LEN 2048
#define NHEAD 16
#define NOPE 128
#define ROPE 64
#define HD 192   // nope + rope

typedef unsigned short ushort_t;
typedef __attribute__((ext_vector_type(8))) short short8;
typedef __attribute__((ext_vector_type(4))) float f32x4;

#define AS1 __attribute__((address_space(1)))
#define AS3 __attribute__((address_space(3)))

__device__ __forceinline__ unsigned short f2bf(float f) {
  unsigned int u = __float_as_uint(f);
  return (unsigned short)((u + 0x7FFFu + ((u >> 16) & 1u)) >> 16);
}

// ---------------- fused prep: cast x -> bf16  +  5x transpose_cast ----------------
__global__ __launch_bounds__(256) void prep_k(const float* __restrict__ x, ushort_t* __restrict__ xb,
                                              const float* __restrict__ wd_q, ushort_t* __restrict__ wdqt,
                                              const float* __restrict__ wd_kv, ushort_t* __restrict__ wdkvt,
                                              const float* __restrict__ wu_q, ushort_t* __restrict__ wuqt,
                                              const float* __restrict__ wu_kv, ushort_t* __restrict__ wukvt,
                                              const float* __restrict__ wo, ushort_t* __restrict__ wot) {
  int id = blockIdx.x;
  if (id < 4096) {
    const int i = id * 256 + threadIdx.x;
    const float4 v0 = *(const float4*)&x[(size_t)i * 8];
    const float4 v1 = *(const float4*)&x[(size_t)i * 8 + 4];
    union { uint4 u; ushort_t s[8]; } pk;
    pk.s[0] = f2bf(v0.x); pk.s[1] = f2bf(v0.y); pk.s[2] = f2bf(v0.z); pk.s[3] = f2bf(v0.w);
    pk.s[4] = f2bf(v1.x); pk.s[5] = f2bf(v1.y); pk.s[6] = f2bf(v1.z); pk.s[7] = f2bf(v1.w);
    *(uint4*)&xb[(size_t)i * 8] = pk.u;
    return;
  }
  id -= 4096;
  const float* B; ushort_t* Bt; int K, N, gx;
  if (id < 3072)               { B = wd_q;  Bt = wdqt;  K = 2048; N = 1536; gx = 48;  }
  else if ((id -= 3072) < 1280){ B = wd_kv; Bt = wdkvt; K = 2048; N = 576;  gx = 20;  }
  else if ((id -= 1280) < 4608){ B = wu_q;  Bt = wuqt;  K = 1536; N = 3072; gx = 96;  }
  else if ((id -= 4608) < 2048){ B = wu_kv; Bt = wukvt; K = 512;  N = 4096; gx = 128; }
  else { id -= 2048;             B = wo;    Bt = wot;   K = 2048; N = 2048; gx = 64;  }
  __shared__ float tile[32][33];
  const int tx = threadIdx.x & 31, ty = threadIdx.x >> 5;  // 32 x 8
  const int n0 = (id % gx) * 32, k0 = (id / gx) * 32;
  if (n0 >= N) {
#pragma unroll
    for (int r = 0; r < 4; ++r)
      Bt[(size_t)(n0 + ty + 8 * r) * K + k0 + tx] = 0;
    return;
  }
#pragma unroll
  for (int r = 0; r < 4; ++r)
    tile[ty + 8 * r][tx] = B[(size_t)(k0 + ty + 8 * r) * N + n0 + tx];
  __syncthreads();
#pragma unroll
  for (int r = 0; r < 4; ++r)
    Bt[(size_t)(n0 + ty + 8 * r) * K + k0 + tx] = f2bf(tile[tx][ty + 8 * r]);
}

// ---------------- MFMA GEMM (bf16 A/B; global_load_lds staging; XCD swizzle) ----------
// EPI=0: f32 row-major C.
// EPI=1: KV split epilogue (kvu GEMM, N=4096 = 16 heads x [128 K | 128 V]).
// EPI=2: fused down-proj: n0<1536 -> C (cq, ld 1536); else C2 (kvd, ld 640).
// EPI=3: q-up: scale + RoPE + bf16 -> qo16 [row][3072].
template<int EPI>
__global__ __launch_bounds__(256) void mfma_gemm(const ushort_t* __restrict__ A,
                                                 const ushort_t* __restrict__ Bt,
                                                 float* __restrict__ C,
                                                 int M, int N, int K, int ldc,
                                                 ushort_t* __restrict__ kb16o,
                                                 ushort_t* __restrict__ vto,
                                                 float* __restrict__ C2,
                                                 const float* __restrict__ cosb,
                                                 const float* __restrict__ sinb) {
  __shared__ ushort_t As[128 * 32];
  __shared__ ushort_t Bs[128 * 32];
  const int tid = threadIdx.x;
  const int lane = tid & 63;
  const int wave = tid >> 6;
  const int wm = wave & 1, wn = wave >> 1;

  unsigned bxu = blockIdx.x, byu = blockIdx.y;
  {
    const unsigned gx = gridDim.x;
    const unsigned nwg = gx * gridDim.y;
    if ((nwg & 7u) == 0u) {
      unsigned flat = byu * gx + bxu;
      const unsigned cpx = nwg >> 3;
      flat = (flat & 7u) * cpx + (flat >> 3);
      bxu = flat % gx; byu = flat / gx;
    }
  }
  const int m0 = byu * 128, n0 = bxu * 128;
  const int l15 = lane & 15, quad = lane >> 4;

  f32x4 acc[4][4] = {};

  const int it0 = tid, it1 = tid + 256;
  const int ma0 = it0 >> 2, kc0 = it0 & 3;
  const int ma1 = it1 >> 2, kc1 = it1 & 3;

  typedef AS3 ushort_t lds_us;
  lds_us* AsL = (lds_us*)As;
  lds_us* BsL = (lds_us*)Bs;
  const int wbase = wave * 512;

  for (int k0 = 0; k0 < K; k0 += 32) {
    __builtin_amdgcn_global_load_lds(
        (const AS1 void*)&A[(size_t)(m0 + ma0) * K + k0 + kc0 * 8],
        (AS3 void*)(AsL + wbase), 16, 0, 0);
    __builtin_amdgcn_global_load_lds(
        (const AS1 void*)&A[(size_t)(m0 + ma1) * K + k0 + kc1 * 8],
        (AS3 void*)(AsL + 2048 + wbase), 16, 0, 0);
    __builtin_amdgcn_global_load_lds(
        (const AS1 void*)&Bt[(size_t)(n0 + ma0) * K + k0 + kc0 * 8],
        (AS3 void*)(BsL + wbase), 16, 0, 0);
    __builtin_amdgcn_global_load_lds(
        (const AS1 void*)&Bt[(size_t)(n0 + ma1) * K + k0 + kc1 * 8],
        (AS3 void*)(BsL + 2048 + wbase), 16, 0, 0);
    __syncthreads();

    short8 af[4], bf[4];
#pragma unroll
    for (int i = 0; i < 4; ++i)
      af[i] = *(const short8*)&As[(wm * 64 + i * 16 + l15) * 32 + quad * 8];
#pragma unroll
    for (int j = 0; j < 4; ++j)
      bf[j] = *(const short8*)&Bs[(wn * 64 + j * 16 + l15) * 32 + quad * 8];
#pragma unroll
    for (int i = 0; i < 4; ++i)
#pragma unroll
      for (int j = 0; j < 4; ++j)
        acc[i][j] = __builtin_amdgcn_mfma_f32_16x16x32_bf16(af[i], bf[j], acc[i][j], 0, 0, 0);
    __syncthreads();
  }

  if constexpr (EPI == 0) {
#pragma unroll
    for (int i = 0; i < 4; ++i)
#pragma unroll
      for (int r = 0; r < 4; ++r) {
        const size_t rg = (size_t)(m0 + wm * 64 + i * 16 + quad * 4 + r);
#pragma unroll
        for (int j = 0; j < 4; ++j)
          C[rg * ldc + n0 + wn * 64 + j * 16 + l15] = acc[i][j][r];
      }
  } else if constexpr (EPI == 1) {
    const int h = n0 >> 8;
    const bool is_v = (n0 >> 7) & 1;
    if (!is_v) {
#pragma unroll
      for (int i = 0; i < 4; ++i)
#pragma unroll
        for (int r = 0; r < 4; ++r) {
          const size_t rg = (size_t)(m0 + wm * 64 + i * 16 + quad * 4 + r);
#pragma unroll
          for (int j = 0; j < 4; ++j)
            kb16o[rg * 2048 + h * 128 + wn * 64 + j * 16 + l15] = f2bf(acc[i][j][r]);
        }
    } else {
      __shared__ __align__(16) ushort_t trb[64 * 136];
      const int bb = m0 >> 11;
      const int m0loc = m0 & 2047;
      ushort_t* vbase = vto + ((size_t)(bb * NHEAD + h) * 128) * 2048;
#pragma unroll
      for (int vh = 0; vh < 2; ++vh) {
        if (wn == vh) {
#pragma unroll
          for (int i = 0; i < 4; ++i)
#pragma unroll
            for (int r = 0; r < 4; ++r) {
              const int tloc = wm * 64 + i * 16 + quad * 4 + r;
#pragma unroll
              for (int j = 0; j < 4; ++j)
                trb[(j * 16 + l15) * 136 + tloc] = f2bf(acc[i][j][r]);
            }
        }
        __syncthreads();
#pragma unroll
        for (int it = 0; it < 4; ++it) {
          const int u = tid + (it << 8);
          const int vdl = u >> 4, tc = u & 15;
          *(uint4*)&vbase[(size_t)(vh * 64 + vdl) * 2048 + m0loc + tc * 8] =
              *(const uint4*)&trb[vdl * 136 + tc * 8];
        }
        __syncthreads();
      }
    }
  } else if constexpr (EPI == 2) {
    float* Cd;
    int ldd, nc;
    if (n0 < 1536) { Cd = C;  ldd = 1536; nc = n0; }
    else           { Cd = C2; ldd = 640;  nc = n0 - 1536; }
#pragma unroll
    for (int i = 0; i < 4; ++i)
#pragma unroll
      for (int r = 0; r < 4; ++r) {
        const size_t rg = (size_t)(m0 + wm * 64 + i * 16 + quad * 4 + r);
#pragma unroll
        for (int j = 0; j < 4; ++j)
          Cd[rg * ldd + nc + wn * 64 + j * 16 + l15] = acc[i][j][r];
      }
  } else {  // EPI == 3: q-up epilogue: scale + RoPE + bf16 -> qo16 (kb16o arg)
    const float qscale = 0.07216878364870323f;  // 1/sqrt(192)
#pragma unroll
    for (int i = 0; i < 4; ++i)
#pragma unroll
      for (int r = 0; r < 4; ++r) {
        const int rg = m0 + wm * 64 + i * 16 + quad * 4 + r;
        const int sp = rg & (S_LEN - 1);
#pragma unroll
        for (int j = 0; j < 4; ++j) {
          const int col = n0 + wn * 64 + j * 16 + l15;
          float val = acc[i][j][r] * qscale;
          const float pr = __shfl_xor(val, 1);   // adjacent column (same row)
          const int dd = col % HD;               // 0..191 within head
          float o = val;
          if (dd >= NOPE) {
            const int d = (dd - NOPE) >> 1;
            const float cc = cosb[sp * 32 + d];
            const float sn = sinb[sp * 32 + d];
            o = (lane & 1) ? (pr * sn + val * cc) : (val * cc - pr * sn);
          }
          kb16o[(size_t)rg * 3072 + col] = f2bf(o);
        }
      }
  }
}

// ---------------- merged RMSNorm (+ fused k-rope on kv rows) ----------------
__global__ __launch_bounds__(256) void rmsnorm2_k(const float* __restrict__ cq,
                                                  ushort_t* __restrict__ cqn,
                                                  const float* __restrict__ qw,
                                                  const float* __restrict__ kvd,
                                                  ushort_t* __restrict__ ckvn,
                                                  const float* __restrict__ kvw,
                                                  ushort_t* __restrict__ krope16,
                                                  const float* __restrict__ cosb,
                                                  const float* __restrict__ sinb) {
  const bool is_q = blockIdx.x < 4096;
  const int row = blockIdx.x & 4095;
  const int tid = threadIdx.x;
  const float* ip = is_q ? cq + (size_t)row * 1536 : kvd + (size_t)row * 640;
  ushort_t* op = is_q ? cqn + (size_t)row * 1536 : ckvn + (size_t)row * 512;
  const float* w = is_q ? qw : kvw;
  const int L = is_q ? 1536 : 512;
  const int nper = L >> 8;
  float r[6];
  float ss = 0.f;
  for (int j = 0; j < nper; ++j) {
    r[j] = ip[tid + (j << 8)];
    ss += r[j] * r[j];
  }
  for (int off = 32; off; off >>= 1) ss += __shfl_down(ss, off);
  __shared__ float wsum[4];
  __shared__ float scale_s;
  if ((tid & 63) == 0) wsum[tid >> 6] = ss;
  __syncthreads();
  if (tid == 0) {
    float t = wsum[0] + wsum[1] + wsum[2] + wsum[3];
    scale_s = rsqrtf(t / (float)L + 1e-5f);
  }
  __syncthreads();
  const float sc = scale_s;
  for (int j = 0; j < nper; ++j)
    op[tid + (j << 8)] = f2bf(r[j] * sc * w[tid + (j << 8)]);
  if (!is_q && tid < 32) {           // fused k-rope (kvd cols 512..639)
    const int d = tid;
    const int s = row & (S_LEN - 1);
    const float c = cosb[s * 32 + d];
    const float sn = sinb[s * 32 + d];
    const float* kb = kvd + (size_t)row * 640 + 512;
    const float y0 = kb[2 * d], y1 = kb[2 * d + 1];
    union { unsigned int u; ushort_t s2[2]; } pk;
    pk.s2[0] = f2bf(y0 * c - y1 * sn);
    pk.s2[1] = f2bf(y0 * sn + y1 * c);
    *(unsigned int*)&krope16[(size_t)row * 64 + 2 * d] = pk.u;
  }
}

// ---------------- MFMA flash attention ----------------
// Round 7: 512-thread blocks (8 waves, one 16-row q-strip each). Same tiling
// (QT=128, KC=64, grid 512, XCD-locality mapping), same 75.8KB LDS -> still
// 2 blocks/CU, but now 16 waves/CU = 4 waves/SIMD (was 2): double the TLP to
// hide the phase-chain latencies the round-6 counters exposed (66% idle at
// near-ideal FETCH). Per-wave phase work halves -> shorter critical paths.
#define QT 128
#define KC 64
__global__ __launch_bounds__(512, 4) void attn_k(const ushort_t* __restrict__ q16,
                                                 const ushort_t* __restrict__ kb16,
                                                 const ushort_t* __restrict__ vT,
                                                 const ushort_t* __restrict__ krope16,
                                                 ushort_t* __restrict__ outp) {
  const int bx = blockIdx.x;
  const int g = bx & 31;            // (b,h) group -> XCD g%8
  const int s = bx >> 5;            // slot 0..15
  const int tile = (s < 8) ? s : 23 - s;
  const int b = g >> 4, h = g & 15;
  const int q0 = tile * QT;
  const int tid = threadIdx.x;
  const int lane = tid & 63;
  const int wq = tid >> 6;          // 0..7
  const int l15 = lane & 15, quad = lane >> 4;

  __shared__ __align__(16) ushort_t Kn[64 * 128];    // 16 KB
  __shared__ __align__(16) ushort_t Kr[64 * 64];     //  8 KB
  __shared__ __align__(16) ushort_t Vt[2][128 * 64]; // 32 KB (double buffer)
  __shared__ __align__(16) ushort_t Pb[8][16 * 72];  // 18 KB (per-wave 16x64 P)

  const int qbase = q0 + wq * 16;   // wave's 16 q-rows
  const size_t growq = (size_t)b * S_LEN + qbase;
  const ushort_t* vTh = vT + ((size_t)(b * NHEAD + h) * 128) * 2048;
  const size_t bbase = (size_t)b * S_LEN;

  typedef AS3 ushort_t lds_us;
  lds_us* KnL = (lds_us*)Kn;
  lds_us* KrL = (lds_us*)Kr;
  lds_us* VtL = (lds_us*)Vt;
  const int wbase = wq * 512;       // shorts (64 lanes x 8 shorts)

  // --- async staging (512 threads): issueK = 3 instrs/wave, issueV = 2 ---
  auto issueK = [&](int c) {
    const size_t growk = bbase + (size_t)c * KC;
#pragma unroll
    for (int it = 0; it < 2; ++it) {
      const int u = tid + (it << 9);
      const int key = u >> 4, sl = u & 15;
      const int ss = sl ^ (key & 7);
      __builtin_amdgcn_global_load_lds(
          (const AS1 void*)&kb16[(growk + key) * 2048 + h * 128 + ss * 8],
          (AS3 void*)(KnL + wbase + it * 4096), 16, 0, 0);
    }
    {
      const int u = tid;
      const int key = u >> 3, sl = u & 7;
      const int ss = sl ^ (key & 7);
      __builtin_amdgcn_global_load_lds(
          (const AS1 void*)&krope16[(growk + key) * 64 + ss * 8],
          (AS3 void*)(KrL + wbase), 16, 0, 0);
    }
  };
  auto issueV = [&](int c, int buf) {
    const int j0 = c * KC;
#pragma unroll
    for (int it = 0; it < 2; ++it) {
      const int u = tid + (it << 9);
      const int vd = u >> 3, sl = u & 7;
      const int ss = sl ^ (vd & 7);
      __builtin_amdgcn_global_load_lds(
          (const AS1 void*)&vTh[(size_t)vd * 2048 + j0 + ss * 8],
          (AS3 void*)(VtL + buf * 8192 + wbase + it * 4096), 16, 0, 0);
    }
  };

  // ---- prologue ----
  issueK(0);
  issueV(0, 0);
  __builtin_amdgcn_sched_barrier(0);

  // Q fragments (pre-scaled, pre-roped bf16): wave's 16 rows, lane l15 = row
  short8 qf[6];
#pragma unroll
  for (int ks = 0; ks < 6; ++ks)
    qf[ks] = *(const short8*)&q16[(growq + l15) * 3072 + h * HD + ks * 32 + quad * 8];

  f32x4 oacc[8] = {};
  float mrow[4], lrow[4];
  int q_r[4];
#pragma unroll
  for (int r = 0; r < 4; ++r) {
    mrow[r] = -1e30f; lrow[r] = 0.f;
    q_r[r] = qbase + quad * 4 + r;
  }

  const int nchunk = (q0 + QT) / KC;

  asm volatile("s_waitcnt vmcnt(2)" ::: "memory");   // K(0) landed (V may fly)
  __builtin_amdgcn_s_barrier();
  __builtin_amdgcn_sched_barrier(0);

  for (int c = 0; c < nchunk; ++c) {
    const int j0 = c * KC;
    const bool more = (c + 1 < nchunk);
    const int buf = c & 1;
    const bool skipw = (j0 > qbase + 15);   // chunk fully above diagonal for this wave

    // ---- QK^T on K(c) ----
    f32x4 sacc[4] = {};
    if (!skipw) {
      __builtin_amdgcn_s_setprio(1);
#pragma unroll
      for (int ks = 0; ks < 6; ++ks) {
        short8 kf[4];
        if (ks < 4) {
#pragma unroll
          for (int kt = 0; kt < 4; ++kt)
            kf[kt] = *(const short8*)&Kn[(kt * 16 + l15) * 128 + (((ks * 4 + quad) ^ (l15 & 7)) << 3)];
        } else {
#pragma unroll
          for (int kt = 0; kt < 4; ++kt)
            kf[kt] = *(const short8*)&Kr[(kt * 16 + l15) * 64 + ((((ks - 4) * 4 + quad) ^ (l15 & 7)) << 3)];
        }
#pragma unroll
        for (int kt = 0; kt < 4; ++kt)
          sacc[kt] = __builtin_amdgcn_mfma_f32_16x16x32_bf16(qf[ks], kf[kt], sacc[kt], 0, 0, 0);
      }
      __builtin_amdgcn_s_setprio(0);
    }

    __builtin_amdgcn_s_barrier();          // all waves done reading Kn/Kr
    if (more) issueK(c + 1);               // DMA, flies under softmax+PV
    __builtin_amdgcn_sched_barrier(0);

    if (!skipw) {
      // ---- mask (diagonal chunks only) ----
      if (j0 + KC - 1 > qbase) {
#pragma unroll
        for (int kt = 0; kt < 4; ++kt) {
          const int key = j0 + kt * 16 + l15;
#pragma unroll
          for (int r = 0; r < 4; ++r)
            sacc[kt][r] = (key <= q_r[r]) ? sacc[kt][r] : -1e30f;
        }
      }
      // ---- chunk max ----
      float pmax[4];
#pragma unroll
      for (int r = 0; r < 4; ++r) {
        float mx = fmaxf(fmaxf(sacc[0][r], sacc[1][r]),
                         fmaxf(sacc[2][r], sacc[3][r]));
        mx = fmaxf(mx, __shfl_xor(mx, 1));
        mx = fmaxf(mx, __shfl_xor(mx, 2));
        mx = fmaxf(mx, __shfl_xor(mx, 4));
        mx = fmaxf(mx, __shfl_xor(mx, 8));
        pmax[r] = mx;
      }
      // ---- T13 defer-max ----
      bool need = false;
#pragma unroll
      for (int r = 0; r < 4; ++r)
        need = need || (pmax[r] > mrow[r] + 8.0f);
      const bool upd = __any(need);
      float alpha[4];
      if (upd) {
#pragma unroll
        for (int r = 0; r < 4; ++r) {
          const float mn = fmaxf(mrow[r], pmax[r]);
          alpha[r] = __expf(mrow[r] - mn);
          mrow[r] = mn;
        }
      }
      // ---- exp + row sums ----
#pragma unroll
      for (int kt = 0; kt < 4; ++kt)
#pragma unroll
        for (int r = 0; r < 4; ++r)
          sacc[kt][r] = __expf(sacc[kt][r] - mrow[r]);
#pragma unroll
      for (int r = 0; r < 4; ++r) {
        float rs = sacc[0][r] + sacc[1][r] + sacc[2][r] + sacc[3][r];
        rs += __shfl_xor(rs, 1);
        rs += __shfl_xor(rs, 2);
        rs += __shfl_xor(rs, 4);
        rs += __shfl_xor(rs, 8);
        lrow[r] = upd ? lrow[r] * alpha[r] + rs : lrow[r] + rs;
      }
      // ---- write P (bf16) to per-wave-private LDS ----
#pragma unroll
      for (int kt = 0; kt < 4; ++kt)
#pragma unroll
        for (int r = 0; r < 4; ++r)
          Pb[wq][(quad * 4 + r) * 72 + kt * 16 + l15] = f2bf(sacc[kt][r]);
      // ---- rescale O (only when max grew) ----
      if (upd) {
#pragma unroll
        for (int nt = 0; nt < 8; ++nt)
#pragma unroll
          for (int r = 0; r < 4; ++r)
            oacc[nt][r] *= alpha[r];
      }
    }

    if (more) asm volatile("s_waitcnt vmcnt(3)" ::: "memory");  // V(c) landed; K(c+1) flying
    else      asm volatile("s_waitcnt vmcnt(0)" ::: "memory");
    __builtin_amdgcn_s_barrier();          // Vt[buf] visible blockwide
    __builtin_amdgcn_sched_barrier(0);

    // ---- PV on Vt[buf] ----
    if (!skipw) {
      __builtin_amdgcn_s_setprio(1);
#pragma unroll
      for (int st = 0; st < 2; ++st) {
        const short8 pf = *(const short8*)&Pb[wq][l15 * 72 + st * 32 + quad * 8];
#pragma unroll
        for (int nt = 0; nt < 8; ++nt) {
          const short8 vf = *(const short8*)&Vt[buf][(nt * 16 + l15) * 64 + (((st * 4 + quad) ^ (l15 & 7)) << 3)];
          oacc[nt] = __builtin_amdgcn_mfma_f32_16x16x32_bf16(pf, vf, oacc[nt], 0, 0, 0);
        }
      }
      __builtin_amdgcn_s_setprio(0);
    }

    if (more) {
      issueV(c + 1, buf ^ 1);              // other buffer; no barrier needed
      __builtin_amdgcn_sched_barrier(0);
      asm volatile("s_waitcnt vmcnt(2)" ::: "memory");  // K(c+1) landed; V(c+1) flying
      __builtin_amdgcn_s_barrier();        // K(c+1) visible blockwide
      __builtin_amdgcn_sched_barrier(0);
    }
  }

  // ---- store (bf16) ----
#pragma unroll
  for (int r = 0; r < 4; ++r) {
    const float inv = 1.0f / lrow[r];
    const size_t orow = growq + quad * 4 + r;
#pragma unroll
    for (int nt = 0; nt < 8; ++nt)
      outp[orow * 2048 + h * 128 + nt * 16 + l15] = f2bf(oacc[nt][r] * inv);
  }
}

extern "C" void kernel_launch(void* const* d_in, const int* in_sizes, int n_in,
                              void* d_out, int out_size, void* d_ws, size_t ws_size,
                              hipStream_t stream) {
  const float* x        = (const float*)d_in[0];
  const float* wd_q     = (const float*)d_in[1];
  const float* wu_q     = (const float*)d_in[2];
  const float* q_norm_w = (const float*)d_in[3];
  const float* wd_kv    = (const float*)d_in[4];
  const float* wu_kv    = (const float*)d_in[5];
  const float* kv_norm_w= (const float*)d_in[6];
  const float* wo       = (const float*)d_in[7];
  const float* cosb     = (const float*)d_in[8];
  const float* sinb     = (const float*)d_in[9];
  float* out = (float*)d_out;

  char* ws = (char*)d_ws;
  float*    cq    = (float*)(ws + 0);            // 4096x1536 f32 (dead after rmsnorm)
  ushort_t* q16   = (ushort_t*)(ws + 0);         // 4096x3072 bf16 (overwrites cq in q-up)
  ushort_t* kb16  = (ushort_t*)(ws + 50331648);  // 4096x2048 bf16 K rows (16MB)
  ushort_t* vT    = (ushort_t*)(ws + 67108864);  // [b*16+h][128 vd][2048 tok] bf16 (16MB)
  ushort_t* xb    = (ushort_t*)(ws + 83886080);  // 4096x2048 bf16 pre-cast x (16MB)
  ushort_t* cqn   = (ushort_t*)(ws + 117440512); // 4096x1536 bf16
  float*    kvd   = (float*)(ws + 130023424);    // 4096x640 f32 (dead after rmsnorm2)
  ushort_t* ckvn  = (ushort_t*)(ws + 140509184); // 4096x512 bf16 (dead after kvu gemm)
  ushort_t* aoutb = (ushort_t*)(ws + 130023424); // 4096x2048 bf16, aliases kvd+ckvn
  ushort_t* krope16 = (ushort_t*)(ws + 146800640); // 4096x64 bf16
  ushort_t* wdqt  = (ushort_t*)(ws + 147849216); // 1536x2048 bf16  (contiguous with ->)
  ushort_t* wdkvt = (ushort_t*)(ws + 154140672); // 640x2048 bf16   (fused B = [wdqt;wdkvt])
  ushort_t* wuqt  = (ushort_t*)(ws + 156762112); // 3072x1536 bf16
  ushort_t* wukvt = (ushort_t*)(ws + 166199296); // 4096x512 bf16
  ushort_t* wot   = (ushort_t*)(ws + 170393600); // 2048x2048 bf16

  const int M = 2 * S_LEN;  // 4096
  dim3 blk(256);

  prep_k<<<19200, blk, 0, stream>>>(x, xb, wd_q, wdqt, wd_kv, wdkvt,
                                    wu_q, wuqt, wu_kv, wukvt, wo, wot);

  mfma_gemm<2><<<dim3(2176 / 128, M / 128), blk, 0, stream>>>(
      xb, wdqt, cq, M, 2176, 2048, 1536, nullptr, nullptr, kvd, nullptr, nullptr);
  rmsnorm2_k<<<2 * M, 256, 0, stream>>>(cq, cqn, q_norm_w, kvd, ckvn, kv_norm_w,
                                        krope16, cosb, sinb);
  mfma_gemm<3><<<dim3(3072 / 128, M / 128), blk, 0, stream>>>(
      cqn, wuqt, nullptr, M, 3072, 1536, 0, q16, nullptr, nullptr, cosb, sinb);
  mfma_gemm<1><<<dim3(4096 / 128, M / 128), blk, 0, stream>>>(
      ckvn, wukvt, nullptr, M, 4096, 512, 0, kb16, vT, nullptr, nullptr, nullptr);
  attn_k<<<2 * NHEAD * (S_LEN / QT), 512, 0, stream>>>(q16, kb16, vT, krope16, aoutb);
  mfma_gemm<0><<<dim3(2048 / 128, M / 128), blk, 0, stream>>>(
      aoutb, wot, out, M, 2048, 2048, 2048, nullptr, nullptr, nullptr, nullptr, nullptr);
}

// Round 8
// 462.557 us; speedup vs baseline: 1.8881x; 1.0433x over previous
//
#include <hip/hip_runtime.h>
#include <hip/hip_bf16.h>

#define S_LEN 2048
#define NHEAD 16
#define NOPE 128
#define ROPE 64
#define HD 192   // nope + rope

typedef unsigned short ushort_t;
typedef __attribute__((ext_vector_type(8))) short short8;
typedef __attribute__((ext_vector_type(4))) float f32x4;

#define AS1 __attribute__((address_space(1)))
#define AS3 __attribute__((address_space(3)))

__device__ __forceinline__ unsigned short f2bf(float f) {
  unsigned int u = __float_as_uint(f);
  return (unsigned short)((u + 0x7FFFu + ((u >> 16) & 1u)) >> 16);
}

// ---------------- fused prep: cast x -> bf16  +  5x transpose_cast ----------------
__global__ __launch_bounds__(256) void prep_k(const float* __restrict__ x, ushort_t* __restrict__ xb,
                                              const float* __restrict__ wd_q, ushort_t* __restrict__ wdqt,
                                              const float* __restrict__ wd_kv, ushort_t* __restrict__ wdkvt,
                                              const float* __restrict__ wu_q, ushort_t* __restrict__ wuqt,
                                              const float* __restrict__ wu_kv, ushort_t* __restrict__ wukvt,
                                              const float* __restrict__ wo, ushort_t* __restrict__ wot) {
  int id = blockIdx.x;
  if (id < 4096) {
    const int i = id * 256 + threadIdx.x;
    const float4 v0 = *(const float4*)&x[(size_t)i * 8];
    const float4 v1 = *(const float4*)&x[(size_t)i * 8 + 4];
    union { uint4 u; ushort_t s[8]; } pk;
    pk.s[0] = f2bf(v0.x); pk.s[1] = f2bf(v0.y); pk.s[2] = f2bf(v0.z); pk.s[3] = f2bf(v0.w);
    pk.s[4] = f2bf(v1.x); pk.s[5] = f2bf(v1.y); pk.s[6] = f2bf(v1.z); pk.s[7] = f2bf(v1.w);
    *(uint4*)&xb[(size_t)i * 8] = pk.u;
    return;
  }
  id -= 4096;
  const float* B; ushort_t* Bt; int K, N, gx;
  if (id < 3072)               { B = wd_q;  Bt = wdqt;  K = 2048; N = 1536; gx = 48;  }
  else if ((id -= 3072) < 1280){ B = wd_kv; Bt = wdkvt; K = 2048; N = 576;  gx = 20;  }
  else if ((id -= 1280) < 4608){ B = wu_q;  Bt = wuqt;  K = 1536; N = 3072; gx = 96;  }
  else if ((id -= 4608) < 2048){ B = wu_kv; Bt = wukvt; K = 512;  N = 4096; gx = 128; }
  else { id -= 2048;             B = wo;    Bt = wot;   K = 2048; N = 2048; gx = 64;  }
  __shared__ float tile[32][33];
  const int tx = threadIdx.x & 31, ty = threadIdx.x >> 5;  // 32 x 8
  const int n0 = (id % gx) * 32, k0 = (id / gx) * 32;
  if (n0 >= N) {
#pragma unroll
    for (int r = 0; r < 4; ++r)
      Bt[(size_t)(n0 + ty + 8 * r) * K + k0 + tx] = 0;
    return;
  }
#pragma unroll
  for (int r = 0; r < 4; ++r)
    tile[ty + 8 * r][tx] = B[(size_t)(k0 + ty + 8 * r) * N + n0 + tx];
  __syncthreads();
#pragma unroll
  for (int r = 0; r < 4; ++r)
    Bt[(size_t)(n0 + ty + 8 * r) * K + k0 + tx] = f2bf(tile[tx][ty + 8 * r]);
}

// ---------------- MFMA GEMM: 512 threads / 8 waves on a 128x128 tile --------------
// Round 8: same K-loop structure (global_load_lds, BK=32, 2 barriers) but 8 waves
// per block (wave grid 4m x 2n, acc[2][4]) -> 16 waves/CU at the grid-limited
// 2 blocks/CU of the down/out GEMMs (was 8 waves/CU = 2/SIMD). One gload_lds
// per thread per operand (512 thr x 16B = 8KB tile half).
// EPI=0: f32 row-major C.   EPI=1: KV split (K rows bf16 + V transpose).
// EPI=2: fused down-proj routing.   EPI=3: q-up scale+RoPE+bf16.
template<int EPI>
__global__ __launch_bounds__(512, 4) void mfma_gemm(const ushort_t* __restrict__ A,
                                                 const ushort_t* __restrict__ Bt,
                                                 float* __restrict__ C,
                                                 int M, int N, int K, int ldc,
                                                 ushort_t* __restrict__ kb16o,
                                                 ushort_t* __restrict__ vto,
                                                 float* __restrict__ C2,
                                                 const float* __restrict__ cosb,
                                                 const float* __restrict__ sinb) {
  __shared__ ushort_t As[128 * 32];
  __shared__ ushort_t Bs[128 * 32];
  const int tid = threadIdx.x;
  const int lane = tid & 63;
  const int wave = tid >> 6;        // 0..7
  const int wm = wave & 3, wn = wave >> 2;   // 4 m-strips x 2 n-strips

  unsigned bxu = blockIdx.x, byu = blockIdx.y;
  {
    const unsigned gx = gridDim.x;
    const unsigned nwg = gx * gridDim.y;
    if ((nwg & 7u) == 0u) {
      unsigned flat = byu * gx + bxu;
      const unsigned cpx = nwg >> 3;
      flat = (flat & 7u) * cpx + (flat >> 3);
      bxu = flat % gx; byu = flat / gx;
    }
  }
  const int m0 = byu * 128, n0 = bxu * 128;
  const int l15 = lane & 15, quad = lane >> 4;

  f32x4 acc[2][4] = {};

  const int ma0 = tid >> 2, kc0 = tid & 3;   // 512 threads cover 128 rows x 4 k-chunks

  typedef AS3 ushort_t lds_us;
  lds_us* AsL = (lds_us*)As;
  lds_us* BsL = (lds_us*)Bs;
  const int wbase = wave * 512;   // shorts: 64 lanes * 8 shorts

  for (int k0 = 0; k0 < K; k0 += 32) {
    __builtin_amdgcn_global_load_lds(
        (const AS1 void*)&A[(size_t)(m0 + ma0) * K + k0 + kc0 * 8],
        (AS3 void*)(AsL + wbase), 16, 0, 0);
    __builtin_amdgcn_global_load_lds(
        (const AS1 void*)&Bt[(size_t)(n0 + ma0) * K + k0 + kc0 * 8],
        (AS3 void*)(BsL + wbase), 16, 0, 0);
    __syncthreads();

    short8 af[2], bf[4];
#pragma unroll
    for (int i = 0; i < 2; ++i)
      af[i] = *(const short8*)&As[(wm * 32 + i * 16 + l15) * 32 + quad * 8];
#pragma unroll
    for (int j = 0; j < 4; ++j)
      bf[j] = *(const short8*)&Bs[(wn * 64 + j * 16 + l15) * 32 + quad * 8];
#pragma unroll
    for (int i = 0; i < 2; ++i)
#pragma unroll
      for (int j = 0; j < 4; ++j)
        acc[i][j] = __builtin_amdgcn_mfma_f32_16x16x32_bf16(af[i], bf[j], acc[i][j], 0, 0, 0);
    __syncthreads();
  }

  if constexpr (EPI == 0) {
#pragma unroll
    for (int i = 0; i < 2; ++i)
#pragma unroll
      for (int r = 0; r < 4; ++r) {
        const size_t rg = (size_t)(m0 + wm * 32 + i * 16 + quad * 4 + r);
#pragma unroll
        for (int j = 0; j < 4; ++j)
          C[rg * ldc + n0 + wn * 64 + j * 16 + l15] = acc[i][j][r];
      }
  } else if constexpr (EPI == 1) {
    const int h = n0 >> 8;
    const bool is_v = (n0 >> 7) & 1;
    if (!is_v) {
#pragma unroll
      for (int i = 0; i < 2; ++i)
#pragma unroll
        for (int r = 0; r < 4; ++r) {
          const size_t rg = (size_t)(m0 + wm * 32 + i * 16 + quad * 4 + r);
#pragma unroll
          for (int j = 0; j < 4; ++j)
            kb16o[rg * 2048 + h * 128 + wn * 64 + j * 16 + l15] = f2bf(acc[i][j][r]);
        }
    } else {
      __shared__ __align__(16) ushort_t trb[64 * 136];
      const int bb = m0 >> 11;
      const int m0loc = m0 & 2047;
      ushort_t* vbase = vto + ((size_t)(bb * NHEAD + h) * 128) * 2048;
#pragma unroll
      for (int vh = 0; vh < 2; ++vh) {
        if (wn == vh) {
#pragma unroll
          for (int i = 0; i < 2; ++i)
#pragma unroll
            for (int r = 0; r < 4; ++r) {
              const int tloc = wm * 32 + i * 16 + quad * 4 + r;   // 0..127
#pragma unroll
              for (int j = 0; j < 4; ++j)
                trb[(j * 16 + l15) * 136 + tloc] = f2bf(acc[i][j][r]);
            }
        }
        __syncthreads();
#pragma unroll
        for (int it = 0; it < 2; ++it) {
          const int u = tid + (it << 9);
          const int vdl = u >> 4, tc = u & 15;
          *(uint4*)&vbase[(size_t)(vh * 64 + vdl) * 2048 + m0loc + tc * 8] =
              *(const uint4*)&trb[vdl * 136 + tc * 8];
        }
        __syncthreads();
      }
    }
  } else if constexpr (EPI == 2) {
    float* Cd;
    int ldd, nc;
    if (n0 < 1536) { Cd = C;  ldd = 1536; nc = n0; }
    else           { Cd = C2; ldd = 640;  nc = n0 - 1536; }
#pragma unroll
    for (int i = 0; i < 2; ++i)
#pragma unroll
      for (int r = 0; r < 4; ++r) {
        const size_t rg = (size_t)(m0 + wm * 32 + i * 16 + quad * 4 + r);
#pragma unroll
        for (int j = 0; j < 4; ++j)
          Cd[rg * ldd + nc + wn * 64 + j * 16 + l15] = acc[i][j][r];
      }
  } else {  // EPI == 3: q-up epilogue: scale + RoPE + bf16 -> qo16 (kb16o arg)
    const float qscale = 0.07216878364870323f;  // 1/sqrt(192)
#pragma unroll
    for (int i = 0; i < 2; ++i)
#pragma unroll
      for (int r = 0; r < 4; ++r) {
        const int rg = m0 + wm * 32 + i * 16 + quad * 4 + r;
        const int sp = rg & (S_LEN - 1);
#pragma unroll
        for (int j = 0; j < 4; ++j) {
          const int col = n0 + wn * 64 + j * 16 + l15;
          float val = acc[i][j][r] * qscale;
          const float pr = __shfl_xor(val, 1);   // adjacent column (same row)
          const int dd = col % HD;               // 0..191 within head
          float o = val;
          if (dd >= NOPE) {
            const int d = (dd - NOPE) >> 1;
            const float cc = cosb[sp * 32 + d];
            const float sn = sinb[sp * 32 + d];
            o = (lane & 1) ? (pr * sn + val * cc) : (val * cc - pr * sn);
          }
          kb16o[(size_t)rg * 3072 + col] = f2bf(o);
        }
      }
  }
}

// ---------------- merged RMSNorm (+ fused k-rope on kv rows) ----------------
__global__ __launch_bounds__(256) void rmsnorm2_k(const float* __restrict__ cq,
                                                  ushort_t* __restrict__ cqn,
                                                  const float* __restrict__ qw,
                                                  const float* __restrict__ kvd,
                                                  ushort_t* __restrict__ ckvn,
                                                  const float* __restrict__ kvw,
                                                  ushort_t* __restrict__ krope16,
                                                  const float* __restrict__ cosb,
                                                  const float* __restrict__ sinb) {
  const bool is_q = blockIdx.x < 4096;
  const int row = blockIdx.x & 4095;
  const int tid = threadIdx.x;
  const float* ip = is_q ? cq + (size_t)row * 1536 : kvd + (size_t)row * 640;
  ushort_t* op = is_q ? cqn + (size_t)row * 1536 : ckvn + (size_t)row * 512;
  const float* w = is_q ? qw : kvw;
  const int L = is_q ? 1536 : 512;
  const int nper = L >> 8;
  float r[6];
  float ss = 0.f;
  for (int j = 0; j < nper; ++j) {
    r[j] = ip[tid + (j << 8)];
    ss += r[j] * r[j];
  }
  for (int off = 32; off; off >>= 1) ss += __shfl_down(ss, off);
  __shared__ float wsum[4];
  __shared__ float scale_s;
  if ((tid & 63) == 0) wsum[tid >> 6] = ss;
  __syncthreads();
  if (tid == 0) {
    float t = wsum[0] + wsum[1] + wsum[2] + wsum[3];
    scale_s = rsqrtf(t / (float)L + 1e-5f);
  }
  __syncthreads();
  const float sc = scale_s;
  for (int j = 0; j < nper; ++j)
    op[tid + (j << 8)] = f2bf(r[j] * sc * w[tid + (j << 8)]);
  if (!is_q && tid < 32) {           // fused k-rope (kvd cols 512..639)
    const int d = tid;
    const int s = row & (S_LEN - 1);
    const float c = cosb[s * 32 + d];
    const float sn = sinb[s * 32 + d];
    const float* kb = kvd + (size_t)row * 640 + 512;
    const float y0 = kb[2 * d], y1 = kb[2 * d + 1];
    union { unsigned int u; ushort_t s2[2]; } pk;
    pk.s2[0] = f2bf(y0 * c - y1 * sn);
    pk.s2[1] = f2bf(y0 * sn + y1 * c);
    *(unsigned int*)&krope16[(size_t)row * 64 + 2 * d] = pk.u;
  }
}

// ---------------- MFMA flash attention (unchanged from round 7) ----------------
#define QT 128
#define KC 64
__global__ __launch_bounds__(512, 4) void attn_k(const ushort_t* __restrict__ q16,
                                                 const ushort_t* __restrict__ kb16,
                                                 const ushort_t* __restrict__ vT,
                                                 const ushort_t* __restrict__ krope16,
                                                 ushort_t* __restrict__ outp) {
  const int bx = blockIdx.x;
  const int g = bx & 31;            // (b,h) group -> XCD g%8
  const int s = bx >> 5;            // slot 0..15
  const int tile = (s < 8) ? s : 23 - s;
  const int b = g >> 4, h = g & 15;
  const int q0 = tile * QT;
  const int tid = threadIdx.x;
  const int lane = tid & 63;
  const int wq = tid >> 6;          // 0..7
  const int l15 = lane & 15, quad = lane >> 4;

  __shared__ __align__(16) ushort_t Kn[64 * 128];    // 16 KB
  __shared__ __align__(16) ushort_t Kr[64 * 64];     //  8 KB
  __shared__ __align__(16) ushort_t Vt[2][128 * 64]; // 32 KB (double buffer)
  __shared__ __align__(16) ushort_t Pb[8][16 * 72];  // 18 KB (per-wave 16x64 P)

  const int qbase = q0 + wq * 16;   // wave's 16 q-rows
  const size_t growq = (size_t)b * S_LEN + qbase;
  const ushort_t* vTh = vT + ((size_t)(b * NHEAD + h) * 128) * 2048;
  const size_t bbase = (size_t)b * S_LEN;

  typedef AS3 ushort_t lds_us;
  lds_us* KnL = (lds_us*)Kn;
  lds_us* KrL = (lds_us*)Kr;
  lds_us* VtL = (lds_us*)Vt;
  const int wbase = wq * 512;       // shorts (64 lanes x 8 shorts)

  auto issueK = [&](int c) {
    const size_t growk = bbase + (size_t)c * KC;
#pragma unroll
    for (int it = 0; it < 2; ++it) {
      const int u = tid + (it << 9);
      const int key = u >> 4, sl = u & 15;
      const int ss = sl ^ (key & 7);
      __builtin_amdgcn_global_load_lds(
          (const AS1 void*)&kb16[(growk + key) * 2048 + h * 128 + ss * 8],
          (AS3 void*)(KnL + wbase + it * 4096), 16, 0, 0);
    }
    {
      const int u = tid;
      const int key = u >> 3, sl = u & 7;
      const int ss = sl ^ (key & 7);
      __builtin_amdgcn_global_load_lds(
          (const AS1 void*)&krope16[(growk + key) * 64 + ss * 8],
          (AS3 void*)(KrL + wbase), 16, 0, 0);
    }
  };
  auto issueV = [&](int c, int buf) {
    const int j0 = c * KC;
#pragma unroll
    for (int it = 0; it < 2; ++it) {
      const int u = tid + (it << 9);
      const int vd = u >> 3, sl = u & 7;
      const int ss = sl ^ (vd & 7);
      __builtin_amdgcn_global_load_lds(
          (const AS1 void*)&vTh[(size_t)vd * 2048 + j0 + ss * 8],
          (AS3 void*)(VtL + buf * 8192 + wbase + it * 4096), 16, 0, 0);
    }
  };

  // ---- prologue ----
  issueK(0);
  issueV(0, 0);
  __builtin_amdgcn_sched_barrier(0);

  short8 qf[6];
#pragma unroll
  for (int ks = 0; ks < 6; ++ks)
    qf[ks] = *(const short8*)&q16[(growq + l15) * 3072 + h * HD + ks * 32 + quad * 8];

  f32x4 oacc[8] = {};
  float mrow[4], lrow[4];
  int q_r[4];
#pragma unroll
  for (int r = 0; r < 4; ++r) {
    mrow[r] = -1e30f; lrow[r] = 0.f;
    q_r[r] = qbase + quad * 4 + r;
  }

  const int nchunk = (q0 + QT) / KC;

  asm volatile("s_waitcnt vmcnt(2)" ::: "memory");   // K(0) landed (V may fly)
  __builtin_amdgcn_s_barrier();
  __builtin_amdgcn_sched_barrier(0);

  for (int c = 0; c < nchunk; ++c) {
    const int j0 = c * KC;
    const bool more = (c + 1 < nchunk);
    const int buf = c & 1;
    const bool skipw = (j0 > qbase + 15);   // chunk fully above diagonal for this wave

    // ---- QK^T on K(c) ----
    f32x4 sacc[4] = {};
    if (!skipw) {
      __builtin_amdgcn_s_setprio(1);
#pragma unroll
      for (int ks = 0; ks < 6; ++ks) {
        short8 kf[4];
        if (ks < 4) {
#pragma unroll
          for (int kt = 0; kt < 4; ++kt)
            kf[kt] = *(const short8*)&Kn[(kt * 16 + l15) * 128 + (((ks * 4 + quad) ^ (l15 & 7)) << 3)];
        } else {
#pragma unroll
          for (int kt = 0; kt < 4; ++kt)
            kf[kt] = *(const short8*)&Kr[(kt * 16 + l15) * 64 + ((((ks - 4) * 4 + quad) ^ (l15 & 7)) << 3)];
        }
#pragma unroll
        for (int kt = 0; kt < 4; ++kt)
          sacc[kt] = __builtin_amdgcn_mfma_f32_16x16x32_bf16(qf[ks], kf[kt], sacc[kt], 0, 0, 0);
      }
      __builtin_amdgcn_s_setprio(0);
    }

    __builtin_amdgcn_s_barrier();          // all waves done reading Kn/Kr
    if (more) issueK(c + 1);               // DMA, flies under softmax+PV
    __builtin_amdgcn_sched_barrier(0);

    if (!skipw) {
      if (j0 + KC - 1 > qbase) {
#pragma unroll
        for (int kt = 0; kt < 4; ++kt) {
          const int key = j0 + kt * 16 + l15;
#pragma unroll
          for (int r = 0; r < 4; ++r)
            sacc[kt][r] = (key <= q_r[r]) ? sacc[kt][r] : -1e30f;
        }
      }
      float pmax[4];
#pragma unroll
      for (int r = 0; r < 4; ++r) {
        float mx = fmaxf(fmaxf(sacc[0][r], sacc[1][r]),
                         fmaxf(sacc[2][r], sacc[3][r]));
        mx = fmaxf(mx, __shfl_xor(mx, 1));
        mx = fmaxf(mx, __shfl_xor(mx, 2));
        mx = fmaxf(mx, __shfl_xor(mx, 4));
        mx = fmaxf(mx, __shfl_xor(mx, 8));
        pmax[r] = mx;
      }
      bool need = false;
#pragma unroll
      for (int r = 0; r < 4; ++r)
        need = need || (pmax[r] > mrow[r] + 8.0f);
      const bool upd = __any(need);
      float alpha[4];
      if (upd) {
#pragma unroll
        for (int r = 0; r < 4; ++r) {
          const float mn = fmaxf(mrow[r], pmax[r]);
          alpha[r] = __expf(mrow[r] - mn);
          mrow[r] = mn;
        }
      }
#pragma unroll
      for (int kt = 0; kt < 4; ++kt)
#pragma unroll
        for (int r = 0; r < 4; ++r)
          sacc[kt][r] = __expf(sacc[kt][r] - mrow[r]);
#pragma unroll
      for (int r = 0; r < 4; ++r) {
        float rs = sacc[0][r] + sacc[1][r] + sacc[2][r] + sacc[3][r];
        rs += __shfl_xor(rs, 1);
        rs += __shfl_xor(rs, 2);
        rs += __shfl_xor(rs, 4);
        rs += __shfl_xor(rs, 8);
        lrow[r] = upd ? lrow[r] * alpha[r] + rs : lrow[r] + rs;
      }
#pragma unroll
      for (int kt = 0; kt < 4; ++kt)
#pragma unroll
        for (int r = 0; r < 4; ++r)
          Pb[wq][(quad * 4 + r) * 72 + kt * 16 + l15] = f2bf(sacc[kt][r]);
      if (upd) {
#pragma unroll
        for (int nt = 0; nt < 8; ++nt)
#pragma unroll
          for (int r = 0; r < 4; ++r)
            oacc[nt][r] *= alpha[r];
      }
    }

    if (more) asm volatile("s_waitcnt vmcnt(3)" ::: "memory");  // V(c) landed; K(c+1) flying
    else      asm volatile("s_waitcnt vmcnt(0)" ::: "memory");
    __builtin_amdgcn_s_barrier();          // Vt[buf] visible blockwide
    __builtin_amdgcn_sched_barrier(0);

    if (!skipw) {
      __builtin_amdgcn_s_setprio(1);
#pragma unroll
      for (int st = 0; st < 2; ++st) {
        const short8 pf = *(const short8*)&Pb[wq][l15 * 72 + st * 32 + quad * 8];
#pragma unroll
        for (int nt = 0; nt < 8; ++nt) {
          const short8 vf = *(const short8*)&Vt[buf][(nt * 16 + l15) * 64 + (((st * 4 + quad) ^ (l15 & 7)) << 3)];
          oacc[nt] = __builtin_amdgcn_mfma_f32_16x16x32_bf16(pf, vf, oacc[nt], 0, 0, 0);
        }
      }
      __builtin_amdgcn_s_setprio(0);
    }

    if (more) {
      issueV(c + 1, buf ^ 1);              // other buffer; no barrier needed
      __builtin_amdgcn_sched_barrier(0);
      asm volatile("s_waitcnt vmcnt(2)" ::: "memory");  // K(c+1) landed; V(c+1) flying
      __builtin_amdgcn_s_barrier();        // K(c+1) visible blockwide
      __builtin_amdgcn_sched_barrier(0);
    }
  }

  // ---- store (bf16) ----
#pragma unroll
  for (int r = 0; r < 4; ++r) {
    const float inv = 1.0f / lrow[r];
    const size_t orow = growq + quad * 4 + r;
#pragma unroll
    for (int nt = 0; nt < 8; ++nt)
      outp[orow * 2048 + h * 128 + nt * 16 + l15] = f2bf(oacc[nt][r] * inv);
  }
}

extern "C" void kernel_launch(void* const* d_in, const int* in_sizes, int n_in,
                              void* d_out, int out_size, void* d_ws, size_t ws_size,
                              hipStream_t stream) {
  const float* x        = (const float*)d_in[0];
  const float* wd_q     = (const float*)d_in[1];
  const float* wu_q     = (const float*)d_in[2];
  const float* q_norm_w = (const float*)d_in[3];
  const float* wd_kv    = (const float*)d_in[4];
  const float* wu_kv    = (const float*)d_in[5];
  const float* kv_norm_w= (const float*)d_in[6];
  const float* wo       = (const float*)d_in[7];
  const float* cosb     = (const float*)d_in[8];
  const float* sinb     = (const float*)d_in[9];
  float* out = (float*)d_out;

  char* ws = (char*)d_ws;
  float*    cq    = (float*)(ws + 0);            // 4096x1536 f32 (dead after rmsnorm)
  ushort_t* q16   = (ushort_t*)(ws + 0);         // 4096x3072 bf16 (overwrites cq in q-up)
  ushort_t* kb16  = (ushort_t*)(ws + 50331648);  // 4096x2048 bf16 K rows (16MB)
  ushort_t* vT    = (ushort_t*)(ws + 67108864);  // [b*16+h][128 vd][2048 tok] bf16 (16MB)
  ushort_t* xb    = (ushort_t*)(ws + 83886080);  // 4096x2048 bf16 pre-cast x (16MB)
  ushort_t* cqn   = (ushort_t*)(ws + 117440512); // 4096x1536 bf16
  float*    kvd   = (float*)(ws + 130023424);    // 4096x640 f32 (dead after rmsnorm2)
  ushort_t* ckvn  = (ushort_t*)(ws + 140509184); // 4096x512 bf16 (dead after kvu gemm)
  ushort_t* aoutb = (ushort_t*)(ws + 130023424); // 4096x2048 bf16, aliases kvd+ckvn
  ushort_t* krope16 = (ushort_t*)(ws + 146800640); // 4096x64 bf16
  ushort_t* wdqt  = (ushort_t*)(ws + 147849216); // 1536x2048 bf16  (contiguous with ->)
  ushort_t* wdkvt = (ushort_t*)(ws + 154140672); // 640x2048 bf16   (fused B = [wdqt;wdkvt])
  ushort_t* wuqt  = (ushort_t*)(ws + 156762112); // 3072x1536 bf16
  ushort_t* wukvt = (ushort_t*)(ws + 166199296); // 4096x512 bf16
  ushort_t* wot   = (ushort_t*)(ws + 170393600); // 2048x2048 bf16

  const int M = 2 * S_LEN;  // 4096
  dim3 blk(256);
  dim3 blk512(512);

  prep_k<<<19200, blk, 0, stream>>>(x, xb, wd_q, wdqt, wd_kv, wdkvt,
                                    wu_q, wuqt, wu_kv, wukvt, wo, wot);

  mfma_gemm<2><<<dim3(2176 / 128, M / 128), blk512, 0, stream>>>(
      xb, wdqt, cq, M, 2176, 2048, 1536, nullptr, nullptr, kvd, nullptr, nullptr);
  rmsnorm2_k<<<2 * M, 256, 0, stream>>>(cq, cqn, q_norm_w, kvd, ckvn, kv_norm_w,
                                        krope16, cosb, sinb);
  mfma_gemm<3><<<dim3(3072 / 128, M / 128), blk512, 0, stream>>>(
      cqn, wuqt, nullptr, M, 3072, 1536, 0, q16, nullptr, nullptr, cosb, sinb);
  mfma_gemm<1><<<dim3(4096 / 128, M / 128), blk512, 0, stream>>>(
      ckvn, wukvt, nullptr, M, 4096, 512, 0, kb16, vT, nullptr, nullptr, nullptr);
  attn_k<<<2 * NHEAD * (S_LEN / QT), 512, 0, stream>>>(q16, kb16, vT, krope16, aoutb);
  mfma_gemm<0><<<dim3(2048 / 128, M / 128), blk512, 0, stream>>>(
      aoutb, wot, out, M, 2048, 2048, 2048, nullptr, nullptr, nullptr, nullptr, nullptr);
}

// Round 9
// 444.117 us; speedup vs baseline: 1.9665x; 1.0415x over previous
//
#include <hip/hip_runtime.h>
#include <hip/hip_bf16.h>

#define S_LEN 2048
#define NHEAD 16
#define NOPE 128
#define ROPE 64
#define HD 192   // nope + rope

typedef unsigned short ushort_t;
typedef __attribute__((ext_vector_type(8))) short short8;
typedef __attribute__((ext_vector_type(4))) float f32x4;

#define AS1 __attribute__((address_space(1)))
#define AS3 __attribute__((address_space(3)))

__device__ __forceinline__ unsigned short f2bf(float f) {
  unsigned int u = __float_as_uint(f);
  return (unsigned short)((u + 0x7FFFu + ((u >> 16) & 1u)) >> 16);
}

// ---------------- fused prep: cast x -> bf16  +  5x transpose_cast ----------------
__global__ __launch_bounds__(256) void prep_k(const float* __restrict__ x, ushort_t* __restrict__ xb,
                                              const float* __restrict__ wd_q, ushort_t* __restrict__ wdqt,
                                              const float* __restrict__ wd_kv, ushort_t* __restrict__ wdkvt,
                                              const float* __restrict__ wu_q, ushort_t* __restrict__ wuqt,
                                              const float* __restrict__ wu_kv, ushort_t* __restrict__ wukvt,
                                              const float* __restrict__ wo, ushort_t* __restrict__ wot) {
  int id = blockIdx.x;
  if (id < 4096) {
    const int i = id * 256 + threadIdx.x;
    const float4 v0 = *(const float4*)&x[(size_t)i * 8];
    const float4 v1 = *(const float4*)&x[(size_t)i * 8 + 4];
    union { uint4 u; ushort_t s[8]; } pk;
    pk.s[0] = f2bf(v0.x); pk.s[1] = f2bf(v0.y); pk.s[2] = f2bf(v0.z); pk.s[3] = f2bf(v0.w);
    pk.s[4] = f2bf(v1.x); pk.s[5] = f2bf(v1.y); pk.s[6] = f2bf(v1.z); pk.s[7] = f2bf(v1.w);
    *(uint4*)&xb[(size_t)i * 8] = pk.u;
    return;
  }
  id -= 4096;
  const float* B; ushort_t* Bt; int K, N, gx;
  if (id < 3072)               { B = wd_q;  Bt = wdqt;  K = 2048; N = 1536; gx = 48;  }
  else if ((id -= 3072) < 1280){ B = wd_kv; Bt = wdkvt; K = 2048; N = 576;  gx = 20;  }
  else if ((id -= 1280) < 4608){ B = wu_q;  Bt = wuqt;  K = 1536; N = 3072; gx = 96;  }
  else if ((id -= 4608) < 2048){ B = wu_kv; Bt = wukvt; K = 512;  N = 4096; gx = 128; }
  else { id -= 2048;             B = wo;    Bt = wot;   K = 2048; N = 2048; gx = 64;  }
  __shared__ float tile[32][33];
  const int tx = threadIdx.x & 31, ty = threadIdx.x >> 5;  // 32 x 8
  const int n0 = (id % gx) * 32, k0 = (id / gx) * 32;
  if (n0 >= N) {
#pragma unroll
    for (int r = 0; r < 4; ++r)
      Bt[(size_t)(n0 + ty + 8 * r) * K + k0 + tx] = 0;
    return;
  }
#pragma unroll
  for (int r = 0; r < 4; ++r)
    tile[ty + 8 * r][tx] = B[(size_t)(k0 + ty + 8 * r) * N + n0 + tx];
  __syncthreads();
#pragma unroll
  for (int r = 0; r < 4; ++r)
    Bt[(size_t)(n0 + ty + 8 * r) * K + k0 + tx] = f2bf(tile[tx][ty + 8 * r]);
}

// ---------------- MFMA GEMM: 512 thr / 8 waves / 128x128 tile ----------------
// Round 9: (T3/T4) double-buffered LDS + raw s_barrier + counted vmcnt(2) —
// step c issues next step's global_load_lds into the other buffer; the wait
// covers only loads issued one full compute phase earlier. Removes the
// vmcnt(0) drain at every barrier.
// (T2) LDS slot swizzle: linear DMA dest, global SOURCE slot ^= (row>>1)&3
// (self-inverse), read side quad ^= (l15>>1)&3. Fragment reads go from 8-way
// bank conflict (2 of 8 16B-windows) to 2-way (8 of 8) = free per m136.
// EPI=0: f32 C.  EPI=1: KV split.  EPI=2: down-proj routing.  EPI=3: q-up RoPE.
template<int EPI>
__global__ __launch_bounds__(512, 4) void mfma_gemm(const ushort_t* __restrict__ A,
                                                 const ushort_t* __restrict__ Bt,
                                                 float* __restrict__ C,
                                                 int M, int N, int K, int ldc,
                                                 ushort_t* __restrict__ kb16o,
                                                 ushort_t* __restrict__ vto,
                                                 float* __restrict__ C2,
                                                 const float* __restrict__ cosb,
                                                 const float* __restrict__ sinb) {
  __shared__ ushort_t As[2][128 * 32];
  __shared__ ushort_t Bs[2][128 * 32];
  const int tid = threadIdx.x;
  const int lane = tid & 63;
  const int wave = tid >> 6;        // 0..7
  const int wm = wave & 3, wn = wave >> 2;   // 4 m-strips x 2 n-strips

  unsigned bxu = blockIdx.x, byu = blockIdx.y;
  {
    const unsigned gx = gridDim.x;
    const unsigned nwg = gx * gridDim.y;
    if ((nwg & 7u) == 0u) {
      unsigned flat = byu * gx + bxu;
      const unsigned cpx = nwg >> 3;
      flat = (flat & 7u) * cpx + (flat >> 3);
      bxu = flat % gx; byu = flat / gx;
    }
  }
  const int m0 = byu * 128, n0 = bxu * 128;
  const int l15 = lane & 15, quad = lane >> 4;

  f32x4 acc[2][4] = {};

  const int ma0 = tid >> 2;                                  // row 0..127
  const int scol = (((tid & 3) ^ ((tid >> 3) & 3)) << 3);    // swizzled src col (shorts)
  const int rsw = (l15 >> 1) & 3;                            // read-side slot XOR

  typedef AS3 ushort_t lds_us;
  lds_us* AsL = (lds_us*)As;
  lds_us* BsL = (lds_us*)Bs;
  const int wbase = wave * 512;   // shorts: 64 lanes * 8 shorts

  auto issue = [&](int k0, int buf) {
    __builtin_amdgcn_global_load_lds(
        (const AS1 void*)&A[(size_t)(m0 + ma0) * K + k0 + scol],
        (AS3 void*)(AsL + buf * 4096 + wbase), 16, 0, 0);
    __builtin_amdgcn_global_load_lds(
        (const AS1 void*)&Bt[(size_t)(n0 + ma0) * K + k0 + scol],
        (AS3 void*)(BsL + buf * 4096 + wbase), 16, 0, 0);
  };

  const int nk = K >> 5;
  issue(0, 0);
  __builtin_amdgcn_sched_barrier(0);

  for (int ks = 0; ks < nk; ++ks) {
    const int buf = ks & 1;
    const bool more = (ks + 1 < nk);
    if (more) {                       // prefetch next K-step into other buffer
      issue((ks + 1) << 5, buf ^ 1);  // safe: buf^1 last read at ks-1, end-barrier passed
      __builtin_amdgcn_sched_barrier(0);
      asm volatile("s_waitcnt vmcnt(2)" ::: "memory");   // buf's 2 loads landed
    } else {
      asm volatile("s_waitcnt vmcnt(0)" ::: "memory");
    }
    __builtin_amdgcn_s_barrier();     // buf visible blockwide
    __builtin_amdgcn_sched_barrier(0);

    short8 af[2], bf[4];
#pragma unroll
    for (int i = 0; i < 2; ++i)
      af[i] = *(const short8*)&As[buf][(wm * 32 + i * 16 + l15) * 32 + ((quad ^ rsw) << 3)];
#pragma unroll
    for (int j = 0; j < 4; ++j)
      bf[j] = *(const short8*)&Bs[buf][(wn * 64 + j * 16 + l15) * 32 + ((quad ^ rsw) << 3)];
    __builtin_amdgcn_s_setprio(1);
#pragma unroll
    for (int i = 0; i < 2; ++i)
#pragma unroll
      for (int j = 0; j < 4; ++j)
        acc[i][j] = __builtin_amdgcn_mfma_f32_16x16x32_bf16(af[i], bf[j], acc[i][j], 0, 0, 0);
    __builtin_amdgcn_s_setprio(0);
    __builtin_amdgcn_s_barrier();     // all waves done reading buf (overwritten at ks+2)
    __builtin_amdgcn_sched_barrier(0);
  }

  if constexpr (EPI == 0) {
#pragma unroll
    for (int i = 0; i < 2; ++i)
#pragma unroll
      for (int r = 0; r < 4; ++r) {
        const size_t rg = (size_t)(m0 + wm * 32 + i * 16 + quad * 4 + r);
#pragma unroll
        for (int j = 0; j < 4; ++j)
          C[rg * ldc + n0 + wn * 64 + j * 16 + l15] = acc[i][j][r];
      }
  } else if constexpr (EPI == 1) {
    const int h = n0 >> 8;
    const bool is_v = (n0 >> 7) & 1;
    if (!is_v) {
#pragma unroll
      for (int i = 0; i < 2; ++i)
#pragma unroll
        for (int r = 0; r < 4; ++r) {
          const size_t rg = (size_t)(m0 + wm * 32 + i * 16 + quad * 4 + r);
#pragma unroll
          for (int j = 0; j < 4; ++j)
            kb16o[rg * 2048 + h * 128 + wn * 64 + j * 16 + l15] = f2bf(acc[i][j][r]);
        }
    } else {
      __shared__ __align__(16) ushort_t trb[64 * 136];
      const int bb = m0 >> 11;
      const int m0loc = m0 & 2047;
      ushort_t* vbase = vto + ((size_t)(bb * NHEAD + h) * 128) * 2048;
#pragma unroll
      for (int vh = 0; vh < 2; ++vh) {
        if (wn == vh) {
#pragma unroll
          for (int i = 0; i < 2; ++i)
#pragma unroll
            for (int r = 0; r < 4; ++r) {
              const int tloc = wm * 32 + i * 16 + quad * 4 + r;   // 0..127
#pragma unroll
              for (int j = 0; j < 4; ++j)
                trb[(j * 16 + l15) * 136 + tloc] = f2bf(acc[i][j][r]);
            }
        }
        __syncthreads();
#pragma unroll
        for (int it = 0; it < 2; ++it) {
          const int u = tid + (it << 9);
          const int vdl = u >> 4, tc = u & 15;
          *(uint4*)&vbase[(size_t)(vh * 64 + vdl) * 2048 + m0loc + tc * 8] =
              *(const uint4*)&trb[vdl * 136 + tc * 8];
        }
        __syncthreads();
      }
    }
  } else if constexpr (EPI == 2) {
    float* Cd;
    int ldd, nc;
    if (n0 < 1536) { Cd = C;  ldd = 1536; nc = n0; }
    else           { Cd = C2; ldd = 640;  nc = n0 - 1536; }
#pragma unroll
    for (int i = 0; i < 2; ++i)
#pragma unroll
      for (int r = 0; r < 4; ++r) {
        const size_t rg = (size_t)(m0 + wm * 32 + i * 16 + quad * 4 + r);
#pragma unroll
        for (int j = 0; j < 4; ++j)
          Cd[rg * ldd + nc + wn * 64 + j * 16 + l15] = acc[i][j][r];
      }
  } else {  // EPI == 3: q-up epilogue: scale + RoPE + bf16 -> qo16 (kb16o arg)
    const float qscale = 0.07216878364870323f;  // 1/sqrt(192)
#pragma unroll
    for (int i = 0; i < 2; ++i)
#pragma unroll
      for (int r = 0; r < 4; ++r) {
        const int rg = m0 + wm * 32 + i * 16 + quad * 4 + r;
        const int sp = rg & (S_LEN - 1);
#pragma unroll
        for (int j = 0; j < 4; ++j) {
          const int col = n0 + wn * 64 + j * 16 + l15;
          float val = acc[i][j][r] * qscale;
          const float pr = __shfl_xor(val, 1);   // adjacent column (same row)
          const int dd = col % HD;               // 0..191 within head
          float o = val;
          if (dd >= NOPE) {
            const int d = (dd - NOPE) >> 1;
            const float cc = cosb[sp * 32 + d];
            const float sn = sinb[sp * 32 + d];
            o = (lane & 1) ? (pr * sn + val * cc) : (val * cc - pr * sn);
          }
          kb16o[(size_t)rg * 3072 + col] = f2bf(o);
        }
      }
  }
}

// ---------------- merged RMSNorm (+ fused k-rope on kv rows) ----------------
__global__ __launch_bounds__(256) void rmsnorm2_k(const float* __restrict__ cq,
                                                  ushort_t* __restrict__ cqn,
                                                  const float* __restrict__ qw,
                                                  const float* __restrict__ kvd,
                                                  ushort_t* __restrict__ ckvn,
                                                  const float* __restrict__ kvw,
                                                  ushort_t* __restrict__ krope16,
                                                  const float* __restrict__ cosb,
                                                  const float* __restrict__ sinb) {
  const bool is_q = blockIdx.x < 4096;
  const int row = blockIdx.x & 4095;
  const int tid = threadIdx.x;
  const float* ip = is_q ? cq + (size_t)row * 1536 : kvd + (size_t)row * 640;
  ushort_t* op = is_q ? cqn + (size_t)row * 1536 : ckvn + (size_t)row * 512;
  const float* w = is_q ? qw : kvw;
  const int L = is_q ? 1536 : 512;
  const int nper = L >> 8;
  float r[6];
  float ss = 0.f;
  for (int j = 0; j < nper; ++j) {
    r[j] = ip[tid + (j << 8)];
    ss += r[j] * r[j];
  }
  for (int off = 32; off; off >>= 1) ss += __shfl_down(ss, off);
  __shared__ float wsum[4];
  __shared__ float scale_s;
  if ((tid & 63) == 0) wsum[tid >> 6] = ss;
  __syncthreads();
  if (tid == 0) {
    float t = wsum[0] + wsum[1] + wsum[2] + wsum[3];
    scale_s = rsqrtf(t / (float)L + 1e-5f);
  }
  __syncthreads();
  const float sc = scale_s;
  for (int j = 0; j < nper; ++j)
    op[tid + (j << 8)] = f2bf(r[j] * sc * w[tid + (j << 8)]);
  if (!is_q && tid < 32) {           // fused k-rope (kvd cols 512..639)
    const int d = tid;
    const int s = row & (S_LEN - 1);
    const float c = cosb[s * 32 + d];
    const float sn = sinb[s * 32 + d];
    const float* kb = kvd + (size_t)row * 640 + 512;
    const float y0 = kb[2 * d], y1 = kb[2 * d + 1];
    union { unsigned int u; ushort_t s2[2]; } pk;
    pk.s2[0] = f2bf(y0 * c - y1 * sn);
    pk.s2[1] = f2bf(y0 * sn + y1 * c);
    *(unsigned int*)&krope16[(size_t)row * 64 + 2 * d] = pk.u;
  }
}

// ---------------- MFMA flash attention (unchanged from round 8) ----------------
#define QT 128
#define KC 64
__global__ __launch_bounds__(512, 4) void attn_k(const ushort_t* __restrict__ q16,
                                                 const ushort_t* __restrict__ kb16,
                                                 const ushort_t* __restrict__ vT,
                                                 const ushort_t* __restrict__ krope16,
                                                 ushort_t* __restrict__ outp) {
  const int bx = blockIdx.x;
  const int g = bx & 31;            // (b,h) group -> XCD g%8
  const int s = bx >> 5;            // slot 0..15
  const int tile = (s < 8) ? s : 23 - s;
  const int b = g >> 4, h = g & 15;
  const int q0 = tile * QT;
  const int tid = threadIdx.x;
  const int lane = tid & 63;
  const int wq = tid >> 6;          // 0..7
  const int l15 = lane & 15, quad = lane >> 4;

  __shared__ __align__(16) ushort_t Kn[64 * 128];    // 16 KB
  __shared__ __align__(16) ushort_t Kr[64 * 64];     //  8 KB
  __shared__ __align__(16) ushort_t Vt[2][128 * 64]; // 32 KB (double buffer)
  __shared__ __align__(16) ushort_t Pb[8][16 * 72];  // 18 KB (per-wave 16x64 P)

  const int qbase = q0 + wq * 16;   // wave's 16 q-rows
  const size_t growq = (size_t)b * S_LEN + qbase;
  const ushort_t* vTh = vT + ((size_t)(b * NHEAD + h) * 128) * 2048;
  const size_t bbase = (size_t)b * S_LEN;

  typedef AS3 ushort_t lds_us;
  lds_us* KnL = (lds_us*)Kn;
  lds_us* KrL = (lds_us*)Kr;
  lds_us* VtL = (lds_us*)Vt;
  const int wbase = wq * 512;       // shorts (64 lanes x 8 shorts)

  auto issueK = [&](int c) {
    const size_t growk = bbase + (size_t)c * KC;
#pragma unroll
    for (int it = 0; it < 2; ++it) {
      const int u = tid + (it << 9);
      const int key = u >> 4, sl = u & 15;
      const int ss = sl ^ (key & 7);
      __builtin_amdgcn_global_load_lds(
          (const AS1 void*)&kb16[(growk + key) * 2048 + h * 128 + ss * 8],
          (AS3 void*)(KnL + wbase + it * 4096), 16, 0, 0);
    }
    {
      const int u = tid;
      const int key = u >> 3, sl = u & 7;
      const int ss = sl ^ (key & 7);
      __builtin_amdgcn_global_load_lds(
          (const AS1 void*)&krope16[(growk + key) * 64 + ss * 8],
          (AS3 void*)(KrL + wbase), 16, 0, 0);
    }
  };
  auto issueV = [&](int c, int buf) {
    const int j0 = c * KC;
#pragma unroll
    for (int it = 0; it < 2; ++it) {
      const int u = tid + (it << 9);
      const int vd = u >> 3, sl = u & 7;
      const int ss = sl ^ (vd & 7);
      __builtin_amdgcn_global_load_lds(
          (const AS1 void*)&vTh[(size_t)vd * 2048 + j0 + ss * 8],
          (AS3 void*)(VtL + buf * 8192 + wbase + it * 4096), 16, 0, 0);
    }
  };

  // ---- prologue ----
  issueK(0);
  issueV(0, 0);
  __builtin_amdgcn_sched_barrier(0);

  short8 qf[6];
#pragma unroll
  for (int ks = 0; ks < 6; ++ks)
    qf[ks] = *(const short8*)&q16[(growq + l15) * 3072 + h * HD + ks * 32 + quad * 8];

  f32x4 oacc[8] = {};
  float mrow[4], lrow[4];
  int q_r[4];
#pragma unroll
  for (int r = 0; r < 4; ++r) {
    mrow[r] = -1e30f; lrow[r] = 0.f;
    q_r[r] = qbase + quad * 4 + r;
  }

  const int nchunk = (q0 + QT) / KC;

  asm volatile("s_waitcnt vmcnt(2)" ::: "memory");   // K(0) landed (V may fly)
  __builtin_amdgcn_s_barrier();
  __builtin_amdgcn_sched_barrier(0);

  for (int c = 0; c < nchunk; ++c) {
    const int j0 = c * KC;
    const bool more = (c + 1 < nchunk);
    const int buf = c & 1;
    const bool skipw = (j0 > qbase + 15);   // chunk fully above diagonal for this wave

    // ---- QK^T on K(c) ----
    f32x4 sacc[4] = {};
    if (!skipw) {
      __builtin_amdgcn_s_setprio(1);
#pragma unroll
      for (int ks = 0; ks < 6; ++ks) {
        short8 kf[4];
        if (ks < 4) {
#pragma unroll
          for (int kt = 0; kt < 4; ++kt)
            kf[kt] = *(const short8*)&Kn[(kt * 16 + l15) * 128 + (((ks * 4 + quad) ^ (l15 & 7)) << 3)];
        } else {
#pragma unroll
          for (int kt = 0; kt < 4; ++kt)
            kf[kt] = *(const short8*)&Kr[(kt * 16 + l15) * 64 + ((((ks - 4) * 4 + quad) ^ (l15 & 7)) << 3)];
        }
#pragma unroll
        for (int kt = 0; kt < 4; ++kt)
          sacc[kt] = __builtin_amdgcn_mfma_f32_16x16x32_bf16(qf[ks], kf[kt], sacc[kt], 0, 0, 0);
      }
      __builtin_amdgcn_s_setprio(0);
    }

    __builtin_amdgcn_s_barrier();          // all waves done reading Kn/Kr
    if (more) issueK(c + 1);               // DMA, flies under softmax+PV
    __builtin_amdgcn_sched_barrier(0);

    if (!skipw) {
      if (j0 + KC - 1 > qbase) {
#pragma unroll
        for (int kt = 0; kt < 4; ++kt) {
          const int key = j0 + kt * 16 + l15;
#pragma unroll
          for (int r = 0; r < 4; ++r)
            sacc[kt][r] = (key <= q_r[r]) ? sacc[kt][r] : -1e30f;
        }
      }
      float pmax[4];
#pragma unroll
      for (int r = 0; r < 4; ++r) {
        float mx = fmaxf(fmaxf(sacc[0][r], sacc[1][r]),
                         fmaxf(sacc[2][r], sacc[3][r]));
        mx = fmaxf(mx, __shfl_xor(mx, 1));
        mx = fmaxf(mx, __shfl_xor(mx, 2));
        mx = fmaxf(mx, __shfl_xor(mx, 4));
        mx = fmaxf(mx, __shfl_xor(mx, 8));
        pmax[r] = mx;
      }
      bool need = false;
#pragma unroll
      for (int r = 0; r < 4; ++r)
        need = need || (pmax[r] > mrow[r] + 8.0f);
      const bool upd = __any(need);
      float alpha[4];
      if (upd) {
#pragma unroll
        for (int r = 0; r < 4; ++r) {
          const float mn = fmaxf(mrow[r], pmax[r]);
          alpha[r] = __expf(mrow[r] - mn);
          mrow[r] = mn;
        }
      }
#pragma unroll
      for (int kt = 0; kt < 4; ++kt)
#pragma unroll
        for (int r = 0; r < 4; ++r)
          sacc[kt][r] = __expf(sacc[kt][r] - mrow[r]);
#pragma unroll
      for (int r = 0; r < 4; ++r) {
        float rs = sacc[0][r] + sacc[1][r] + sacc[2][r] + sacc[3][r];
        rs += __shfl_xor(rs, 1);
        rs += __shfl_xor(rs, 2);
        rs += __shfl_xor(rs, 4);
        rs += __shfl_xor(rs, 8);
        lrow[r] = upd ? lrow[r] * alpha[r] + rs : lrow[r] + rs;
      }
#pragma unroll
      for (int kt = 0; kt < 4; ++kt)
#pragma unroll
        for (int r = 0; r < 4; ++r)
          Pb[wq][(quad * 4 + r) * 72 + kt * 16 + l15] = f2bf(sacc[kt][r]);
      if (upd) {
#pragma unroll
        for (int nt = 0; nt < 8; ++nt)
#pragma unroll
          for (int r = 0; r < 4; ++r)
            oacc[nt][r] *= alpha[r];
      }
    }

    if (more) asm volatile("s_waitcnt vmcnt(3)" ::: "memory");  // V(c) landed; K(c+1) flying
    else      asm volatile("s_waitcnt vmcnt(0)" ::: "memory");
    __builtin_amdgcn_s_barrier();          // Vt[buf] visible blockwide
    __builtin_amdgcn_sched_barrier(0);

    if (!skipw) {
      __builtin_amdgcn_s_setprio(1);
#pragma unroll
      for (int st = 0; st < 2; ++st) {
        const short8 pf = *(const short8*)&Pb[wq][l15 * 72 + st * 32 + quad * 8];
#pragma unroll
        for (int nt = 0; nt < 8; ++nt) {
          const short8 vf = *(const short8*)&Vt[buf][(nt * 16 + l15) * 64 + (((st * 4 + quad) ^ (l15 & 7)) << 3)];
          oacc[nt] = __builtin_amdgcn_mfma_f32_16x16x32_bf16(pf, vf, oacc[nt], 0, 0, 0);
        }
      }
      __builtin_amdgcn_s_setprio(0);
    }

    if (more) {
      issueV(c + 1, buf ^ 1);              // other buffer; no barrier needed
      __builtin_amdgcn_sched_barrier(0);
      asm volatile("s_waitcnt vmcnt(2)" ::: "memory");  // K(c+1) landed; V(c+1) flying
      __builtin_amdgcn_s_barrier();        // K(c+1) visible blockwide
      __builtin_amdgcn_sched_barrier(0);
    }
  }

  // ---- store (bf16) ----
#pragma unroll
  for (int r = 0; r < 4; ++r) {
    const float inv = 1.0f / lrow[r];
    const size_t orow = growq + quad * 4 + r;
#pragma unroll
    for (int nt = 0; nt < 8; ++nt)
      outp[orow * 2048 + h * 128 + nt * 16 + l15] = f2bf(oacc[nt][r] * inv);
  }
}

extern "C" void kernel_launch(void* const* d_in, const int* in_sizes, int n_in,
                              void* d_out, int out_size, void* d_ws, size_t ws_size,
                              hipStream_t stream) {
  const float* x        = (const float*)d_in[0];
  const float* wd_q     = (const float*)d_in[1];
  const float* wu_q     = (const float*)d_in[2];
  const float* q_norm_w = (const float*)d_in[3];
  const float* wd_kv    = (const float*)d_in[4];
  const float* wu_kv    = (const float*)d_in[5];
  const float* kv_norm_w= (const float*)d_in[6];
  const float* wo       = (const float*)d_in[7];
  const float* cosb     = (const float*)d_in[8];
  const float* sinb     = (const float*)d_in[9];
  float* out = (float*)d_out;

  char* ws = (char*)d_ws;
  float*    cq    = (float*)(ws + 0);            // 4096x1536 f32 (dead after rmsnorm)
  ushort_t* q16   = (ushort_t*)(ws + 0);         // 4096x3072 bf16 (overwrites cq in q-up)
  ushort_t* kb16  = (ushort_t*)(ws + 50331648);  // 4096x2048 bf16 K rows (16MB)
  ushort_t* vT    = (ushort_t*)(ws + 67108864);  // [b*16+h][128 vd][2048 tok] bf16 (16MB)
  ushort_t* xb    = (ushort_t*)(ws + 83886080);  // 4096x2048 bf16 pre-cast x (16MB)
  ushort_t* cqn   = (ushort_t*)(ws + 117440512); // 4096x1536 bf16
  float*    kvd   = (float*)(ws + 130023424);    // 4096x640 f32 (dead after rmsnorm2)
  ushort_t* ckvn  = (ushort_t*)(ws + 140509184); // 4096x512 bf16 (dead after kvu gemm)
  ushort_t* aoutb = (ushort_t*)(ws + 130023424); // 4096x2048 bf16, aliases kvd+ckvn
  ushort_t* krope16 = (ushort_t*)(ws + 146800640); // 4096x64 bf16
  ushort_t* wdqt  = (ushort_t*)(ws + 147849216); // 1536x2048 bf16  (contiguous with ->)
  ushort_t* wdkvt = (ushort_t*)(ws + 154140672); // 640x2048 bf16   (fused B = [wdqt;wdkvt])
  ushort_t* wuqt  = (ushort_t*)(ws + 156762112); // 3072x1536 bf16
  ushort_t* wukvt = (ushort_t*)(ws + 166199296); // 4096x512 bf16
  ushort_t* wot   = (ushort_t*)(ws + 170393600); // 2048x2048 bf16

  const int M = 2 * S_LEN;  // 4096
  dim3 blk(256);
  dim3 blk512(512);

  prep_k<<<19200, blk, 0, stream>>>(x, xb, wd_q, wdqt, wd_kv, wdkvt,
                                    wu_q, wuqt, wu_kv, wukvt, wo, wot);

  mfma_gemm<2><<<dim3(2176 / 128, M / 128), blk512, 0, stream>>>(
      xb, wdqt, cq, M, 2176, 2048, 1536, nullptr, nullptr, kvd, nullptr, nullptr);
  rmsnorm2_k<<<2 * M, 256, 0, stream>>>(cq, cqn, q_norm_w, kvd, ckvn, kv_norm_w,
                                        krope16, cosb, sinb);
  mfma_gemm<3><<<dim3(3072 / 128, M / 128), blk512, 0, stream>>>(
      cqn, wuqt, nullptr, M, 3072, 1536, 0, q16, nullptr, nullptr, cosb, sinb);
  mfma_gemm<1><<<dim3(4096 / 128, M / 128), blk512, 0, stream>>>(
      ckvn, wukvt, nullptr, M, 4096, 512, 0, kb16, vT, nullptr, nullptr, nullptr);
  attn_k<<<2 * NHEAD * (S_LEN / QT), 512, 0, stream>>>(q16, kb16, vT, krope16, aoutb);
  mfma_gemm<0><<<dim3(2048 / 128, M / 128), blk512, 0, stream>>>(
      aoutb, wot, out, M, 2048, 2048, 2048, nullptr, nullptr, nullptr, nullptr, nullptr);
}